// Round 12
// baseline (339.741 us; speedup 1.0000x reference)
//
#include <hip/hip_runtime.h>
#include <hip/hip_bf16.h>
#include <math.h>

#define NF 128   // IN_F == HID == 128

typedef __bf16 bf16x8 __attribute__((ext_vector_type(8)));
typedef unsigned short ushort8 __attribute__((ext_vector_type(8)));
typedef float f32x4 __attribute__((ext_vector_type(4)));
typedef _Float16 half8 __attribute__((ext_vector_type(8)));
typedef _Float16 half4 __attribute__((ext_vector_type(4)));

static inline int ceil_div(int a, int b) { return (a + b - 1) / b; }

// ================= CSR build: two-level multisplit counting sort =================
__global__ __launch_bounds__(256) void bucket_hist_kernel(const int* __restrict__ dst,
                                                          int* __restrict__ counts,
                                                          int e, int nblk, int nbuck) {
  __shared__ int h[256];
  int t = threadIdx.x, blk = blockIdx.x;
  h[t] = 0;
  __syncthreads();
  int base = blk * 4096;
#pragma unroll
  for (int k = 0; k < 16; ++k) {
    int i = base + k * 256 + t;
    if (i < e) atomicAdd(&h[dst[i] >> 8], 1);
  }
  __syncthreads();
  for (int b = t; b < nbuck; b += 256) counts[b * nblk + blk] = h[b];
}

__global__ __launch_bounds__(256) void bucket_scan_rows_kernel(int* __restrict__ counts,
                                                               int* __restrict__ btot,
                                                               int nblk) {
  __shared__ int sh[256];
  int b = blockIdx.x, t = threadIdx.x;
  int* row = counts + (size_t)b * nblk;
  int carry = 0;
  for (int base = 0; base < nblk; base += 256) {
    int v = (base + t < nblk) ? row[base + t] : 0;
    sh[t] = v;
    __syncthreads();
    for (int off = 1; off < 256; off <<= 1) {
      int add = (t >= off) ? sh[t - off] : 0;
      __syncthreads();
      sh[t] += add;
      __syncthreads();
    }
    if (base + t < nblk) row[base + t] = carry + sh[t] - v;
    carry += sh[255];
    __syncthreads();
  }
  if (t == 0) btot[b] = carry;
}

__global__ __launch_bounds__(256) void bucket_base_kernel(const int* __restrict__ btot,
                                                          int* __restrict__ bbase,
                                                          int nbuck, int e) {
  __shared__ int sh[256];
  __shared__ int carry;
  int t = threadIdx.x;
  if (t == 0) carry = 0;
  __syncthreads();
  for (int base = 0; base < nbuck; base += 256) {
    int v = (base + t < nbuck) ? btot[base + t] : 0;
    sh[t] = v;
    __syncthreads();
    for (int off = 1; off < 256; off <<= 1) {
      int add = (t >= off) ? sh[t - off] : 0;
      __syncthreads();
      sh[t] += add;
      __syncthreads();
    }
    if (base + t < nbuck) bbase[base + t] = carry + sh[t] - v;
    __syncthreads();
    if (t == 0) carry += sh[255];
    __syncthreads();
  }
  if (t == 0) bbase[nbuck] = e;
}

__global__ __launch_bounds__(256) void bucket_bin_kernel(const int* __restrict__ src,
                                                         const int* __restrict__ dst,
                                                         const int* __restrict__ counts,
                                                         const int* __restrict__ bbase,
                                                         int2* __restrict__ binned,
                                                         int e, int nblk, int nbuck) {
  __shared__ int cur[256];
  int t = threadIdx.x, blk = blockIdx.x;
  for (int b = t; b < nbuck; b += 256) cur[b] = counts[b * nblk + blk] + bbase[b];
  __syncthreads();
  int base = blk * 4096;
#pragma unroll
  for (int k = 0; k < 16; ++k) {
    int i = base + k * 256 + t;
    if (i < e) {
      int d = dst[i];
      int pos = atomicAdd(&cur[d >> 8], 1);
      binned[pos] = make_int2(src[i], d);
    }
  }
}

__global__ __launch_bounds__(256) void bucket_finalize_kernel(const int2* __restrict__ binned,
                                                              const int* __restrict__ bbase,
                                                              int* __restrict__ offsets,
                                                              int* __restrict__ csr,
                                                              float* __restrict__ dinv,
                                                              int n, int e, int nbuck) {
  __shared__ int deg[256];
  __shared__ int offs[256];
  __shared__ int cur[256];
  int b = blockIdx.x, t = threadIdx.x;
  int ebeg = bbase[b];
  int eend = bbase[b + 1];
  deg[t] = 0;
  __syncthreads();
  for (int j = ebeg + t; j < eend; j += 256) atomicAdd(&deg[binned[j].y & 255], 1);
  __syncthreads();
  int v = deg[t];
  offs[t] = v;
  __syncthreads();
  for (int off = 1; off < 256; off <<= 1) {
    int add = (t >= off) ? offs[t - off] : 0;
    __syncthreads();
    offs[t] += add;
    __syncthreads();
  }
  int excl = offs[t] - v;
  cur[t] = excl;
  int node = b * 256 + t;
  if (node < n) {
    offsets[node] = ebeg + excl;
    float d = (float)(v > 1 ? v : 1);
    dinv[node] = rsqrtf(d);
  }
  if (b == nbuck - 1 && t == 0) offsets[n] = e;
  __syncthreads();
  for (int j = ebeg + t; j < eend; j += 256) {
    int2 pr = binned[j];
    int pos = atomicAdd(&cur[pr.y & 255], 1);
    csr[ebeg + pos] = pr.x;
  }
}

// ============== swz-split-bf16 helpers ==============
// Row layout (512 B): [16 hi-frags of 8 bf16, slot fc^(row&15)][16 lo-frags, same swizzle]
__device__ __forceinline__ void split8(const float* xv, ushort8& hi, ushort8& lo) {
#pragma unroll
  for (int j = 0; j < 8; ++j) {
    __bf16 hh = (__bf16)xv[j];
    __bf16 ll = (__bf16)(xv[j] - (float)hh);
    hi[j] = __builtin_bit_cast(unsigned short, hh);
    lo[j] = __builtin_bit_cast(unsigned short, ll);
  }
}

// ---------------- prep_feat: emits Fsp (swz-split) + xsA = fp16(feat*dinv) ----------------
__global__ void prep_feat_kernel(const float* __restrict__ feat, const float* __restrict__ dinv,
                                 unsigned short* __restrict__ Fsp, _Float16* __restrict__ xs,
                                 int n) {
  int i = blockIdx.x * 256 + threadIdx.x;   // frag index
  if (i >= n * 16) return;
  int row = i >> 4, fc = i & 15;
  const float4* s = (const float4*)(feat + (size_t)row * NF + fc * 8);
  float4 a = s[0], b = s[1];
  float xv[8] = {a.x, a.y, a.z, a.w, b.x, b.y, b.z, b.w};
  float d = dinv[row];
  half8 h;
#pragma unroll
  for (int j = 0; j < 8; ++j) h[j] = (_Float16)(xv[j] * d);
  *(half8*)(xs + (size_t)row * NF + fc * 8) = h;
  ushort8 hi, lo;
  split8(xv, hi, lo);
  int swz = (fc ^ (row & 15)) * 8;
  *(ushort8*)(Fsp + (size_t)row * 256 + swz) = hi;
  *(ushort8*)(Fsp + (size_t)row * 256 + 128 + swz) = lo;
}

// ---------------- SpMV, feature-half-split (2 passes in one dispatch, pass-major) -------
// Pass p handles feature frags [8p, 8p+8) (128 B of each 256 B row) -> per-pass L2
// footprint halves (12.8 -> 6.4 MB per XCD). Lane = [edge-of-8 (lane>>3)][frag (lane&7)];
// one dwordx4 gathers 8 edges' worth across the wave. 16-edge unrolled main loop.
__global__ __launch_bounds__(256) void spmv_kernel(
    const _Float16* __restrict__ xs16, const float* __restrict__ dinv,
    const int* __restrict__ offsets, const int* __restrict__ csr,
    const float* __restrict__ z, float a, float bz,
    unsigned short* __restrict__ outsp, _Float16* __restrict__ outs16, int n, int nbHalf) {
  int blk = blockIdx.x;
  int pass = 0;
  if (blk >= nbHalf) { pass = 1; blk -= nbHalf; }
  int w = threadIdx.x >> 6, lane = threadIdx.x & 63;
  int node = blk * 4 + w;
  if (node >= n) return;
  int beg = __builtin_amdgcn_readfirstlane(offsets[node]);
  int end = __builtin_amdgcn_readfirstlane(offsets[node + 1]);
  int eh = lane >> 3;               // edge-of-8 (0..7)
  int cq = (lane & 7) + pass * 8;   // half8 frag within the 128-half row

  float acc[8];
#pragma unroll
  for (int j = 0; j < 8; ++j) acc[j] = 0.f;

  int e2 = beg;
  for (; e2 + 16 <= end; e2 += 16) {
    int s0 = csr[e2 + eh];
    int s1 = csr[e2 + 8 + eh];
    half8 g0 = ((const half8*)(xs16 + (size_t)s0 * NF))[cq];
    half8 g1 = ((const half8*)(xs16 + (size_t)s1 * NF))[cq];
#pragma unroll
    for (int j = 0; j < 8; ++j) acc[j] += (float)g0[j];
#pragma unroll
    for (int j = 0; j < 8; ++j) acc[j] += (float)g1[j];
  }
  for (; e2 + 8 <= end; e2 += 8) {
    int s0 = csr[e2 + eh];
    half8 g0 = ((const half8*)(xs16 + (size_t)s0 * NF))[cq];
#pragma unroll
    for (int j = 0; j < 8; ++j) acc[j] += (float)g0[j];
  }
  int rem = end - e2;
  if (eh < rem) {
    int s0 = csr[e2 + eh];
    half8 g0 = ((const half8*)(xs16 + (size_t)s0 * NF))[cq];
#pragma unroll
    for (int j = 0; j < 8; ++j) acc[j] += (float)g0[j];
  }
  // reduce across the 8 edge-groups (stride 8, 16, 32)
#pragma unroll
  for (int j = 0; j < 8; ++j) {
    acc[j] += __shfl_xor(acc[j], 8);
    acc[j] += __shfl_xor(acc[j], 16);
    acc[j] += __shfl_xor(acc[j], 32);
  }
  if (eh == 0) {
    float dv = dinv[node];
    float v[8];
#pragma unroll
    for (int j = 0; j < 8; ++j) v[j] = a * dv * acc[j];
    if (z) {
      const f32x4* zp = (const f32x4*)(z + (size_t)node * NF + cq * 8);
      f32x4 z0 = zp[0], z1 = zp[1];
#pragma unroll
      for (int j = 0; j < 4; ++j) { v[j] += bz * z0[j]; v[4 + j] += bz * z1[j]; }
    }
    ushort8 hi, lo;
    split8(v, hi, lo);
    int swz = (cq ^ (node & 15)) * 8;
    *(ushort8*)(outsp + (size_t)node * 256 + swz) = hi;
    *(ushort8*)(outsp + (size_t)node * 256 + 128 + swz) = lo;
    if (outs16) {
      half8 hv;
#pragma unroll
      for (int j = 0; j < 8; ++j) hv[j] = (_Float16)(v[j] * dv);
      *(half8*)(outs16 + (size_t)node * NF + cq * 8) = hv;
    }
  }
}

// ---------------- W pre-split + frag-pack ----------------
__device__ __forceinline__ void pack_one(const float* __restrict__ W, ushort8* __restrict__ Wp,
                                         int f, int NT, int K) {
  int lane = f & 63;
  int hl = (f >> 6) & 1;
  int rest = f >> 7;
  int nt = rest % NT;
  int kunit = rest / NT;
  int nrow = nt * 16 + (lane & 15);
  int k0 = kunit * 32 + (lane >> 4) * 8;
  const float* srcp = W + (size_t)nrow * K + k0;
  ushort8 v;
#pragma unroll
  for (int j = 0; j < 8; ++j) {
    float x = srcp[j];
    __bf16 h = (__bf16)x;
    if (hl) h = (__bf16)(x - (float)h);
    v[j] = __builtin_bit_cast(unsigned short, h);
  }
  Wp[f] = v;
}

__global__ void pack_all_kernel(const float* __restrict__ W1, ushort8* __restrict__ P1,
                                const float* __restrict__ W3, ushort8* __restrict__ P3,
                                const float* __restrict__ Wm1, ushort8* __restrict__ PM1,
                                const float* __restrict__ Wm2, ushort8* __restrict__ PM2) {
  int f = blockIdx.x * 256 + threadIdx.x;
  if (f < 12288) pack_one(W1, P1, f, 8, 384);
  else if (f < 24576) pack_one(W3, P3, f - 12288, 8, 384);
  else if (f < 28672) pack_one(Wm1, PM1, f - 24576, 8, 128);
  else if (f < 30720) pack_one(Wm2, PM2, f - 28672, 4, 128);
}

// ================= GEMM machinery =================
// 512 thr = 8 waves (wm{0,1} x wn{0..3}); tile 64 rows x NC; A staged via global_load_lds
// from pre-swizzled split-bf16 global rows (32 KB/part), double-buffered, counted vmcnt.
// B register-double-buffered at half-phase (2-kunit) granularity.

__device__ __forceinline__ void stage_sp(const unsigned short* gsrc, float4* lbuf, int tid) {
  const char* g = (const char*)gsrc;
  char* l = (char*)lbuf;
#pragma unroll
  for (int k = 0; k < 4; ++k) {
    int off = k * 8192 + tid * 16;
    __builtin_amdgcn_global_load_lds(
        (const __attribute__((address_space(1))) void*)(g + off),
        (__attribute__((address_space(3))) void*)(l + off), 16, 0, 0);
  }
}

__device__ __forceinline__ void lds_put_split(unsigned short* L, int row, int col, float v) {
  __bf16 hh = (__bf16)v;
  __bf16 ll = (__bf16)(v - (float)hh);
  int base = row * 256 + (((col >> 3) ^ (row & 15)) << 3) + (col & 7);
  L[base] = __builtin_bit_cast(unsigned short, hh);
  L[base + 128] = __builtin_bit_cast(unsigned short, ll);
}

// B chunk: 2 kunits x NT2=2 n-tiles x (hi,lo) = 8 frags = 32 VGPR
struct Bchunk {
  ushort8 h[2][2];
  ushort8 l[2][2];
};

__device__ __forceinline__ void loadB(const ushort8* __restrict__ Wp, int kunit0,
                                      int lane, int wn, Bchunk& c) {
#pragma unroll
  for (int k2 = 0; k2 < 2; ++k2) {
#pragma unroll
    for (int j = 0; j < 2; ++j) {
      const ushort8* bp = Wp + (size_t)((kunit0 + k2) * 8 + wn * 2 + j) * 128 + lane;
      c.h[k2][j] = bp[0];
      c.l[k2][j] = bp[64];
    }
  }
}

// MFMA one B-chunk: 2 kunits x 2 mt x 2 j x 3 split-terms = 24 MFMAs
__device__ __forceinline__ void mfma_chunk(const float4* B4, const Bchunk& c, int kbase,
                                           int lane, int wm, f32x4 (*acc)[2]) {
#pragma unroll
  for (int k2 = 0; k2 < 2; ++k2) {
    int kunit = kbase + k2;
    bf16x8 ah[2], al[2];
#pragma unroll
    for (int mt = 0; mt < 2; ++mt) {
      int arow = wm * 32 + mt * 16 + (lane & 15);
      int fc = (kunit & 3) * 4 + (lane >> 4);
      int idx = arow * 32 + (fc ^ (arow & 15));
      ah[mt] = __builtin_bit_cast(bf16x8, B4[idx]);
      al[mt] = __builtin_bit_cast(bf16x8, B4[idx + 16]);
    }
#pragma unroll
    for (int j = 0; j < 2; ++j) {
      bf16x8 bh = __builtin_bit_cast(bf16x8, c.h[k2][j]);
      bf16x8 bl = __builtin_bit_cast(bf16x8, c.l[k2][j]);
#pragma unroll
      for (int mt = 0; mt < 2; ++mt) {
        acc[mt][j] = __builtin_amdgcn_mfma_f32_16x16x32_bf16(ah[mt], bh, acc[mt][j], 0, 0, 0);
        acc[mt][j] = __builtin_amdgcn_mfma_f32_16x16x32_bf16(ah[mt], bl, acc[mt][j], 0, 0, 0);
        acc[mt][j] = __builtin_amdgcn_mfma_f32_16x16x32_bf16(al[mt], bh, acc[mt][j], 0, 0, 0);
      }
    }
  }
}

// generic gemm_step for the small MLP phases (B compiler-managed)
template<int NT, int NT2>
__device__ __forceinline__ void gemm_step512(const float4* B4, const ushort8* __restrict__ Wp,
                                             int kunit, int lane, int wm, int wn,
                                             f32x4 (*acc)[NT2]) {
  bf16x8 ah[2], al[2];
#pragma unroll
  for (int mt = 0; mt < 2; ++mt) {
    int arow = wm * 32 + mt * 16 + (lane & 15);
    int fc = (kunit & 3) * 4 + (lane >> 4);
    int idx = arow * 32 + (fc ^ (arow & 15));
    ah[mt] = __builtin_bit_cast(bf16x8, B4[idx]);
    al[mt] = __builtin_bit_cast(bf16x8, B4[idx + 16]);
  }
#pragma unroll
  for (int j = 0; j < NT2; ++j) {
    int nt = wn * NT2 + j;
    const ushort8* bp = Wp + (size_t)(kunit * NT + nt) * 2 * 64 + lane;
    bf16x8 bh = __builtin_bit_cast(bf16x8, bp[0]);
    bf16x8 bl = __builtin_bit_cast(bf16x8, bp[64]);
#pragma unroll
    for (int mt = 0; mt < 2; ++mt) {
      acc[mt][j] = __builtin_amdgcn_mfma_f32_16x16x32_bf16(ah[mt], bh, acc[mt][j], 0, 0, 0);
      acc[mt][j] = __builtin_amdgcn_mfma_f32_16x16x32_bf16(ah[mt], bl, acc[mt][j], 0, 0, 0);
      acc[mt][j] = __builtin_amdgcn_mfma_f32_16x16x32_bf16(al[mt], bh, acc[mt][j], 0, 0, 0);
    }
  }
}

// 3-part pipelined K-loop: A via gload_lds dbuf (counted vmcnt), B via register dbuf chunks
__device__ __forceinline__ void gemm3_pipeline(const unsigned short* A0, const unsigned short* A1,
                                               const unsigned short* A2, const ushort8* Wp,
                                               float4 (*buf)[2048], size_t r0,
                                               int tid, int lane, int wm, int wn,
                                               f32x4 (*acc)[2]) {
  const unsigned short* Aarr[3] = {A0, A1, A2};
  stage_sp(A0 + r0 * 256, buf[0], tid);
  Bchunk bc0, bc1;
#pragma unroll
  for (int p = 0; p < 3; ++p) {
    loadB(Wp, p * 4, lane, wn, bc0);          // oldest-after-A[p]: stays in flight past wait
    if (p + 1 < 3) {
      stage_sp(Aarr[p + 1] + r0 * 256, buf[(p + 1) & 1], tid);
      asm volatile("s_waitcnt vmcnt(12)" ::: "memory");   // A[p] done; bc0+A[p+1] in flight
    } else {
      asm volatile("s_waitcnt vmcnt(8)" ::: "memory");    // A[2] done; bc0 in flight
    }
    __builtin_amdgcn_s_barrier();
    __builtin_amdgcn_sched_barrier(0);
    loadB(Wp, p * 4 + 2, lane, wn, bc1);      // next chunk flies during bc0's MFMAs
    mfma_chunk(buf[p & 1], bc0, p * 4, lane, wm, acc);
    mfma_chunk(buf[p & 1], bc1, p * 4 + 2, lane, wm, acc);
    __builtin_amdgcn_sched_barrier(0);
    __builtin_amdgcn_s_barrier();
  }
}

// ---------------- conv1 GEMM + fused BN partial stats ----------------
__global__ __launch_bounds__(512, 4) void conv1_gemm_kernel(
    const unsigned short* __restrict__ A0, const unsigned short* __restrict__ A1,
    const unsigned short* __restrict__ A2,
    const ushort8* __restrict__ Wp, const float* __restrict__ bias,
    float* __restrict__ out, float* __restrict__ stats, int n) {
  __shared__ float4 buf[2][2048];   // 64 KB
  __shared__ float sstat[256];

  int tid = threadIdx.x;
  int lane = tid & 63, wid = tid >> 6;
  int wm = wid >> 2, wn = wid & 3;
  size_t r0 = (size_t)blockIdx.x * 64;

  f32x4 acc[2][2];
#pragma unroll
  for (int mt = 0; mt < 2; ++mt)
#pragma unroll
    for (int j = 0; j < 2; ++j) acc[mt][j] = (f32x4)0.f;

  gemm3_pipeline(A0, A1, A2, Wp, buf, r0, tid, lane, wm, wn, acc);

  // epilogue: relu + store + BN partial stats
  if (tid < 256) sstat[tid] = 0.f;
  __syncthreads();
#pragma unroll
  for (int mt = 0; mt < 2; ++mt) {
    int rbase = (int)r0 + wm * 32 + mt * 16 + (lane >> 4) * 4;
#pragma unroll
    for (int j = 0; j < 2; ++j) {
      int col = wn * 32 + j * 16 + (lane & 15);
      float b = bias[col];
      float sj = 0.f, qj = 0.f;
#pragma unroll
      for (int i = 0; i < 4; ++i) {
        int row = rbase + i;
        if (row < n) {
          float v = fmaxf(acc[mt][j][i] + b, 0.f);
          out[(size_t)row * NF + col] = v;
          sj += v; qj += v * v;
        }
      }
      sj += __shfl_xor(sj, 16); sj += __shfl_xor(sj, 32);
      qj += __shfl_xor(qj, 16); qj += __shfl_xor(qj, 32);
      if ((lane >> 4) == 0) {
        atomicAdd(&sstat[col], sj);
        atomicAdd(&sstat[128 + col], qj);
      }
    }
  }
  __syncthreads();
  if (tid < 256) atomicAdd(&stats[tid], sstat[tid]);
}

// ---------------- fused tail: conv2 GEMM + residual -> MLP1 -> MLP2 on-chip ----------------
__global__ __launch_bounds__(512, 4) void fused_tail_kernel(
    const unsigned short* __restrict__ Xsp, const unsigned short* __restrict__ T1sp,
    const unsigned short* __restrict__ T2sp, const float* __restrict__ X,
    const ushort8* __restrict__ Wp3, const float* __restrict__ b3,
    const ushort8* __restrict__ WpM1, const float* __restrict__ bm1,
    const ushort8* __restrict__ WpM2, const float* __restrict__ bm2,
    float* __restrict__ out, int n) {
  __shared__ float4 buf[2][2048];
  unsigned short* L = (unsigned short*)buf[0];

  int tid = threadIdx.x;
  int lane = tid & 63, wid = tid >> 6;
  int wm = wid >> 2, wn = wid & 3;
  size_t r0 = (size_t)blockIdx.x * 64;

  f32x4 acc[2][2];
#pragma unroll
  for (int mt = 0; mt < 2; ++mt)
#pragma unroll
    for (int j = 0; j < 2; ++j) acc[mt][j] = (f32x4)0.f;

  // ---- phase 1: conv2 GEMM over {Xsp, T1sp, T2sp}
  gemm3_pipeline(Xsp, T1sp, T2sp, Wp3, buf, r0, tid, lane, wm, wn, acc);

  // ---- epilogue 1: Y = relu(acc+b3)+X -> split into LDS (buf[0], packed layout)
#pragma unroll
  for (int mt = 0; mt < 2; ++mt) {
    int rb = wm * 32 + mt * 16 + (lane >> 4) * 4;
#pragma unroll
    for (int j = 0; j < 2; ++j) {
      int col = wn * 32 + j * 16 + (lane & 15);
      float b = b3[col];
#pragma unroll
      for (int i = 0; i < 4; ++i) {
        int lrow = rb + i;
        int row = (int)r0 + lrow;
        float v = 0.f;
        if (row < n) v = fmaxf(acc[mt][j][i] + b, 0.f) + X[(size_t)row * NF + col];
        lds_put_split(L, lrow, col, v);
      }
    }
  }
  __syncthreads();
  // ---- phase 2: H = relu(Y @ Wm1^T + bm1)
  f32x4 acc2[2][2];
#pragma unroll
  for (int mt = 0; mt < 2; ++mt)
#pragma unroll
    for (int j = 0; j < 2; ++j) acc2[mt][j] = (f32x4)0.f;
#pragma unroll
  for (int ks = 0; ks < 4; ++ks)
    gemm_step512<8, 2>(buf[0], WpM1, ks, lane, wm, wn, acc2);
  __syncthreads();   // all reads of Y done before overwrite
  // ---- epilogue 2: scatter H into LDS
#pragma unroll
  for (int mt = 0; mt < 2; ++mt) {
    int rb = wm * 32 + mt * 16 + (lane >> 4) * 4;
#pragma unroll
    for (int j = 0; j < 2; ++j) {
      int col = wn * 32 + j * 16 + (lane & 15);
      float b = bm1[col];
#pragma unroll
      for (int i = 0; i < 4; ++i) {
        float v = fmaxf(acc2[mt][j][i] + b, 0.f);
        lds_put_split(L, rb + i, col, v);
      }
    }
  }
  __syncthreads();
  // ---- phase 3: out = H @ Wm2^T + bm2   (NC=64: NT=4, NT2=1)
  f32x4 acc3[2][1];
#pragma unroll
  for (int mt = 0; mt < 2; ++mt) acc3[mt][0] = (f32x4)0.f;
#pragma unroll
  for (int ks = 0; ks < 4; ++ks)
    gemm_step512<4, 1>(buf[0], WpM2, ks, lane, wm, wn, acc3);
#pragma unroll
  for (int mt = 0; mt < 2; ++mt) {
    int rb = wm * 32 + mt * 16 + (lane >> 4) * 4;
    int col = wn * 16 + (lane & 15);
    float b = bm2[col];
#pragma unroll
    for (int i = 0; i < 4; ++i) {
      int row = (int)r0 + rb + i;
      if (row < n) out[(size_t)row * 64 + col] = acc3[mt][0][i] + b;
    }
  }
}

// ---------------- BatchNorm scale/apply ----------------
__global__ void bn_scale_kernel(const float* __restrict__ stats, const float* __restrict__ gamma,
                                const float* __restrict__ beta, float* __restrict__ sc,
                                float* __restrict__ sh, float n) {
  int c = threadIdx.x;   // 128
  float mu = stats[c] / n;
  float var = stats[NF + c] / n - mu * mu;
  float s = gamma[c] * rsqrtf(var + 1e-5f);
  sc[c] = s;
  sh[c] = beta[c] - mu * s;
}

// BN apply in place + emit Xsp (swz-split) + xs16 = fp16(X*dinv)
__global__ void bn_apply_kernel(float* __restrict__ x, const float* __restrict__ sc,
                                const float* __restrict__ sh, const float* __restrict__ dinv,
                                unsigned short* __restrict__ Xsp, _Float16* __restrict__ xs16,
                                int n) {
  int i = blockIdx.x * 256 + threadIdx.x;   // frag index
  if (i >= n * 16) return;
  int row = i >> 4, fc = i & 15;
  float4* xp = (float4*)(x + (size_t)row * NF + fc * 8);
  float4 a = xp[0], b = xp[1];
  float xv[8] = {a.x, a.y, a.z, a.w, b.x, b.y, b.z, b.w};
  int c0 = fc * 8;
#pragma unroll
  for (int j = 0; j < 8; ++j) xv[j] = xv[j] * sc[c0 + j] + sh[c0 + j];
  float4 o0, o1;
  o0.x = xv[0]; o0.y = xv[1]; o0.z = xv[2]; o0.w = xv[3];
  o1.x = xv[4]; o1.y = xv[5]; o1.z = xv[6]; o1.w = xv[7];
  xp[0] = o0; xp[1] = o1;
  float d = dinv[row];
  half8 h;
#pragma unroll
  for (int j = 0; j < 8; ++j) h[j] = (_Float16)(xv[j] * d);
  *(half8*)(xs16 + (size_t)row * NF + fc * 8) = h;
  ushort8 hi, lo;
  split8(xv, hi, lo);
  int swz = (fc ^ (row & 15)) * 8;
  *(ushort8*)(Xsp + (size_t)row * 256 + swz) = hi;
  *(ushort8*)(Xsp + (size_t)row * 256 + 128 + swz) = lo;
}

// ---------------- launcher ----------------
extern "C" void kernel_launch(void* const* d_in, const int* in_sizes, int n_in,
                              void* d_out, int out_size, void* d_ws, size_t ws_size,
                              hipStream_t stream) {
  const float* feat  = (const float*)d_in[0];
  const int*   src   = (const int*)d_in[1];
  const int*   dst   = (const int*)d_in[2];
  const float* W1    = (const float*)d_in[3];
  const float* b1    = (const float*)d_in[4];
  const float* W3    = (const float*)d_in[5];
  const float* b3    = (const float*)d_in[6];
  const float* gamma = (const float*)d_in[7];
  const float* beta  = (const float*)d_in[8];
  const float* Wm1   = (const float*)d_in[9];
  const float* bm1   = (const float*)d_in[10];
  const float* Wm2   = (const float*)d_in[11];
  const float* bm2   = (const float*)d_in[12];
  int n = in_sizes[0] / NF;
  int e = in_sizes[1];

  char* p = (char*)d_ws;
  auto alloc = [&](size_t bytes) {
    char* r = p;
    p += (bytes + 255) & ~size_t(255);
    return r;
  };
  int nblk  = ceil_div(e, 4096);   // multisplit tiles
  int nbuck = ceil_div(n, 256);    // node buckets

  float* dinv     = (float*)alloc((size_t)n * 4);
  int*   offsets  = (int*)alloc((size_t)(n + 1) * 4);
  int*   counts   = (int*)alloc((size_t)nblk * nbuck * 4);
  int*   btot     = (int*)alloc((size_t)nbuck * 4);
  int*   bbase    = (int*)alloc((size_t)(nbuck + 1) * 4);
  int*   csr      = (int*)alloc((size_t)e * 4);
  float* stats    = (float*)alloc(256 * 4);
  float* bnsc     = (float*)alloc(128 * 4);
  float* bnsh     = (float*)alloc(128 * 4);
  ushort8* Wp1  = (ushort8*)alloc(12 * 8 * 2 * 64 * 16);   // K=384, NT=8
  ushort8* Wp3  = (ushort8*)alloc(12 * 8 * 2 * 64 * 16);
  ushort8* WpM1 = (ushort8*)alloc(4 * 8 * 2 * 64 * 16);    // K=128, NT=8
  ushort8* WpM2 = (ushort8*)alloc(4 * 4 * 2 * 64 * 16);    // K=128, NT=4
  size_t spb = (size_t)(n + 64) * 512;        // swz-split rows, 64 pad rows for gload_lds
  unsigned short* Fsp  = (unsigned short*)alloc(spb);
  unsigned short* T1sp = (unsigned short*)alloc(spb);
  unsigned short* T2sp = (unsigned short*)alloc(spb);
  unsigned short* Xsp  = (unsigned short*)alloc(spb);
  float* X = (float*)alloc((size_t)n * NF * 4);           // conv1 out -> BN in place -> x_res
  _Float16* xsA = (_Float16*)alloc((size_t)n * NF * 2);   // fp16 scaled gather sources
  _Float16* xsB = (_Float16*)alloc((size_t)n * NF * 2);
  int2* binned = (int2*)Fsp;   // alias: 6.4 MB scratch, dead before prep_feat writes Fsp

  hipMemsetAsync(stats, 0, 256 * 4, stream);

  int fb = ceil_div(n * 16, 256);            // frag-grid over matrices
  int nbHalf = ceil_div(n, 4);               // spmv node-blocks per feature-half pass
  int sb = 2 * nbHalf;                       // spmv grid: pass-major, 2 passes
  int gb = ceil_div(n, 64);                  // gemm: 64 rows/block, 512 threads

  // CSR build (sorted by dst) via two-level multisplit; also emits offsets/dinv
  bucket_hist_kernel<<<nblk, 256, 0, stream>>>(dst, counts, e, nblk, nbuck);
  bucket_scan_rows_kernel<<<nbuck, 256, 0, stream>>>(counts, btot, nblk);
  bucket_base_kernel<<<1, 256, 0, stream>>>(btot, bbase, nbuck, e);
  bucket_bin_kernel<<<nblk, 256, 0, stream>>>(src, dst, counts, bbase, binned, e, nblk, nbuck);
  bucket_finalize_kernel<<<nbuck, 256, 0, stream>>>(binned, bbase, offsets, csr, dinv, n, e, nbuck);

  // W split+pack
  pack_all_kernel<<<120, 256, 0, stream>>>(W1, Wp1, W3, Wp3, Wm1, WpM1, Wm2, WpM2);

  // conv1: T1 = -A^ F ; T2 = -2 A^ T1 - F ; X = relu([F,T1,T2] @ W1^T + b1)  (+BN stats)
  prep_feat_kernel<<<fb, 256, 0, stream>>>(feat, dinv, Fsp, xsA, n);
  spmv_kernel<<<sb, 256, 0, stream>>>(xsA, dinv, offsets, csr, nullptr, -1.f, 0.f, T1sp, xsB, n, nbHalf);
  spmv_kernel<<<sb, 256, 0, stream>>>(xsB, dinv, offsets, csr, feat, -2.f, -1.f, T2sp, nullptr, n, nbHalf);
  conv1_gemm_kernel<<<gb, 512, 0, stream>>>(Fsp, T1sp, T2sp, Wp1, b1, X, stats, n);

  // BatchNorm finalize + apply in place; emits Xsp + xsA = fp16(X*dinv)
  bn_scale_kernel<<<1, 128, 0, stream>>>(stats, gamma, beta, bnsc, bnsh, (float)n);
  bn_apply_kernel<<<fb, 256, 0, stream>>>(X, bnsc, bnsh, dinv, Xsp, xsA, n);

  // conv2 spmvs
  spmv_kernel<<<sb, 256, 0, stream>>>(xsA, dinv, offsets, csr, nullptr, -1.f, 0.f, T1sp, xsB, n, nbHalf);
  spmv_kernel<<<sb, 256, 0, stream>>>(xsB, dinv, offsets, csr, X, -2.f, -1.f, T2sp, nullptr, n, nbHalf);

  // fused conv2-GEMM + residual + MLP1 + MLP2 (Y, H stay on-chip)
  fused_tail_kernel<<<gb, 512, 0, stream>>>(Xsp, T1sp, T2sp, X, Wp3, b3, WpM1, bm1, WpM2, bm2,
                                            (float*)d_out, n);
}

// Round 13
// 297.305 us; speedup vs baseline: 1.1427x; 1.1427x over previous
//
#include <hip/hip_runtime.h>
#include <hip/hip_bf16.h>
#include <math.h>

#define NF 128   // IN_F == HID == 128

typedef __bf16 bf16x8 __attribute__((ext_vector_type(8)));
typedef unsigned short ushort8 __attribute__((ext_vector_type(8)));
typedef float f32x4 __attribute__((ext_vector_type(4)));
typedef _Float16 half8 __attribute__((ext_vector_type(8)));
typedef _Float16 half4 __attribute__((ext_vector_type(4)));

static inline int ceil_div(int a, int b) { return (a + b - 1) / b; }

// ================= CSR build: two-level multisplit counting sort =================
__global__ __launch_bounds__(256) void bucket_hist_kernel(const int* __restrict__ dst,
                                                          int* __restrict__ counts,
                                                          int e, int nblk, int nbuck) {
  __shared__ int h[256];
  int t = threadIdx.x, blk = blockIdx.x;
  h[t] = 0;
  __syncthreads();
  int base = blk * 4096;
#pragma unroll
  for (int k = 0; k < 16; ++k) {
    int i = base + k * 256 + t;
    if (i < e) atomicAdd(&h[dst[i] >> 8], 1);
  }
  __syncthreads();
  for (int b = t; b < nbuck; b += 256) counts[b * nblk + blk] = h[b];
}

__global__ __launch_bounds__(256) void bucket_scan_rows_kernel(int* __restrict__ counts,
                                                               int* __restrict__ btot,
                                                               int nblk) {
  __shared__ int sh[256];
  int b = blockIdx.x, t = threadIdx.x;
  int* row = counts + (size_t)b * nblk;
  int carry = 0;
  for (int base = 0; base < nblk; base += 256) {
    int v = (base + t < nblk) ? row[base + t] : 0;
    sh[t] = v;
    __syncthreads();
    for (int off = 1; off < 256; off <<= 1) {
      int add = (t >= off) ? sh[t - off] : 0;
      __syncthreads();
      sh[t] += add;
      __syncthreads();
    }
    if (base + t < nblk) row[base + t] = carry + sh[t] - v;
    carry += sh[255];
    __syncthreads();
  }
  if (t == 0) btot[b] = carry;
}

__global__ __launch_bounds__(256) void bucket_base_kernel(const int* __restrict__ btot,
                                                          int* __restrict__ bbase,
                                                          int nbuck, int e) {
  __shared__ int sh[256];
  __shared__ int carry;
  int t = threadIdx.x;
  if (t == 0) carry = 0;
  __syncthreads();
  for (int base = 0; base < nbuck; base += 256) {
    int v = (base + t < nbuck) ? btot[base + t] : 0;
    sh[t] = v;
    __syncthreads();
    for (int off = 1; off < 256; off <<= 1) {
      int add = (t >= off) ? sh[t - off] : 0;
      __syncthreads();
      sh[t] += add;
      __syncthreads();
    }
    if (base + t < nbuck) bbase[base + t] = carry + sh[t] - v;
    __syncthreads();
    if (t == 0) carry += sh[255];
    __syncthreads();
  }
  if (t == 0) bbase[nbuck] = e;
}

__global__ __launch_bounds__(256) void bucket_bin_kernel(const int* __restrict__ src,
                                                         const int* __restrict__ dst,
                                                         const int* __restrict__ counts,
                                                         const int* __restrict__ bbase,
                                                         int2* __restrict__ binned,
                                                         int e, int nblk, int nbuck) {
  __shared__ int cur[256];
  int t = threadIdx.x, blk = blockIdx.x;
  for (int b = t; b < nbuck; b += 256) cur[b] = counts[b * nblk + blk] + bbase[b];
  __syncthreads();
  int base = blk * 4096;
#pragma unroll
  for (int k = 0; k < 16; ++k) {
    int i = base + k * 256 + t;
    if (i < e) {
      int d = dst[i];
      int pos = atomicAdd(&cur[d >> 8], 1);
      binned[pos] = make_int2(src[i], d);
    }
  }
}

__global__ __launch_bounds__(256) void bucket_finalize_kernel(const int2* __restrict__ binned,
                                                              const int* __restrict__ bbase,
                                                              int* __restrict__ offsets,
                                                              int* __restrict__ csr,
                                                              float* __restrict__ dinv,
                                                              int n, int e, int nbuck) {
  __shared__ int deg[256];
  __shared__ int offs[256];
  __shared__ int cur[256];
  int b = blockIdx.x, t = threadIdx.x;
  int ebeg = bbase[b];
  int eend = bbase[b + 1];
  deg[t] = 0;
  __syncthreads();
  for (int j = ebeg + t; j < eend; j += 256) atomicAdd(&deg[binned[j].y & 255], 1);
  __syncthreads();
  int v = deg[t];
  offs[t] = v;
  __syncthreads();
  for (int off = 1; off < 256; off <<= 1) {
    int add = (t >= off) ? offs[t - off] : 0;
    __syncthreads();
    offs[t] += add;
    __syncthreads();
  }
  int excl = offs[t] - v;
  cur[t] = excl;
  int node = b * 256 + t;
  if (node < n) {
    offsets[node] = ebeg + excl;
    float d = (float)(v > 1 ? v : 1);
    dinv[node] = rsqrtf(d);
  }
  if (b == nbuck - 1 && t == 0) offsets[n] = e;
  __syncthreads();
  for (int j = ebeg + t; j < eend; j += 256) {
    int2 pr = binned[j];
    int pos = atomicAdd(&cur[pr.y & 255], 1);
    csr[ebeg + pos] = pr.x;
  }
}

// ============== swz-split-bf16 helpers ==============
// Row layout (512 B): [16 hi-frags of 8 bf16, slot fc^(row&15)][16 lo-frags, same swizzle]
__device__ __forceinline__ void split8(const float* xv, ushort8& hi, ushort8& lo) {
#pragma unroll
  for (int j = 0; j < 8; ++j) {
    __bf16 hh = (__bf16)xv[j];
    __bf16 ll = (__bf16)(xv[j] - (float)hh);
    hi[j] = __builtin_bit_cast(unsigned short, hh);
    lo[j] = __builtin_bit_cast(unsigned short, ll);
  }
}

// ---------------- prep_feat: emits Fsp (swz-split) + xsA = fp16(feat*dinv) ----------------
__global__ void prep_feat_kernel(const float* __restrict__ feat, const float* __restrict__ dinv,
                                 unsigned short* __restrict__ Fsp, _Float16* __restrict__ xs,
                                 int n) {
  int i = blockIdx.x * 256 + threadIdx.x;   // frag index
  if (i >= n * 16) return;
  int row = i >> 4, fc = i & 15;
  const float4* s = (const float4*)(feat + (size_t)row * NF + fc * 8);
  float4 a = s[0], b = s[1];
  float xv[8] = {a.x, a.y, a.z, a.w, b.x, b.y, b.z, b.w};
  float d = dinv[row];
  half8 h;
#pragma unroll
  for (int j = 0; j < 8; ++j) h[j] = (_Float16)(xv[j] * d);
  *(half8*)(xs + (size_t)row * NF + fc * 8) = h;
  ushort8 hi, lo;
  split8(xv, hi, lo);
  int swz = (fc ^ (row & 15)) * 8;
  *(ushort8*)(Fsp + (size_t)row * 256 + swz) = hi;
  *(ushort8*)(Fsp + (size_t)row * 256 + 128 + swz) = lo;
}

// ---------------- SpMV (R11 form): gathers fp16 pre-scaled; emits swz-split out ----------
// One wave per node. Lane = [edge-of-quad (lane>>4)][16B slot of 256B row (lane&15)].
__global__ __launch_bounds__(256) void spmv_kernel(
    const _Float16* __restrict__ xs16, const float* __restrict__ dinv,
    const int* __restrict__ offsets, const int* __restrict__ csr,
    const float* __restrict__ z, float a, float bz,
    unsigned short* __restrict__ outsp, _Float16* __restrict__ outs16, int n) {
  int w = threadIdx.x >> 6, lane = threadIdx.x & 63;
  int node = blockIdx.x * 4 + w;
  if (node >= n) return;
  int beg = __builtin_amdgcn_readfirstlane(offsets[node]);
  int end = __builtin_amdgcn_readfirstlane(offsets[node + 1]);
  int eh = lane >> 4;        // which edge of the quad (0..3)
  int cq = lane & 15;        // half8 frag within the 128-half row

  float acc[8];
#pragma unroll
  for (int j = 0; j < 8; ++j) acc[j] = 0.f;

  int e2 = beg;
  for (; e2 + 8 <= end; e2 += 8) {
    int s0 = csr[e2 + eh];
    int s1 = csr[e2 + 4 + eh];
    half8 g0 = ((const half8*)(xs16 + (size_t)s0 * NF))[cq];
    half8 g1 = ((const half8*)(xs16 + (size_t)s1 * NF))[cq];
#pragma unroll
    for (int j = 0; j < 8; ++j) acc[j] += (float)g0[j];
#pragma unroll
    for (int j = 0; j < 8; ++j) acc[j] += (float)g1[j];
  }
  for (; e2 + 4 <= end; e2 += 4) {
    int s0 = csr[e2 + eh];
    half8 g0 = ((const half8*)(xs16 + (size_t)s0 * NF))[cq];
#pragma unroll
    for (int j = 0; j < 8; ++j) acc[j] += (float)g0[j];
  }
  int rem = end - e2;
  if (eh < rem) {
    int s0 = csr[e2 + eh];
    half8 g0 = ((const half8*)(xs16 + (size_t)s0 * NF))[cq];
#pragma unroll
    for (int j = 0; j < 8; ++j) acc[j] += (float)g0[j];
  }
#pragma unroll
  for (int j = 0; j < 8; ++j) {
    acc[j] += __shfl_xor(acc[j], 16);
    acc[j] += __shfl_xor(acc[j], 32);
  }
  if (eh == 0) {
    float dv = dinv[node];
    float v[8];
#pragma unroll
    for (int j = 0; j < 8; ++j) v[j] = a * dv * acc[j];
    if (z) {
      const f32x4* zp = (const f32x4*)(z + (size_t)node * NF + cq * 8);
      f32x4 z0 = zp[0], z1 = zp[1];
#pragma unroll
      for (int j = 0; j < 4; ++j) { v[j] += bz * z0[j]; v[4 + j] += bz * z1[j]; }
    }
    ushort8 hi, lo;
    split8(v, hi, lo);
    int swz = (cq ^ (node & 15)) * 8;
    *(ushort8*)(outsp + (size_t)node * 256 + swz) = hi;
    *(ushort8*)(outsp + (size_t)node * 256 + 128 + swz) = lo;
    if (outs16) {
      half8 hv;
#pragma unroll
      for (int j = 0; j < 8; ++j) hv[j] = (_Float16)(v[j] * dv);
      *(half8*)(outs16 + (size_t)node * NF + cq * 8) = hv;
    }
  }
}

// ---------------- W pre-split + frag-pack ----------------
__device__ __forceinline__ void pack_one(const float* __restrict__ W, ushort8* __restrict__ Wp,
                                         int f, int NT, int K) {
  int lane = f & 63;
  int hl = (f >> 6) & 1;
  int rest = f >> 7;
  int nt = rest % NT;
  int kunit = rest / NT;
  int nrow = nt * 16 + (lane & 15);
  int k0 = kunit * 32 + (lane >> 4) * 8;
  const float* srcp = W + (size_t)nrow * K + k0;
  ushort8 v;
#pragma unroll
  for (int j = 0; j < 8; ++j) {
    float x = srcp[j];
    __bf16 h = (__bf16)x;
    if (hl) h = (__bf16)(x - (float)h);
    v[j] = __builtin_bit_cast(unsigned short, h);
  }
  Wp[f] = v;
}

__global__ void pack_all_kernel(const float* __restrict__ W1, ushort8* __restrict__ P1,
                                const float* __restrict__ W3, ushort8* __restrict__ P3,
                                const float* __restrict__ Wm1, ushort8* __restrict__ PM1,
                                const float* __restrict__ Wm2, ushort8* __restrict__ PM2) {
  int f = blockIdx.x * 256 + threadIdx.x;
  if (f < 12288) pack_one(W1, P1, f, 8, 384);
  else if (f < 24576) pack_one(W3, P3, f - 12288, 8, 384);
  else if (f < 28672) pack_one(Wm1, PM1, f - 24576, 8, 128);
  else if (f < 30720) pack_one(Wm2, PM2, f - 28672, 4, 128);
}

// ================= GEMM machinery =================
// 512 thr = 8 waves (wm{0,1} x wn{0..3}); tile 64 rows x NC; A staged via global_load_lds
// from pre-swizzled split-bf16 global rows (32 KB/part), double-buffered, counted vmcnt.
// B register-double-buffered at half-phase (2-kunit) granularity.

__device__ __forceinline__ void stage_sp(const unsigned short* gsrc, float4* lbuf, int tid) {
  const char* g = (const char*)gsrc;
  char* l = (char*)lbuf;
#pragma unroll
  for (int k = 0; k < 4; ++k) {
    int off = k * 8192 + tid * 16;
    __builtin_amdgcn_global_load_lds(
        (const __attribute__((address_space(1))) void*)(g + off),
        (__attribute__((address_space(3))) void*)(l + off), 16, 0, 0);
  }
}

__device__ __forceinline__ void lds_put_split(unsigned short* L, int row, int col, float v) {
  __bf16 hh = (__bf16)v;
  __bf16 ll = (__bf16)(v - (float)hh);
  int base = row * 256 + (((col >> 3) ^ (row & 15)) << 3) + (col & 7);
  L[base] = __builtin_bit_cast(unsigned short, hh);
  L[base + 128] = __builtin_bit_cast(unsigned short, ll);
}

// B chunk: 2 kunits x NT2=2 n-tiles x (hi,lo) = 8 frags = 32 VGPR
struct Bchunk {
  ushort8 h[2][2];
  ushort8 l[2][2];
};

__device__ __forceinline__ void loadB(const ushort8* __restrict__ Wp, int kunit0,
                                      int lane, int wn, Bchunk& c) {
#pragma unroll
  for (int k2 = 0; k2 < 2; ++k2) {
#pragma unroll
    for (int j = 0; j < 2; ++j) {
      const ushort8* bp = Wp + (size_t)((kunit0 + k2) * 8 + wn * 2 + j) * 128 + lane;
      c.h[k2][j] = bp[0];
      c.l[k2][j] = bp[64];
    }
  }
}

// MFMA one B-chunk: 2 kunits x 2 mt x 2 j x 3 split-terms = 24 MFMAs
__device__ __forceinline__ void mfma_chunk(const float4* B4, const Bchunk& c, int kbase,
                                           int lane, int wm, f32x4 (*acc)[2]) {
#pragma unroll
  for (int k2 = 0; k2 < 2; ++k2) {
    int kunit = kbase + k2;
    bf16x8 ah[2], al[2];
#pragma unroll
    for (int mt = 0; mt < 2; ++mt) {
      int arow = wm * 32 + mt * 16 + (lane & 15);
      int fc = (kunit & 3) * 4 + (lane >> 4);
      int idx = arow * 32 + (fc ^ (arow & 15));
      ah[mt] = __builtin_bit_cast(bf16x8, B4[idx]);
      al[mt] = __builtin_bit_cast(bf16x8, B4[idx + 16]);
    }
#pragma unroll
    for (int j = 0; j < 2; ++j) {
      bf16x8 bh = __builtin_bit_cast(bf16x8, c.h[k2][j]);
      bf16x8 bl = __builtin_bit_cast(bf16x8, c.l[k2][j]);
#pragma unroll
      for (int mt = 0; mt < 2; ++mt) {
        acc[mt][j] = __builtin_amdgcn_mfma_f32_16x16x32_bf16(ah[mt], bh, acc[mt][j], 0, 0, 0);
        acc[mt][j] = __builtin_amdgcn_mfma_f32_16x16x32_bf16(ah[mt], bl, acc[mt][j], 0, 0, 0);
        acc[mt][j] = __builtin_amdgcn_mfma_f32_16x16x32_bf16(al[mt], bh, acc[mt][j], 0, 0, 0);
      }
    }
  }
}

// generic gemm_step for the small MLP phases (B compiler-managed)
template<int NT, int NT2>
__device__ __forceinline__ void gemm_step512(const float4* B4, const ushort8* __restrict__ Wp,
                                             int kunit, int lane, int wm, int wn,
                                             f32x4 (*acc)[NT2]) {
  bf16x8 ah[2], al[2];
#pragma unroll
  for (int mt = 0; mt < 2; ++mt) {
    int arow = wm * 32 + mt * 16 + (lane & 15);
    int fc = (kunit & 3) * 4 + (lane >> 4);
    int idx = arow * 32 + (fc ^ (arow & 15));
    ah[mt] = __builtin_bit_cast(bf16x8, B4[idx]);
    al[mt] = __builtin_bit_cast(bf16x8, B4[idx + 16]);
  }
#pragma unroll
  for (int j = 0; j < NT2; ++j) {
    int nt = wn * NT2 + j;
    const ushort8* bp = Wp + (size_t)(kunit * NT + nt) * 2 * 64 + lane;
    bf16x8 bh = __builtin_bit_cast(bf16x8, bp[0]);
    bf16x8 bl = __builtin_bit_cast(bf16x8, bp[64]);
#pragma unroll
    for (int mt = 0; mt < 2; ++mt) {
      acc[mt][j] = __builtin_amdgcn_mfma_f32_16x16x32_bf16(ah[mt], bh, acc[mt][j], 0, 0, 0);
      acc[mt][j] = __builtin_amdgcn_mfma_f32_16x16x32_bf16(ah[mt], bl, acc[mt][j], 0, 0, 0);
      acc[mt][j] = __builtin_amdgcn_mfma_f32_16x16x32_bf16(al[mt], bh, acc[mt][j], 0, 0, 0);
    }
  }
}

// 3-part pipelined K-loop: A via gload_lds dbuf (counted vmcnt), B via register dbuf chunks
__device__ __forceinline__ void gemm3_pipeline(const unsigned short* A0, const unsigned short* A1,
                                               const unsigned short* A2, const ushort8* Wp,
                                               float4 (*buf)[2048], size_t r0,
                                               int tid, int lane, int wm, int wn,
                                               f32x4 (*acc)[2]) {
  const unsigned short* Aarr[3] = {A0, A1, A2};
  stage_sp(A0 + r0 * 256, buf[0], tid);
  Bchunk bc0, bc1;
#pragma unroll
  for (int p = 0; p < 3; ++p) {
    loadB(Wp, p * 4, lane, wn, bc0);          // oldest-after-A[p]: stays in flight past wait
    if (p + 1 < 3) {
      stage_sp(Aarr[p + 1] + r0 * 256, buf[(p + 1) & 1], tid);
      asm volatile("s_waitcnt vmcnt(12)" ::: "memory");   // A[p] done; bc0+A[p+1] in flight
    } else {
      asm volatile("s_waitcnt vmcnt(8)" ::: "memory");    // A[2] done; bc0 in flight
    }
    __builtin_amdgcn_s_barrier();
    __builtin_amdgcn_sched_barrier(0);
    loadB(Wp, p * 4 + 2, lane, wn, bc1);      // next chunk flies during bc0's MFMAs
    mfma_chunk(buf[p & 1], bc0, p * 4, lane, wm, acc);
    mfma_chunk(buf[p & 1], bc1, p * 4 + 2, lane, wm, acc);
    __builtin_amdgcn_sched_barrier(0);
    __builtin_amdgcn_s_barrier();
  }
}

// ---------------- conv1 GEMM + fused BN partial stats ----------------
__global__ __launch_bounds__(512, 4) void conv1_gemm_kernel(
    const unsigned short* __restrict__ A0, const unsigned short* __restrict__ A1,
    const unsigned short* __restrict__ A2,
    const ushort8* __restrict__ Wp, const float* __restrict__ bias,
    float* __restrict__ out, float* __restrict__ stats, int n) {
  __shared__ float4 buf[2][2048];   // 64 KB
  __shared__ float sstat[256];

  int tid = threadIdx.x;
  int lane = tid & 63, wid = tid >> 6;
  int wm = wid >> 2, wn = wid & 3;
  size_t r0 = (size_t)blockIdx.x * 64;

  f32x4 acc[2][2];
#pragma unroll
  for (int mt = 0; mt < 2; ++mt)
#pragma unroll
    for (int j = 0; j < 2; ++j) acc[mt][j] = (f32x4)0.f;

  gemm3_pipeline(A0, A1, A2, Wp, buf, r0, tid, lane, wm, wn, acc);

  // epilogue: relu + store + BN partial stats
  if (tid < 256) sstat[tid] = 0.f;
  __syncthreads();
#pragma unroll
  for (int mt = 0; mt < 2; ++mt) {
    int rbase = (int)r0 + wm * 32 + mt * 16 + (lane >> 4) * 4;
#pragma unroll
    for (int j = 0; j < 2; ++j) {
      int col = wn * 32 + j * 16 + (lane & 15);
      float b = bias[col];
      float sj = 0.f, qj = 0.f;
#pragma unroll
      for (int i = 0; i < 4; ++i) {
        int row = rbase + i;
        if (row < n) {
          float v = fmaxf(acc[mt][j][i] + b, 0.f);
          out[(size_t)row * NF + col] = v;
          sj += v; qj += v * v;
        }
      }
      sj += __shfl_xor(sj, 16); sj += __shfl_xor(sj, 32);
      qj += __shfl_xor(qj, 16); qj += __shfl_xor(qj, 32);
      if ((lane >> 4) == 0) {
        atomicAdd(&sstat[col], sj);
        atomicAdd(&sstat[128 + col], qj);
      }
    }
  }
  __syncthreads();
  if (tid < 256) atomicAdd(&stats[tid], sstat[tid]);
}

// ---------------- fused tail: conv2 GEMM + residual -> MLP1 -> MLP2 on-chip ----------------
__global__ __launch_bounds__(512, 4) void fused_tail_kernel(
    const unsigned short* __restrict__ Xsp, const unsigned short* __restrict__ T1sp,
    const unsigned short* __restrict__ T2sp, const float* __restrict__ X,
    const ushort8* __restrict__ Wp3, const float* __restrict__ b3,
    const ushort8* __restrict__ WpM1, const float* __restrict__ bm1,
    const ushort8* __restrict__ WpM2, const float* __restrict__ bm2,
    float* __restrict__ out, int n) {
  __shared__ float4 buf[2][2048];
  unsigned short* L = (unsigned short*)buf[0];

  int tid = threadIdx.x;
  int lane = tid & 63, wid = tid >> 6;
  int wm = wid >> 2, wn = wid & 3;
  size_t r0 = (size_t)blockIdx.x * 64;

  f32x4 acc[2][2];
#pragma unroll
  for (int mt = 0; mt < 2; ++mt)
#pragma unroll
    for (int j = 0; j < 2; ++j) acc[mt][j] = (f32x4)0.f;

  // ---- phase 1: conv2 GEMM over {Xsp, T1sp, T2sp}
  gemm3_pipeline(Xsp, T1sp, T2sp, Wp3, buf, r0, tid, lane, wm, wn, acc);

  // ---- epilogue 1: Y = relu(acc+b3)+X -> split into LDS (buf[0], packed layout)
#pragma unroll
  for (int mt = 0; mt < 2; ++mt) {
    int rb = wm * 32 + mt * 16 + (lane >> 4) * 4;
#pragma unroll
    for (int j = 0; j < 2; ++j) {
      int col = wn * 32 + j * 16 + (lane & 15);
      float b = b3[col];
#pragma unroll
      for (int i = 0; i < 4; ++i) {
        int lrow = rb + i;
        int row = (int)r0 + lrow;
        float v = 0.f;
        if (row < n) v = fmaxf(acc[mt][j][i] + b, 0.f) + X[(size_t)row * NF + col];
        lds_put_split(L, lrow, col, v);
      }
    }
  }
  __syncthreads();
  // ---- phase 2: H = relu(Y @ Wm1^T + bm1)
  f32x4 acc2[2][2];
#pragma unroll
  for (int mt = 0; mt < 2; ++mt)
#pragma unroll
    for (int j = 0; j < 2; ++j) acc2[mt][j] = (f32x4)0.f;
#pragma unroll
  for (int ks = 0; ks < 4; ++ks)
    gemm_step512<8, 2>(buf[0], WpM1, ks, lane, wm, wn, acc2);
  __syncthreads();   // all reads of Y done before overwrite
  // ---- epilogue 2: scatter H into LDS
#pragma unroll
  for (int mt = 0; mt < 2; ++mt) {
    int rb = wm * 32 + mt * 16 + (lane >> 4) * 4;
#pragma unroll
    for (int j = 0; j < 2; ++j) {
      int col = wn * 32 + j * 16 + (lane & 15);
      float b = bm1[col];
#pragma unroll
      for (int i = 0; i < 4; ++i) {
        float v = fmaxf(acc2[mt][j][i] + b, 0.f);
        lds_put_split(L, rb + i, col, v);
      }
    }
  }
  __syncthreads();
  // ---- phase 3: out = H @ Wm2^T + bm2   (NC=64: NT=4, NT2=1)
  f32x4 acc3[2][1];
#pragma unroll
  for (int mt = 0; mt < 2; ++mt) acc3[mt][0] = (f32x4)0.f;
#pragma unroll
  for (int ks = 0; ks < 4; ++ks)
    gemm_step512<4, 1>(buf[0], WpM2, ks, lane, wm, wn, acc3);
#pragma unroll
  for (int mt = 0; mt < 2; ++mt) {
    int rb = wm * 32 + mt * 16 + (lane >> 4) * 4;
    int col = wn * 16 + (lane & 15);
    float b = bm2[col];
#pragma unroll
    for (int i = 0; i < 4; ++i) {
      int row = (int)r0 + rb + i;
      if (row < n) out[(size_t)row * 64 + col] = acc3[mt][0][i] + b;
    }
  }
}

// ---------------- BatchNorm apply (scale/shift computed inline from stats) ----------------
// In place on X + emit Xsp (swz-split) + xs16 = fp16(X*dinv)
__global__ void bn_apply_kernel(float* __restrict__ x, const float* __restrict__ stats,
                                const float* __restrict__ gamma, const float* __restrict__ beta,
                                const float* __restrict__ dinv,
                                unsigned short* __restrict__ Xsp, _Float16* __restrict__ xs16,
                                float fn, int n) {
  int i = blockIdx.x * 256 + threadIdx.x;   // frag index
  if (i >= n * 16) return;
  int row = i >> 4, fc = i & 15;
  float4* xp = (float4*)(x + (size_t)row * NF + fc * 8);
  float4 a = xp[0], b = xp[1];
  float xv[8] = {a.x, a.y, a.z, a.w, b.x, b.y, b.z, b.w};
  int c0 = fc * 8;
#pragma unroll
  for (int j = 0; j < 8; ++j) {
    int c = c0 + j;
    float mu = stats[c] / fn;
    float var = stats[NF + c] / fn - mu * mu;
    float s = gamma[c] * rsqrtf(var + 1e-5f);
    xv[j] = (xv[j] - mu) * s + beta[c];
  }
  float4 o0, o1;
  o0.x = xv[0]; o0.y = xv[1]; o0.z = xv[2]; o0.w = xv[3];
  o1.x = xv[4]; o1.y = xv[5]; o1.z = xv[6]; o1.w = xv[7];
  xp[0] = o0; xp[1] = o1;
  float d = dinv[row];
  half8 h;
#pragma unroll
  for (int j = 0; j < 8; ++j) h[j] = (_Float16)(xv[j] * d);
  *(half8*)(xs16 + (size_t)row * NF + fc * 8) = h;
  ushort8 hi, lo;
  split8(xv, hi, lo);
  int swz = (fc ^ (row & 15)) * 8;
  *(ushort8*)(Xsp + (size_t)row * 256 + swz) = hi;
  *(ushort8*)(Xsp + (size_t)row * 256 + 128 + swz) = lo;
}

// ---------------- launcher ----------------
extern "C" void kernel_launch(void* const* d_in, const int* in_sizes, int n_in,
                              void* d_out, int out_size, void* d_ws, size_t ws_size,
                              hipStream_t stream) {
  const float* feat  = (const float*)d_in[0];
  const int*   src   = (const int*)d_in[1];
  const int*   dst   = (const int*)d_in[2];
  const float* W1    = (const float*)d_in[3];
  const float* b1    = (const float*)d_in[4];
  const float* W3    = (const float*)d_in[5];
  const float* b3    = (const float*)d_in[6];
  const float* gamma = (const float*)d_in[7];
  const float* beta  = (const float*)d_in[8];
  const float* Wm1   = (const float*)d_in[9];
  const float* bm1   = (const float*)d_in[10];
  const float* Wm2   = (const float*)d_in[11];
  const float* bm2   = (const float*)d_in[12];
  int n = in_sizes[0] / NF;
  int e = in_sizes[1];

  char* p = (char*)d_ws;
  auto alloc = [&](size_t bytes) {
    char* r = p;
    p += (bytes + 255) & ~size_t(255);
    return r;
  };
  int nblk  = ceil_div(e, 4096);   // multisplit tiles
  int nbuck = ceil_div(n, 256);    // node buckets

  float* dinv     = (float*)alloc((size_t)n * 4);
  int*   offsets  = (int*)alloc((size_t)(n + 1) * 4);
  int*   counts   = (int*)alloc((size_t)nblk * nbuck * 4);
  int*   btot     = (int*)alloc((size_t)nbuck * 4);
  int*   bbase    = (int*)alloc((size_t)(nbuck + 1) * 4);
  int*   csr      = (int*)alloc((size_t)e * 4);
  float* stats    = (float*)alloc(256 * 4);
  ushort8* Wp1  = (ushort8*)alloc(12 * 8 * 2 * 64 * 16);   // K=384, NT=8
  ushort8* Wp3  = (ushort8*)alloc(12 * 8 * 2 * 64 * 16);
  ushort8* WpM1 = (ushort8*)alloc(4 * 8 * 2 * 64 * 16);    // K=128, NT=8
  ushort8* WpM2 = (ushort8*)alloc(4 * 4 * 2 * 64 * 16);    // K=128, NT=4
  size_t spb = (size_t)(n + 64) * 512;        // swz-split rows, 64 pad rows for gload_lds
  unsigned short* Fsp  = (unsigned short*)alloc(spb);
  unsigned short* T1sp = (unsigned short*)alloc(spb);
  unsigned short* T2sp = (unsigned short*)alloc(spb);
  unsigned short* Xsp  = (unsigned short*)alloc(spb);
  float* X = (float*)alloc((size_t)n * NF * 4);           // conv1 out -> BN in place -> x_res
  _Float16* xsA = (_Float16*)alloc((size_t)n * NF * 2);   // fp16 scaled gather sources
  _Float16* xsB = (_Float16*)alloc((size_t)n * NF * 2);
  int2* binned = (int2*)Fsp;   // alias: 6.4 MB scratch, dead before prep_feat writes Fsp

  hipMemsetAsync(stats, 0, 256 * 4, stream);

  int fb = ceil_div(n * 16, 256);            // frag-grid over matrices
  int sb = ceil_div(n, 4);                   // spmv: 4 nodes/block
  int gb = ceil_div(n, 64);                  // gemm: 64 rows/block, 512 threads

  // CSR build (sorted by dst) via two-level multisplit; also emits offsets/dinv
  bucket_hist_kernel<<<nblk, 256, 0, stream>>>(dst, counts, e, nblk, nbuck);
  bucket_scan_rows_kernel<<<nbuck, 256, 0, stream>>>(counts, btot, nblk);
  bucket_base_kernel<<<1, 256, 0, stream>>>(btot, bbase, nbuck, e);
  bucket_bin_kernel<<<nblk, 256, 0, stream>>>(src, dst, counts, bbase, binned, e, nblk, nbuck);
  bucket_finalize_kernel<<<nbuck, 256, 0, stream>>>(binned, bbase, offsets, csr, dinv, n, e, nbuck);

  // W split+pack
  pack_all_kernel<<<120, 256, 0, stream>>>(W1, Wp1, W3, Wp3, Wm1, WpM1, Wm2, WpM2);

  // conv1: T1 = -A^ F ; T2 = -2 A^ T1 - F ; X = relu([F,T1,T2] @ W1^T + b1)  (+BN stats)
  prep_feat_kernel<<<fb, 256, 0, stream>>>(feat, dinv, Fsp, xsA, n);
  spmv_kernel<<<sb, 256, 0, stream>>>(xsA, dinv, offsets, csr, nullptr, -1.f, 0.f, T1sp, xsB, n);
  spmv_kernel<<<sb, 256, 0, stream>>>(xsB, dinv, offsets, csr, feat, -2.f, -1.f, T2sp, nullptr, n);
  conv1_gemm_kernel<<<gb, 512, 0, stream>>>(Fsp, T1sp, T2sp, Wp1, b1, X, stats, n);

  // BatchNorm apply (inline scale/shift from stats); emits Xsp + xsA = fp16(X*dinv)
  bn_apply_kernel<<<fb, 256, 0, stream>>>(X, stats, gamma, beta, dinv, Xsp, xsA, (float)n, n);

  // conv2 spmvs
  spmv_kernel<<<sb, 256, 0, stream>>>(xsA, dinv, offsets, csr, nullptr, -1.f, 0.f, T1sp, xsB, n);
  spmv_kernel<<<sb, 256, 0, stream>>>(xsB, dinv, offsets, csr, X, -2.f, -1.f, T2sp, nullptr, n);

  // fused conv2-GEMM + residual + MLP1 + MLP2 (Y, H stay on-chip)
  fused_tail_kernel<<<gb, 512, 0, stream>>>(Xsp, T1sp, T2sp, X, Wp3, b3, WpM1, bm1, WpM2, bm2,
                                            (float*)d_out, n);
}

// Round 14
// 271.672 us; speedup vs baseline: 1.2506x; 1.0944x over previous
//
#include <hip/hip_runtime.h>
#include <hip/hip_bf16.h>
#include <math.h>

#define NF 128   // IN_F == HID == 128

typedef unsigned short ushort8 __attribute__((ext_vector_type(8)));
typedef float f32x4 __attribute__((ext_vector_type(4)));
typedef _Float16 half8 __attribute__((ext_vector_type(8)));

static inline int ceil_div(int a, int b) { return (a + b - 1) / b; }

// ================= CSR build: two-level multisplit counting sort =================
__global__ __launch_bounds__(256) void bucket_hist_kernel(const int* __restrict__ dst,
                                                          int* __restrict__ counts,
                                                          int e, int nblk, int nbuck) {
  __shared__ int h[256];
  int t = threadIdx.x, blk = blockIdx.x;
  h[t] = 0;
  __syncthreads();
  int base = blk * 4096;
#pragma unroll
  for (int k = 0; k < 16; ++k) {
    int i = base + k * 256 + t;
    if (i < e) atomicAdd(&h[dst[i] >> 8], 1);
  }
  __syncthreads();
  for (int b = t; b < nbuck; b += 256) counts[b * nblk + blk] = h[b];
}

__global__ __launch_bounds__(256) void bucket_scan_rows_kernel(int* __restrict__ counts,
                                                               int* __restrict__ btot,
                                                               int nblk) {
  __shared__ int sh[256];
  int b = blockIdx.x, t = threadIdx.x;
  int* row = counts + (size_t)b * nblk;
  int carry = 0;
  for (int base = 0; base < nblk; base += 256) {
    int v = (base + t < nblk) ? row[base + t] : 0;
    sh[t] = v;
    __syncthreads();
    for (int off = 1; off < 256; off <<= 1) {
      int add = (t >= off) ? sh[t - off] : 0;
      __syncthreads();
      sh[t] += add;
      __syncthreads();
    }
    if (base + t < nblk) row[base + t] = carry + sh[t] - v;
    carry += sh[255];
    __syncthreads();
  }
  if (t == 0) btot[b] = carry;
}

__global__ __launch_bounds__(256) void bucket_base_kernel(const int* __restrict__ btot,
                                                          int* __restrict__ bbase,
                                                          int nbuck, int e) {
  __shared__ int sh[256];
  __shared__ int carry;
  int t = threadIdx.x;
  if (t == 0) carry = 0;
  __syncthreads();
  for (int base = 0; base < nbuck; base += 256) {
    int v = (base + t < nbuck) ? btot[base + t] : 0;
    sh[t] = v;
    __syncthreads();
    for (int off = 1; off < 256; off <<= 1) {
      int add = (t >= off) ? sh[t - off] : 0;
      __syncthreads();
      sh[t] += add;
      __syncthreads();
    }
    if (base + t < nbuck) bbase[base + t] = carry + sh[t] - v;
    __syncthreads();
    if (t == 0) carry += sh[255];
    __syncthreads();
  }
  if (t == 0) bbase[nbuck] = e;
}

__global__ __launch_bounds__(256) void bucket_bin_kernel(const int* __restrict__ src,
                                                         const int* __restrict__ dst,
                                                         const int* __restrict__ counts,
                                                         const int* __restrict__ bbase,
                                                         int2* __restrict__ binned,
                                                         int e, int nblk, int nbuck) {
  __shared__ int cur[256];
  int t = threadIdx.x, blk = blockIdx.x;
  for (int b = t; b < nbuck; b += 256) cur[b] = counts[b * nblk + blk] + bbase[b];
  __syncthreads();
  int base = blk * 4096;
#pragma unroll
  for (int k = 0; k < 16; ++k) {
    int i = base + k * 256 + t;
    if (i < e) {
      int d = dst[i];
      int pos = atomicAdd(&cur[d >> 8], 1);
      binned[pos] = make_int2(src[i], d);
    }
  }
}

__global__ __launch_bounds__(256) void bucket_finalize_kernel(const int2* __restrict__ binned,
                                                              const int* __restrict__ bbase,
                                                              int* __restrict__ offsets,
                                                              int* __restrict__ csr,
                                                              float* __restrict__ dinv,
                                                              float* __restrict__ dsq,
                                                              int n, int e, int nbuck) {
  __shared__ int deg[256];
  __shared__ int offs[256];
  __shared__ int cur[256];
  int b = blockIdx.x, t = threadIdx.x;
  int ebeg = bbase[b];
  int eend = bbase[b + 1];
  deg[t] = 0;
  __syncthreads();
  for (int j = ebeg + t; j < eend; j += 256) atomicAdd(&deg[binned[j].y & 255], 1);
  __syncthreads();
  int v = deg[t];
  offs[t] = v;
  __syncthreads();
  for (int off = 1; off < 256; off <<= 1) {
    int add = (t >= off) ? offs[t - off] : 0;
    __syncthreads();
    offs[t] += add;
    __syncthreads();
  }
  int excl = offs[t] - v;
  cur[t] = excl;
  int node = b * 256 + t;
  if (node < n) {
    offsets[node] = ebeg + excl;
    float d = (float)(v > 1 ? v : 1);
    dinv[node] = rsqrtf(d);
    dsq[node] = sqrtf(d);
  }
  if (b == nbuck - 1 && t == 0) offsets[n] = e;
  __syncthreads();
  for (int j = ebeg + t; j < eend; j += 256) {
    int2 pr = binned[j];
    int pos = atomicAdd(&cur[pr.y & 255], 1);
    csr[ebeg + pos] = pr.x;
  }
}

// ============== swz-f16 row layout (256 B): 16 frags of 8 f16, frag slot fc^(row&15) ========

// ---------------- prep_feat: emits Fsp (swz f16) + xsA = fp16(feat*dinv) ----------------
__global__ void prep_feat_kernel(const float* __restrict__ feat, const float* __restrict__ dinv,
                                 _Float16* __restrict__ Fsp, _Float16* __restrict__ xs,
                                 int n) {
  int i = blockIdx.x * 256 + threadIdx.x;   // frag index
  if (i >= n * 16) return;
  int row = i >> 4, fc = i & 15;
  const float4* s = (const float4*)(feat + (size_t)row * NF + fc * 8);
  float4 a = s[0], b = s[1];
  float xv[8] = {a.x, a.y, a.z, a.w, b.x, b.y, b.z, b.w};
  float d = dinv[row];
  half8 h, f;
#pragma unroll
  for (int j = 0; j < 8; ++j) { h[j] = (_Float16)(xv[j] * d); f[j] = (_Float16)xv[j]; }
  *(half8*)(xs + (size_t)row * NF + fc * 8) = h;
  int swz = (fc ^ (row & 15)) * 8;
  *(half8*)(Fsp + (size_t)row * 128 + swz) = f;
}

// ---------------- SpMV: gathers fp16 pre-scaled; emits swz-f16 out (+ optional fp16 scaled) --
// z-term reconstructed from zs16 (fp16, z*dinv) * dsq[node].
__global__ __launch_bounds__(256) void spmv_kernel(
    const _Float16* __restrict__ xs16, const float* __restrict__ dinv,
    const int* __restrict__ offsets, const int* __restrict__ csr,
    const _Float16* __restrict__ zs16, const float* __restrict__ dsq, float a, float bz,
    _Float16* __restrict__ outsp, _Float16* __restrict__ outs16, int n) {
  int w = threadIdx.x >> 6, lane = threadIdx.x & 63;
  int node = blockIdx.x * 4 + w;
  if (node >= n) return;
  int beg = __builtin_amdgcn_readfirstlane(offsets[node]);
  int end = __builtin_amdgcn_readfirstlane(offsets[node + 1]);
  int eh = lane >> 4;        // which edge of the quad (0..3)
  int cq = lane & 15;        // half8 frag within the 128-half row

  float acc[8];
#pragma unroll
  for (int j = 0; j < 8; ++j) acc[j] = 0.f;

  int e2 = beg;
  for (; e2 + 8 <= end; e2 += 8) {
    int s0 = csr[e2 + eh];
    int s1 = csr[e2 + 4 + eh];
    half8 g0 = ((const half8*)(xs16 + (size_t)s0 * NF))[cq];
    half8 g1 = ((const half8*)(xs16 + (size_t)s1 * NF))[cq];
#pragma unroll
    for (int j = 0; j < 8; ++j) acc[j] += (float)g0[j];
#pragma unroll
    for (int j = 0; j < 8; ++j) acc[j] += (float)g1[j];
  }
  for (; e2 + 4 <= end; e2 += 4) {
    int s0 = csr[e2 + eh];
    half8 g0 = ((const half8*)(xs16 + (size_t)s0 * NF))[cq];
#pragma unroll
    for (int j = 0; j < 8; ++j) acc[j] += (float)g0[j];
  }
  int rem = end - e2;
  if (eh < rem) {
    int s0 = csr[e2 + eh];
    half8 g0 = ((const half8*)(xs16 + (size_t)s0 * NF))[cq];
#pragma unroll
    for (int j = 0; j < 8; ++j) acc[j] += (float)g0[j];
  }
#pragma unroll
  for (int j = 0; j < 8; ++j) {
    acc[j] += __shfl_xor(acc[j], 16);
    acc[j] += __shfl_xor(acc[j], 32);
  }
  if (eh == 0) {
    float dv = dinv[node];
    float v[8];
#pragma unroll
    for (int j = 0; j < 8; ++j) v[j] = a * dv * acc[j];
    if (zs16) {
      float zf = bz * dsq[node];
      half8 zz = ((const half8*)(zs16 + (size_t)node * NF))[cq];
#pragma unroll
      for (int j = 0; j < 8; ++j) v[j] += zf * (float)zz[j];
    }
    half8 ho, hs;
#pragma unroll
    for (int j = 0; j < 8; ++j) { ho[j] = (_Float16)v[j]; hs[j] = (_Float16)(v[j] * dv); }
    int swz = (cq ^ (node & 15)) * 8;
    *(half8*)(outsp + (size_t)node * 128 + swz) = ho;
    if (outs16) *(half8*)(outs16 + (size_t)node * NF + cq * 8) = hs;
  }
}

// ---------------- W pre-split (f16 hi/lo) + frag-pack ----------------
__device__ __forceinline__ void pack_one(const float* __restrict__ W, ushort8* __restrict__ Wp,
                                         int f, int NT, int K) {
  int lane = f & 63;
  int hl = (f >> 6) & 1;
  int rest = f >> 7;
  int nt = rest % NT;
  int kunit = rest / NT;
  int nrow = nt * 16 + (lane & 15);
  int k0 = kunit * 32 + (lane >> 4) * 8;
  const float* srcp = W + (size_t)nrow * K + k0;
  ushort8 v;
#pragma unroll
  for (int j = 0; j < 8; ++j) {
    float x = srcp[j];
    _Float16 h = (_Float16)x;
    if (hl) h = (_Float16)(x - (float)h);
    v[j] = __builtin_bit_cast(unsigned short, h);
  }
  Wp[f] = v;
}

__global__ void pack_all_kernel(const float* __restrict__ W1, ushort8* __restrict__ P1,
                                const float* __restrict__ W3, ushort8* __restrict__ P3,
                                const float* __restrict__ Wm1, ushort8* __restrict__ PM1,
                                const float* __restrict__ Wm2, ushort8* __restrict__ PM2) {
  int f = blockIdx.x * 256 + threadIdx.x;
  if (f < 12288) pack_one(W1, P1, f, 8, 384);
  else if (f < 24576) pack_one(W3, P3, f - 12288, 8, 384);
  else if (f < 28672) pack_one(Wm1, PM1, f - 24576, 8, 128);
  else if (f < 30720) pack_one(Wm2, PM2, f - 28672, 4, 128);
}

// ================= GEMM machinery (f16 A single, f16 W hi+lo) =================
// 512 thr = 8 waves (wm{0,1} x wn{0..3}); tile 64 rows x NC; A staged via global_load_lds
// from pre-swizzled f16 rows (16 KB/part), double-buffered, counted vmcnt.
// Row in LDS: 16 float4 (= 16 frags of 8 f16), frag slot fc^(row&15).

__device__ __forceinline__ void stage_sp(const _Float16* gsrc, float4* lbuf, int tid) {
  const char* g = (const char*)gsrc;
  char* l = (char*)lbuf;
#pragma unroll
  for (int k = 0; k < 2; ++k) {
    int off = k * 8192 + tid * 16;
    __builtin_amdgcn_global_load_lds(
        (const __attribute__((address_space(1))) void*)(g + off),
        (__attribute__((address_space(3))) void*)(l + off), 16, 0, 0);
  }
}

__device__ __forceinline__ void lds_put16(_Float16* L, int row, int col, float v) {
  L[row * 128 + (((col >> 3) ^ (row & 15)) << 3) + (col & 7)] = (_Float16)v;
}

// B chunk: 2 kunits x NT2=2 n-tiles x (hi,lo) = 8 frags = 32 VGPR
struct Bchunk {
  ushort8 h[2][2];
  ushort8 l[2][2];
};

__device__ __forceinline__ void loadB(const ushort8* __restrict__ Wp, int kunit0,
                                      int lane, int wn, Bchunk& c) {
#pragma unroll
  for (int k2 = 0; k2 < 2; ++k2) {
#pragma unroll
    for (int j = 0; j < 2; ++j) {
      const ushort8* bp = Wp + (size_t)((kunit0 + k2) * 8 + wn * 2 + j) * 128 + lane;
      c.h[k2][j] = bp[0];
      c.l[k2][j] = bp[64];
    }
  }
}

// MFMA one B-chunk: 2 kunits x 2 mt x 2 j x 2 terms = 16 MFMAs
__device__ __forceinline__ void mfma_chunk(const float4* A4, const Bchunk& c, int kbase,
                                           int lane, int wm, f32x4 (*acc)[2]) {
#pragma unroll
  for (int k2 = 0; k2 < 2; ++k2) {
    int kunit = kbase + k2;
    half8 a[2];
#pragma unroll
    for (int mt = 0; mt < 2; ++mt) {
      int arow = wm * 32 + mt * 16 + (lane & 15);
      int fc = (kunit & 3) * 4 + (lane >> 4);
      a[mt] = __builtin_bit_cast(half8, A4[arow * 16 + (fc ^ (arow & 15))]);
    }
#pragma unroll
    for (int j = 0; j < 2; ++j) {
      half8 bh = __builtin_bit_cast(half8, c.h[k2][j]);
      half8 bl = __builtin_bit_cast(half8, c.l[k2][j]);
#pragma unroll
      for (int mt = 0; mt < 2; ++mt) {
        acc[mt][j] = __builtin_amdgcn_mfma_f32_16x16x32_f16(a[mt], bh, acc[mt][j], 0, 0, 0);
        acc[mt][j] = __builtin_amdgcn_mfma_f32_16x16x32_f16(a[mt], bl, acc[mt][j], 0, 0, 0);
      }
    }
  }
}

// generic gemm_step for the MLP phases (A = f16 LDS tile, B compiler-managed)
template<int NT, int NT2>
__device__ __forceinline__ void gemm_step16(const float4* A4, const ushort8* __restrict__ Wp,
                                            int kunit, int lane, int wm, int wn,
                                            f32x4 (*acc)[NT2]) {
  half8 a[2];
#pragma unroll
  for (int mt = 0; mt < 2; ++mt) {
    int arow = wm * 32 + mt * 16 + (lane & 15);
    int fc = (kunit & 3) * 4 + (lane >> 4);
    a[mt] = __builtin_bit_cast(half8, A4[arow * 16 + (fc ^ (arow & 15))]);
  }
#pragma unroll
  for (int j = 0; j < NT2; ++j) {
    int nt = wn * NT2 + j;
    const ushort8* bp = Wp + (size_t)(kunit * NT + nt) * 2 * 64 + lane;
    half8 bh = __builtin_bit_cast(half8, bp[0]);
    half8 bl = __builtin_bit_cast(half8, bp[64]);
#pragma unroll
    for (int mt = 0; mt < 2; ++mt) {
      acc[mt][j] = __builtin_amdgcn_mfma_f32_16x16x32_f16(a[mt], bh, acc[mt][j], 0, 0, 0);
      acc[mt][j] = __builtin_amdgcn_mfma_f32_16x16x32_f16(a[mt], bl, acc[mt][j], 0, 0, 0);
    }
  }
}

// 3-part pipelined K-loop: A via gload_lds dbuf (counted vmcnt), B via register dbuf chunks
__device__ __forceinline__ void gemm3_pipeline(const _Float16* A0, const _Float16* A1,
                                               const _Float16* A2, const ushort8* Wp,
                                               float4 (*buf)[1024], size_t r0,
                                               int tid, int lane, int wm, int wn,
                                               f32x4 (*acc)[2]) {
  const _Float16* Aarr[3] = {A0, A1, A2};
  stage_sp(A0 + r0 * 128, buf[0], tid);
  Bchunk bc0, bc1;
#pragma unroll
  for (int p = 0; p < 3; ++p) {
    loadB(Wp, p * 4, lane, wn, bc0);          // stays in flight past the wait
    if (p + 1 < 3) {
      stage_sp(Aarr[p + 1] + r0 * 128, buf[(p + 1) & 1], tid);
      asm volatile("s_waitcnt vmcnt(10)" ::: "memory");   // A[p] done; bc0+A[p+1] in flight
    } else {
      asm volatile("s_waitcnt vmcnt(8)" ::: "memory");    // A[2] done; bc0 in flight
    }
    __builtin_amdgcn_s_barrier();
    __builtin_amdgcn_sched_barrier(0);
    loadB(Wp, p * 4 + 2, lane, wn, bc1);      // next chunk flies during bc0's MFMAs
    mfma_chunk(buf[p & 1], bc0, p * 4, lane, wm, acc);
    mfma_chunk(buf[p & 1], bc1, p * 4 + 2, lane, wm, acc);
    __builtin_amdgcn_sched_barrier(0);
    __builtin_amdgcn_s_barrier();
  }
}

// ---------------- conv1 GEMM + fused BN partial stats; writes Xh (f16 linear) ----------------
__global__ __launch_bounds__(512, 4) void conv1_gemm_kernel(
    const _Float16* __restrict__ A0, const _Float16* __restrict__ A1,
    const _Float16* __restrict__ A2,
    const ushort8* __restrict__ Wp, const float* __restrict__ bias,
    _Float16* __restrict__ Xh, float* __restrict__ stats, int n) {
  __shared__ float4 buf[2][1024];   // 32 KB
  __shared__ float sstat[256];

  int tid = threadIdx.x;
  int lane = tid & 63, wid = tid >> 6;
  int wm = wid >> 2, wn = wid & 3;
  size_t r0 = (size_t)blockIdx.x * 64;

  f32x4 acc[2][2];
#pragma unroll
  for (int mt = 0; mt < 2; ++mt)
#pragma unroll
    for (int j = 0; j < 2; ++j) acc[mt][j] = (f32x4)0.f;

  gemm3_pipeline(A0, A1, A2, Wp, buf, r0, tid, lane, wm, wn, acc);

  // epilogue: relu + f16 store + BN partial stats
  if (tid < 256) sstat[tid] = 0.f;
  __syncthreads();
#pragma unroll
  for (int mt = 0; mt < 2; ++mt) {
    int rbase = (int)r0 + wm * 32 + mt * 16 + (lane >> 4) * 4;
#pragma unroll
    for (int j = 0; j < 2; ++j) {
      int col = wn * 32 + j * 16 + (lane & 15);
      float b = bias[col];
      float sj = 0.f, qj = 0.f;
#pragma unroll
      for (int i = 0; i < 4; ++i) {
        int row = rbase + i;
        if (row < n) {
          float v = fmaxf(acc[mt][j][i] + b, 0.f);
          Xh[(size_t)row * NF + col] = (_Float16)v;
          sj += v; qj += v * v;
        }
      }
      sj += __shfl_xor(sj, 16); sj += __shfl_xor(sj, 32);
      qj += __shfl_xor(qj, 16); qj += __shfl_xor(qj, 32);
      if ((lane >> 4) == 0) {
        atomicAdd(&sstat[col], sj);
        atomicAdd(&sstat[128 + col], qj);
      }
    }
  }
  __syncthreads();
  if (tid < 256) atomicAdd(&stats[tid], sstat[tid]);
}

// ---------------- fused tail: conv2 GEMM + residual -> MLP1 -> MLP2 on-chip ----------------
// Residual X reconstructed from xsA (fp16 X*dinv) * dsq[row].
__global__ __launch_bounds__(512, 4) void fused_tail_kernel(
    const _Float16* __restrict__ Xsp, const _Float16* __restrict__ T1sp,
    const _Float16* __restrict__ T2sp,
    const _Float16* __restrict__ xsA, const float* __restrict__ dsq,
    const ushort8* __restrict__ Wp3, const float* __restrict__ b3,
    const ushort8* __restrict__ WpM1, const float* __restrict__ bm1,
    const ushort8* __restrict__ WpM2, const float* __restrict__ bm2,
    float* __restrict__ out, int n) {
  __shared__ float4 buf[2][1024];
  _Float16* L = (_Float16*)buf[0];

  int tid = threadIdx.x;
  int lane = tid & 63, wid = tid >> 6;
  int wm = wid >> 2, wn = wid & 3;
  size_t r0 = (size_t)blockIdx.x * 64;

  f32x4 acc[2][2];
#pragma unroll
  for (int mt = 0; mt < 2; ++mt)
#pragma unroll
    for (int j = 0; j < 2; ++j) acc[mt][j] = (f32x4)0.f;

  // ---- phase 1: conv2 GEMM over {Xsp, T1sp, T2sp}
  gemm3_pipeline(Xsp, T1sp, T2sp, Wp3, buf, r0, tid, lane, wm, wn, acc);

  // ---- epilogue 1: Y = relu(acc+b3) + X -> f16 into LDS (buf[0], swz layout)
#pragma unroll
  for (int mt = 0; mt < 2; ++mt) {
    int rb = wm * 32 + mt * 16 + (lane >> 4) * 4;
#pragma unroll
    for (int j = 0; j < 2; ++j) {
      int col = wn * 32 + j * 16 + (lane & 15);
      float b = b3[col];
#pragma unroll
      for (int i = 0; i < 4; ++i) {
        int lrow = rb + i;
        int row = (int)r0 + lrow;
        float v = 0.f;
        if (row < n) {
          float xres = (float)xsA[(size_t)row * NF + col] * dsq[row];
          v = fmaxf(acc[mt][j][i] + b, 0.f) + xres;
        }
        lds_put16(L, lrow, col, v);
      }
    }
  }
  __syncthreads();
  // ---- phase 2: H = relu(Y @ Wm1^T + bm1)
  f32x4 acc2[2][2];
#pragma unroll
  for (int mt = 0; mt < 2; ++mt)
#pragma unroll
    for (int j = 0; j < 2; ++j) acc2[mt][j] = (f32x4)0.f;
#pragma unroll
  for (int ks = 0; ks < 4; ++ks)
    gemm_step16<8, 2>(buf[0], WpM1, ks, lane, wm, wn, acc2);
  __syncthreads();   // all reads of Y done before overwrite
  // ---- epilogue 2: scatter H (f16) into LDS
#pragma unroll
  for (int mt = 0; mt < 2; ++mt) {
    int rb = wm * 32 + mt * 16 + (lane >> 4) * 4;
#pragma unroll
    for (int j = 0; j < 2; ++j) {
      int col = wn * 32 + j * 16 + (lane & 15);
      float b = bm1[col];
#pragma unroll
      for (int i = 0; i < 4; ++i) {
        float v = fmaxf(acc2[mt][j][i] + b, 0.f);
        lds_put16(L, rb + i, col, v);
      }
    }
  }
  __syncthreads();
  // ---- phase 3: out = H @ Wm2^T + bm2   (NC=64: NT=4, NT2=1)
  f32x4 acc3[2][1];
#pragma unroll
  for (int mt = 0; mt < 2; ++mt) acc3[mt][0] = (f32x4)0.f;
#pragma unroll
  for (int ks = 0; ks < 4; ++ks)
    gemm_step16<4, 1>(buf[0], WpM2, ks, lane, wm, wn, acc3);
#pragma unroll
  for (int mt = 0; mt < 2; ++mt) {
    int rb = wm * 32 + mt * 16 + (lane >> 4) * 4;
    int col = wn * 16 + (lane & 15);
    float b = bm2[col];
#pragma unroll
    for (int i = 0; i < 4; ++i) {
      int row = (int)r0 + rb + i;
      if (row < n) out[(size_t)row * 64 + col] = acc3[mt][0][i] + b;
    }
  }
}

// ---------------- BatchNorm apply: reads Xh f16, emits Xsp (swz f16) + xsA (fp16 scaled) -----
__global__ void bn_apply_kernel(const _Float16* __restrict__ Xh, const float* __restrict__ stats,
                                const float* __restrict__ gamma, const float* __restrict__ beta,
                                const float* __restrict__ dinv,
                                _Float16* __restrict__ Xsp, _Float16* __restrict__ xs16,
                                float fn, int n) {
  int i = blockIdx.x * 256 + threadIdx.x;   // frag index
  if (i >= n * 16) return;
  int row = i >> 4, fc = i & 15;
  half8 xh = *(const half8*)(Xh + (size_t)row * NF + fc * 8);
  float xv[8];
  int c0 = fc * 8;
#pragma unroll
  for (int j = 0; j < 8; ++j) {
    int c = c0 + j;
    float mu = stats[c] / fn;
    float var = stats[NF + c] / fn - mu * mu;
    float s = gamma[c] * rsqrtf(var + 1e-5f);
    xv[j] = ((float)xh[j] - mu) * s + beta[c];
  }
  float d = dinv[row];
  half8 hs, hu;
#pragma unroll
  for (int j = 0; j < 8; ++j) { hs[j] = (_Float16)(xv[j] * d); hu[j] = (_Float16)xv[j]; }
  *(half8*)(xs16 + (size_t)row * NF + fc * 8) = hs;
  int swz = (fc ^ (row & 15)) * 8;
  *(half8*)(Xsp + (size_t)row * 128 + swz) = hu;
}

// ---------------- launcher ----------------
extern "C" void kernel_launch(void* const* d_in, const int* in_sizes, int n_in,
                              void* d_out, int out_size, void* d_ws, size_t ws_size,
                              hipStream_t stream) {
  const float* feat  = (const float*)d_in[0];
  const int*   src   = (const int*)d_in[1];
  const int*   dst   = (const int*)d_in[2];
  const float* W1    = (const float*)d_in[3];
  const float* b1    = (const float*)d_in[4];
  const float* W3    = (const float*)d_in[5];
  const float* b3    = (const float*)d_in[6];
  const float* gamma = (const float*)d_in[7];
  const float* beta  = (const float*)d_in[8];
  const float* Wm1   = (const float*)d_in[9];
  const float* bm1   = (const float*)d_in[10];
  const float* Wm2   = (const float*)d_in[11];
  const float* bm2   = (const float*)d_in[12];
  int n = in_sizes[0] / NF;
  int e = in_sizes[1];

  char* p = (char*)d_ws;
  auto alloc = [&](size_t bytes) {
    char* r = p;
    p += (bytes + 255) & ~size_t(255);
    return r;
  };
  int nblk  = ceil_div(e, 4096);   // multisplit tiles
  int nbuck = ceil_div(n, 256);    // node buckets

  float* dinv     = (float*)alloc((size_t)n * 4);
  float* dsq      = (float*)alloc((size_t)n * 4);
  int*   offsets  = (int*)alloc((size_t)(n + 1) * 4);
  int*   counts   = (int*)alloc((size_t)nblk * nbuck * 4);
  int*   btot     = (int*)alloc((size_t)nbuck * 4);
  int*   bbase    = (int*)alloc((size_t)(nbuck + 1) * 4);
  int*   csr      = (int*)alloc((size_t)e * 4);
  float* stats    = (float*)alloc(256 * 4);
  ushort8* Wp1  = (ushort8*)alloc(12 * 8 * 2 * 64 * 16);   // K=384, NT=8
  ushort8* Wp3  = (ushort8*)alloc(12 * 8 * 2 * 64 * 16);
  ushort8* WpM1 = (ushort8*)alloc(4 * 8 * 2 * 64 * 16);    // K=128, NT=8
  ushort8* WpM2 = (ushort8*)alloc(4 * 4 * 2 * 64 * 16);    // K=128, NT=4
  size_t spb = (size_t)(n + 64) * 256;        // swz f16 rows, 64 pad rows for gload_lds
  _Float16* Fsp  = (_Float16*)alloc(spb);
  _Float16* T1sp = (_Float16*)alloc(spb);
  _Float16* T2sp = (_Float16*)alloc(spb);
  _Float16* Xsp  = (_Float16*)alloc(spb);
  _Float16* Xh   = (_Float16*)alloc((size_t)n * NF * 2);  // conv1 output (pre-BN, f16)
  _Float16* xsA  = (_Float16*)alloc((size_t)n * NF * 2);  // fp16 scaled gather sources
  _Float16* xsB  = (_Float16*)alloc((size_t)n * NF * 2);
  int2* binned = (int2*)Fsp;   // alias: 6.4 MB scratch, dead before prep_feat writes Fsp

  hipMemsetAsync(stats, 0, 256 * 4, stream);

  int fb = ceil_div(n * 16, 256);            // frag-grid over matrices
  int sb = ceil_div(n, 4);                   // spmv: 4 nodes/block
  int gb = ceil_div(n, 64);                  // gemm: 64 rows/block, 512 threads

  // CSR build (sorted by dst) via two-level multisplit; also emits offsets/dinv/dsq
  bucket_hist_kernel<<<nblk, 256, 0, stream>>>(dst, counts, e, nblk, nbuck);
  bucket_scan_rows_kernel<<<nbuck, 256, 0, stream>>>(counts, btot, nblk);
  bucket_base_kernel<<<1, 256, 0, stream>>>(btot, bbase, nbuck, e);
  bucket_bin_kernel<<<nblk, 256, 0, stream>>>(src, dst, counts, bbase, binned, e, nblk, nbuck);
  bucket_finalize_kernel<<<nbuck, 256, 0, stream>>>(binned, bbase, offsets, csr, dinv, dsq, n, e, nbuck);

  // W split+pack (f16 hi/lo)
  pack_all_kernel<<<120, 256, 0, stream>>>(W1, Wp1, W3, Wp3, Wm1, WpM1, Wm2, WpM2);

  // conv1: T1 = -A^ F ; T2 = -2 A^ T1 - F ; Xh = f16(relu([F,T1,T2] @ W1^T + b1))  (+BN stats)
  prep_feat_kernel<<<fb, 256, 0, stream>>>(feat, dinv, Fsp, xsA, n);
  spmv_kernel<<<sb, 256, 0, stream>>>(xsA, dinv, offsets, csr, nullptr, nullptr, -1.f, 0.f, T1sp, xsB, n);
  spmv_kernel<<<sb, 256, 0, stream>>>(xsB, dinv, offsets, csr, xsA, dsq, -2.f, -1.f, T2sp, nullptr, n);
  conv1_gemm_kernel<<<gb, 512, 0, stream>>>(Fsp, T1sp, T2sp, Wp1, b1, Xh, stats, n);

  // BatchNorm apply (inline scale/shift from stats); emits Xsp + xsA = fp16(X*dinv)
  bn_apply_kernel<<<fb, 256, 0, stream>>>(Xh, stats, gamma, beta, dinv, Xsp, xsA, (float)n, n);

  // conv2 spmvs (z-term from xsA * dsq)
  spmv_kernel<<<sb, 256, 0, stream>>>(xsA, dinv, offsets, csr, nullptr, nullptr, -1.f, 0.f, T1sp, xsB, n);
  spmv_kernel<<<sb, 256, 0, stream>>>(xsB, dinv, offsets, csr, xsA, dsq, -2.f, -1.f, T2sp, nullptr, n);

  // fused conv2-GEMM + residual + MLP1 + MLP2 (Y, H stay on-chip)
  fused_tail_kernel<<<gb, 512, 0, stream>>>(Xsp, T1sp, T2sp, xsA, dsq, Wp3, b3, WpM1, bm1,
                                            WpM2, bm2, (float*)d_out, n);
}

// Round 15
// 267.538 us; speedup vs baseline: 1.2699x; 1.0155x over previous
//
#include <hip/hip_runtime.h>
#include <hip/hip_bf16.h>
#include <math.h>

#define NF 128   // IN_F == HID == 128

typedef unsigned short ushort8 __attribute__((ext_vector_type(8)));
typedef float f32x4 __attribute__((ext_vector_type(4)));
typedef _Float16 half8 __attribute__((ext_vector_type(8)));

static inline int ceil_div(int a, int b) { return (a + b - 1) / b; }

// ================= CSR build: two-level multisplit counting sort =================
__global__ __launch_bounds__(256) void bucket_hist_kernel(const int* __restrict__ dst,
                                                          int* __restrict__ counts,
                                                          int e, int nblk, int nbuck) {
  __shared__ int h[256];
  int t = threadIdx.x, blk = blockIdx.x;
  h[t] = 0;
  __syncthreads();
  int base = blk * 4096;
#pragma unroll
  for (int k = 0; k < 16; ++k) {
    int i = base + k * 256 + t;
    if (i < e) atomicAdd(&h[dst[i] >> 8], 1);
  }
  __syncthreads();
  for (int b = t; b < nbuck; b += 256) counts[b * nblk + blk] = h[b];
}

__global__ __launch_bounds__(256) void bucket_scan_rows_kernel(int* __restrict__ counts,
                                                               int* __restrict__ btot,
                                                               int nblk) {
  __shared__ int sh[256];
  int b = blockIdx.x, t = threadIdx.x;
  int* row = counts + (size_t)b * nblk;
  int carry = 0;
  for (int base = 0; base < nblk; base += 256) {
    int v = (base + t < nblk) ? row[base + t] : 0;
    sh[t] = v;
    __syncthreads();
    for (int off = 1; off < 256; off <<= 1) {
      int add = (t >= off) ? sh[t - off] : 0;
      __syncthreads();
      sh[t] += add;
      __syncthreads();
    }
    if (base + t < nblk) row[base + t] = carry + sh[t] - v;
    carry += sh[255];
    __syncthreads();
  }
  if (t == 0) btot[b] = carry;
}

__global__ __launch_bounds__(256) void bucket_base_kernel(const int* __restrict__ btot,
                                                          int* __restrict__ bbase,
                                                          int nbuck, int e) {
  __shared__ int sh[256];
  __shared__ int carry;
  int t = threadIdx.x;
  if (t == 0) carry = 0;
  __syncthreads();
  for (int base = 0; base < nbuck; base += 256) {
    int v = (base + t < nbuck) ? btot[base + t] : 0;
    sh[t] = v;
    __syncthreads();
    for (int off = 1; off < 256; off <<= 1) {
      int add = (t >= off) ? sh[t - off] : 0;
      __syncthreads();
      sh[t] += add;
      __syncthreads();
    }
    if (base + t < nbuck) bbase[base + t] = carry + sh[t] - v;
    __syncthreads();
    if (t == 0) carry += sh[255];
    __syncthreads();
  }
  if (t == 0) bbase[nbuck] = e;
}

__global__ __launch_bounds__(256) void bucket_bin_kernel(const int* __restrict__ src,
                                                         const int* __restrict__ dst,
                                                         const int* __restrict__ counts,
                                                         const int* __restrict__ bbase,
                                                         int2* __restrict__ binned,
                                                         int e, int nblk, int nbuck) {
  __shared__ int cur[256];
  int t = threadIdx.x, blk = blockIdx.x;
  for (int b = t; b < nbuck; b += 256) cur[b] = counts[b * nblk + blk] + bbase[b];
  __syncthreads();
  int base = blk * 4096;
#pragma unroll
  for (int k = 0; k < 16; ++k) {
    int i = base + k * 256 + t;
    if (i < e) {
      int d = dst[i];
      int pos = atomicAdd(&cur[d >> 8], 1);
      binned[pos] = make_int2(src[i], d);
    }
  }
}

__global__ __launch_bounds__(256) void bucket_finalize_kernel(const int2* __restrict__ binned,
                                                              const int* __restrict__ bbase,
                                                              int* __restrict__ offsets,
                                                              int* __restrict__ csr,
                                                              float* __restrict__ dinv,
                                                              float* __restrict__ dsq,
                                                              int n, int e, int nbuck) {
  __shared__ int deg[256];
  __shared__ int offs[256];
  __shared__ int cur[256];
  int b = blockIdx.x, t = threadIdx.x;
  int ebeg = bbase[b];
  int eend = bbase[b + 1];
  deg[t] = 0;
  __syncthreads();
  for (int j = ebeg + t; j < eend; j += 256) atomicAdd(&deg[binned[j].y & 255], 1);
  __syncthreads();
  int v = deg[t];
  offs[t] = v;
  __syncthreads();
  for (int off = 1; off < 256; off <<= 1) {
    int add = (t >= off) ? offs[t - off] : 0;
    __syncthreads();
    offs[t] += add;
    __syncthreads();
  }
  int excl = offs[t] - v;
  cur[t] = excl;
  int node = b * 256 + t;
  if (node < n) {
    offsets[node] = ebeg + excl;
    float d = (float)(v > 1 ? v : 1);
    dinv[node] = rsqrtf(d);
    dsq[node] = sqrtf(d);
  }
  if (b == nbuck - 1 && t == 0) offsets[n] = e;
  __syncthreads();
  for (int j = ebeg + t; j < eend; j += 256) {
    int2 pr = binned[j];
    int pos = atomicAdd(&cur[pr.y & 255], 1);
    csr[ebeg + pos] = pr.x;
  }
}

// ============== swz-f16 row layout (256 B): 16 frags of 8 f16, frag slot fc^(row&15) ========

// ---------------- prep_feat: emits Fsp (swz f16) + xsA = fp16(feat*dinv) ----------------
__global__ void prep_feat_kernel(const float* __restrict__ feat, const float* __restrict__ dinv,
                                 _Float16* __restrict__ Fsp, _Float16* __restrict__ xs,
                                 int n) {
  int i = blockIdx.x * 256 + threadIdx.x;   // frag index
  if (i >= n * 16) return;
  int row = i >> 4, fc = i & 15;
  const float4* s = (const float4*)(feat + (size_t)row * NF + fc * 8);
  float4 a = s[0], b = s[1];
  float xv[8] = {a.x, a.y, a.z, a.w, b.x, b.y, b.z, b.w};
  float d = dinv[row];
  half8 h, f;
#pragma unroll
  for (int j = 0; j < 8; ++j) { h[j] = (_Float16)(xv[j] * d); f[j] = (_Float16)xv[j]; }
  *(half8*)(xs + (size_t)row * NF + fc * 8) = h;
  int swz = (fc ^ (row & 15)) * 8;
  *(half8*)(Fsp + (size_t)row * 128 + swz) = f;
}

// ---------------- SpMV: gathers fp16 pre-scaled; emits swz-f16 out (+ optional fp16 scaled) --
__global__ __launch_bounds__(256) void spmv_kernel(
    const _Float16* __restrict__ xs16, const float* __restrict__ dinv,
    const int* __restrict__ offsets, const int* __restrict__ csr,
    const _Float16* __restrict__ zs16, const float* __restrict__ dsq, float a, float bz,
    _Float16* __restrict__ outsp, _Float16* __restrict__ outs16, int n) {
  int w = threadIdx.x >> 6, lane = threadIdx.x & 63;
  int node = blockIdx.x * 4 + w;
  if (node >= n) return;
  int beg = __builtin_amdgcn_readfirstlane(offsets[node]);
  int end = __builtin_amdgcn_readfirstlane(offsets[node + 1]);
  int eh = lane >> 4;        // which edge of the quad (0..3)
  int cq = lane & 15;        // half8 frag within the 128-half row

  float acc[8];
#pragma unroll
  for (int j = 0; j < 8; ++j) acc[j] = 0.f;

  int e2 = beg;
  for (; e2 + 8 <= end; e2 += 8) {
    int s0 = csr[e2 + eh];
    int s1 = csr[e2 + 4 + eh];
    half8 g0 = ((const half8*)(xs16 + (size_t)s0 * NF))[cq];
    half8 g1 = ((const half8*)(xs16 + (size_t)s1 * NF))[cq];
#pragma unroll
    for (int j = 0; j < 8; ++j) acc[j] += (float)g0[j];
#pragma unroll
    for (int j = 0; j < 8; ++j) acc[j] += (float)g1[j];
  }
  for (; e2 + 4 <= end; e2 += 4) {
    int s0 = csr[e2 + eh];
    half8 g0 = ((const half8*)(xs16 + (size_t)s0 * NF))[cq];
#pragma unroll
    for (int j = 0; j < 8; ++j) acc[j] += (float)g0[j];
  }
  int rem = end - e2;
  if (eh < rem) {
    int s0 = csr[e2 + eh];
    half8 g0 = ((const half8*)(xs16 + (size_t)s0 * NF))[cq];
#pragma unroll
    for (int j = 0; j < 8; ++j) acc[j] += (float)g0[j];
  }
#pragma unroll
  for (int j = 0; j < 8; ++j) {
    acc[j] += __shfl_xor(acc[j], 16);
    acc[j] += __shfl_xor(acc[j], 32);
  }
  if (eh == 0) {
    float dv = dinv[node];
    float v[8];
#pragma unroll
    for (int j = 0; j < 8; ++j) v[j] = a * dv * acc[j];
    if (zs16) {
      float zf = bz * dsq[node];
      half8 zz = ((const half8*)(zs16 + (size_t)node * NF))[cq];
#pragma unroll
      for (int j = 0; j < 8; ++j) v[j] += zf * (float)zz[j];
    }
    half8 ho, hs;
#pragma unroll
    for (int j = 0; j < 8; ++j) { ho[j] = (_Float16)v[j]; hs[j] = (_Float16)(v[j] * dv); }
    int swz = (cq ^ (node & 15)) * 8;
    *(half8*)(outsp + (size_t)node * 128 + swz) = ho;
    if (outs16) *(half8*)(outs16 + (size_t)node * NF + cq * 8) = hs;
  }
}

// ---------------- W pre-split (f16 hi/lo) + frag-pack ----------------
__device__ __forceinline__ void pack_one(const float* __restrict__ W, ushort8* __restrict__ Wp,
                                         int f, int NT, int K) {
  int lane = f & 63;
  int hl = (f >> 6) & 1;
  int rest = f >> 7;
  int nt = rest % NT;
  int kunit = rest / NT;
  int nrow = nt * 16 + (lane & 15);
  int k0 = kunit * 32 + (lane >> 4) * 8;
  const float* srcp = W + (size_t)nrow * K + k0;
  ushort8 v;
#pragma unroll
  for (int j = 0; j < 8; ++j) {
    float x = srcp[j];
    _Float16 h = (_Float16)x;
    if (hl) h = (_Float16)(x - (float)h);
    v[j] = __builtin_bit_cast(unsigned short, h);
  }
  Wp[f] = v;
}

__global__ void pack_all_kernel(const float* __restrict__ W1, ushort8* __restrict__ P1,
                                const float* __restrict__ W3, ushort8* __restrict__ P3,
                                const float* __restrict__ Wm1, ushort8* __restrict__ PM1,
                                const float* __restrict__ Wm2, ushort8* __restrict__ PM2) {
  int f = blockIdx.x * 256 + threadIdx.x;
  if (f < 12288) pack_one(W1, P1, f, 8, 384);
  else if (f < 24576) pack_one(W3, P3, f - 12288, 8, 384);
  else if (f < 28672) pack_one(Wm1, PM1, f - 24576, 8, 128);
  else if (f < 30720) pack_one(Wm2, PM2, f - 28672, 4, 128);
}

// ================= GEMM machinery (f16 A single, f16 W hi+lo) =================

__device__ __forceinline__ void stage_sp(const _Float16* gsrc, float4* lbuf, int tid) {
  const char* g = (const char*)gsrc;
  char* l = (char*)lbuf;
#pragma unroll
  for (int k = 0; k < 2; ++k) {
    int off = k * 8192 + tid * 16;
    __builtin_amdgcn_global_load_lds(
        (const __attribute__((address_space(1))) void*)(g + off),
        (__attribute__((address_space(3))) void*)(l + off), 16, 0, 0);
  }
}

__device__ __forceinline__ void lds_put16(_Float16* L, int row, int col, float v) {
  L[row * 128 + (((col >> 3) ^ (row & 15)) << 3) + (col & 7)] = (_Float16)v;
}

// B chunk: 2 kunits x NT2=2 n-tiles x (hi,lo) = 8 frags = 32 VGPR
struct Bchunk {
  ushort8 h[2][2];
  ushort8 l[2][2];
};

__device__ __forceinline__ void loadB(const ushort8* __restrict__ Wp, int kunit0,
                                      int lane, int wn, Bchunk& c) {
#pragma unroll
  for (int k2 = 0; k2 < 2; ++k2) {
#pragma unroll
    for (int j = 0; j < 2; ++j) {
      const ushort8* bp = Wp + (size_t)((kunit0 + k2) * 8 + wn * 2 + j) * 128 + lane;
      c.h[k2][j] = bp[0];
      c.l[k2][j] = bp[64];
    }
  }
}

// MFMA one B-chunk: 2 kunits x 2 mt x 2 j x 2 terms = 16 MFMAs
__device__ __forceinline__ void mfma_chunk(const float4* A4, const Bchunk& c, int kbase,
                                           int lane, int wm, f32x4 (*acc)[2]) {
#pragma unroll
  for (int k2 = 0; k2 < 2; ++k2) {
    int kunit = kbase + k2;
    half8 a[2];
#pragma unroll
    for (int mt = 0; mt < 2; ++mt) {
      int arow = wm * 32 + mt * 16 + (lane & 15);
      int fc = (kunit & 3) * 4 + (lane >> 4);
      a[mt] = __builtin_bit_cast(half8, A4[arow * 16 + (fc ^ (arow & 15))]);
    }
#pragma unroll
    for (int j = 0; j < 2; ++j) {
      half8 bh = __builtin_bit_cast(half8, c.h[k2][j]);
      half8 bl = __builtin_bit_cast(half8, c.l[k2][j]);
#pragma unroll
      for (int mt = 0; mt < 2; ++mt) {
        acc[mt][j] = __builtin_amdgcn_mfma_f32_16x16x32_f16(a[mt], bh, acc[mt][j], 0, 0, 0);
        acc[mt][j] = __builtin_amdgcn_mfma_f32_16x16x32_f16(a[mt], bl, acc[mt][j], 0, 0, 0);
      }
    }
  }
}

// generic gemm_step for the MLP phases (A = f16 LDS tile, B compiler-managed)
template<int NT, int NT2>
__device__ __forceinline__ void gemm_step16(const float4* A4, const ushort8* __restrict__ Wp,
                                            int kunit, int lane, int wm, int wn,
                                            f32x4 (*acc)[NT2]) {
  half8 a[2];
#pragma unroll
  for (int mt = 0; mt < 2; ++mt) {
    int arow = wm * 32 + mt * 16 + (lane & 15);
    int fc = (kunit & 3) * 4 + (lane >> 4);
    a[mt] = __builtin_bit_cast(half8, A4[arow * 16 + (fc ^ (arow & 15))]);
  }
#pragma unroll
  for (int j = 0; j < NT2; ++j) {
    int nt = wn * NT2 + j;
    const ushort8* bp = Wp + (size_t)(kunit * NT + nt) * 2 * 64 + lane;
    half8 bh = __builtin_bit_cast(half8, bp[0]);
    half8 bl = __builtin_bit_cast(half8, bp[64]);
#pragma unroll
    for (int mt = 0; mt < 2; ++mt) {
      acc[mt][j] = __builtin_amdgcn_mfma_f32_16x16x32_f16(a[mt], bh, acc[mt][j], 0, 0, 0);
      acc[mt][j] = __builtin_amdgcn_mfma_f32_16x16x32_f16(a[mt], bl, acc[mt][j], 0, 0, 0);
    }
  }
}

// 3-part pipelined K-loop: order per phase = {bc0, bc1, stage A[p+1]} -> vmcnt(10) retires
// previous A; consuming bc1 needs only vmcnt(2) so A[p+1] stays in flight across the phase.
__device__ __forceinline__ void gemm3_pipeline(const _Float16* A0, const _Float16* A1,
                                               const _Float16* A2, const ushort8* Wp,
                                               float4 (*buf)[1024], size_t r0,
                                               int tid, int lane, int wm, int wn,
                                               f32x4 (*acc)[2]) {
  const _Float16* Aarr[3] = {A0, A1, A2};
  stage_sp(A0 + r0 * 128, buf[0], tid);
  Bchunk bc0, bc1;
#pragma unroll
  for (int p = 0; p < 3; ++p) {
    loadB(Wp, p * 4, lane, wn, bc0);
    loadB(Wp, p * 4 + 2, lane, wn, bc1);
    if (p + 1 < 3) stage_sp(Aarr[p + 1] + r0 * 128, buf[(p + 1) & 1], tid);
    // queue: [prev A(2)], bc0(8), bc1(8), [next A(2)] -> vmcnt(10) retires prev A + bc0
    asm volatile("s_waitcnt vmcnt(10)" ::: "memory");
    __builtin_amdgcn_s_barrier();
    __builtin_amdgcn_sched_barrier(0);
    mfma_chunk(buf[p & 1], bc0, p * 4, lane, wm, acc);
    mfma_chunk(buf[p & 1], bc1, p * 4 + 2, lane, wm, acc);   // compiler waits vmcnt(2)
    __builtin_amdgcn_sched_barrier(0);
    __builtin_amdgcn_s_barrier();
  }
}

// ---------------- conv1 GEMM + fused BN partial stats (8-way replicated) ----------------
__global__ __launch_bounds__(512, 4) void conv1_gemm_kernel(
    const _Float16* __restrict__ A0, const _Float16* __restrict__ A1,
    const _Float16* __restrict__ A2,
    const ushort8* __restrict__ Wp, const float* __restrict__ bias,
    _Float16* __restrict__ Xh, float* __restrict__ stats, int n) {
  __shared__ float4 buf[2][1024];   // 32 KB
  __shared__ float sstat[256];

  int tid = threadIdx.x;
  int lane = tid & 63, wid = tid >> 6;
  int wm = wid >> 2, wn = wid & 3;
  size_t r0 = (size_t)blockIdx.x * 64;

  f32x4 acc[2][2];
#pragma unroll
  for (int mt = 0; mt < 2; ++mt)
#pragma unroll
    for (int j = 0; j < 2; ++j) acc[mt][j] = (f32x4)0.f;

  gemm3_pipeline(A0, A1, A2, Wp, buf, r0, tid, lane, wm, wn, acc);

  // epilogue: relu + f16 store + BN partial stats (LDS combine -> replicated global atomics)
  if (tid < 256) sstat[tid] = 0.f;
  __syncthreads();
#pragma unroll
  for (int mt = 0; mt < 2; ++mt) {
    int rbase = (int)r0 + wm * 32 + mt * 16 + (lane >> 4) * 4;
#pragma unroll
    for (int j = 0; j < 2; ++j) {
      int col = wn * 32 + j * 16 + (lane & 15);
      float b = bias[col];
      float sj = 0.f, qj = 0.f;
#pragma unroll
      for (int i = 0; i < 4; ++i) {
        int row = rbase + i;
        if (row < n) {
          float v = fmaxf(acc[mt][j][i] + b, 0.f);
          Xh[(size_t)row * NF + col] = (_Float16)v;
          sj += v; qj += v * v;
        }
      }
      sj += __shfl_xor(sj, 16); sj += __shfl_xor(sj, 32);
      qj += __shfl_xor(qj, 16); qj += __shfl_xor(qj, 32);
      if ((lane >> 4) == 0) {
        atomicAdd(&sstat[col], sj);
        atomicAdd(&sstat[128 + col], qj);
      }
    }
  }
  __syncthreads();
  if (tid < 256) atomicAdd(&stats[(blockIdx.x & 7) * 256 + tid], sstat[tid]);
}

// ---------------- fused tail: conv2 GEMM + residual -> MLP1 -> MLP2 on-chip ----------------
__global__ __launch_bounds__(512, 4) void fused_tail_kernel(
    const _Float16* __restrict__ Xsp, const _Float16* __restrict__ T1sp,
    const _Float16* __restrict__ T2sp,
    const _Float16* __restrict__ xsA, const float* __restrict__ dsq,
    const ushort8* __restrict__ Wp3, const float* __restrict__ b3,
    const ushort8* __restrict__ WpM1, const float* __restrict__ bm1,
    const ushort8* __restrict__ WpM2, const float* __restrict__ bm2,
    float* __restrict__ out, int n) {
  __shared__ float4 buf[2][1024];
  _Float16* L = (_Float16*)buf[0];

  int tid = threadIdx.x;
  int lane = tid & 63, wid = tid >> 6;
  int wm = wid >> 2, wn = wid & 3;
  size_t r0 = (size_t)blockIdx.x * 64;

  f32x4 acc[2][2];
#pragma unroll
  for (int mt = 0; mt < 2; ++mt)
#pragma unroll
    for (int j = 0; j < 2; ++j) acc[mt][j] = (f32x4)0.f;

  // ---- phase 1: conv2 GEMM over {Xsp, T1sp, T2sp}
  gemm3_pipeline(Xsp, T1sp, T2sp, Wp3, buf, r0, tid, lane, wm, wn, acc);

  // ---- epilogue 1: Y = relu(acc+b3) + X -> f16 into LDS (buf[0], swz layout)
#pragma unroll
  for (int mt = 0; mt < 2; ++mt) {
    int rb = wm * 32 + mt * 16 + (lane >> 4) * 4;
#pragma unroll
    for (int j = 0; j < 2; ++j) {
      int col = wn * 32 + j * 16 + (lane & 15);
      float b = b3[col];
#pragma unroll
      for (int i = 0; i < 4; ++i) {
        int lrow = rb + i;
        int row = (int)r0 + lrow;
        float v = 0.f;
        if (row < n) {
          float xres = (float)xsA[(size_t)row * NF + col] * dsq[row];
          v = fmaxf(acc[mt][j][i] + b, 0.f) + xres;
        }
        lds_put16(L, lrow, col, v);
      }
    }
  }
  __syncthreads();
  // ---- phase 2: H = relu(Y @ Wm1^T + bm1)
  f32x4 acc2[2][2];
#pragma unroll
  for (int mt = 0; mt < 2; ++mt)
#pragma unroll
    for (int j = 0; j < 2; ++j) acc2[mt][j] = (f32x4)0.f;
#pragma unroll
  for (int ks = 0; ks < 4; ++ks)
    gemm_step16<8, 2>(buf[0], WpM1, ks, lane, wm, wn, acc2);
  __syncthreads();   // all reads of Y done before overwrite
  // ---- epilogue 2: scatter H (f16) into LDS
#pragma unroll
  for (int mt = 0; mt < 2; ++mt) {
    int rb = wm * 32 + mt * 16 + (lane >> 4) * 4;
#pragma unroll
    for (int j = 0; j < 2; ++j) {
      int col = wn * 32 + j * 16 + (lane & 15);
      float b = bm1[col];
#pragma unroll
      for (int i = 0; i < 4; ++i) {
        float v = fmaxf(acc2[mt][j][i] + b, 0.f);
        lds_put16(L, rb + i, col, v);
      }
    }
  }
  __syncthreads();
  // ---- phase 3: out = H @ Wm2^T + bm2   (NC=64: NT=4, NT2=1)
  f32x4 acc3[2][1];
#pragma unroll
  for (int mt = 0; mt < 2; ++mt) acc3[mt][0] = (f32x4)0.f;
#pragma unroll
  for (int ks = 0; ks < 4; ++ks)
    gemm_step16<4, 1>(buf[0], WpM2, ks, lane, wm, wn, acc3);
#pragma unroll
  for (int mt = 0; mt < 2; ++mt) {
    int rb = wm * 32 + mt * 16 + (lane >> 4) * 4;
    int col = wn * 16 + (lane & 15);
    float b = bm2[col];
#pragma unroll
    for (int i = 0; i < 4; ++i) {
      int row = (int)r0 + rb + i;
      if (row < n) out[(size_t)row * 64 + col] = acc3[mt][0][i] + b;
    }
  }
}

// ---------------- BatchNorm apply: reads Xh f16, sums 8 stat replicas inline ----------------
__global__ void bn_apply_kernel(const _Float16* __restrict__ Xh, const float* __restrict__ stats,
                                const float* __restrict__ gamma, const float* __restrict__ beta,
                                const float* __restrict__ dinv,
                                _Float16* __restrict__ Xsp, _Float16* __restrict__ xs16,
                                float fn, int n) {
  int i = blockIdx.x * 256 + threadIdx.x;   // frag index
  if (i >= n * 16) return;
  int row = i >> 4, fc = i & 15;
  half8 xh = *(const half8*)(Xh + (size_t)row * NF + fc * 8);
  float xv[8];
  int c0 = fc * 8;
#pragma unroll
  for (int j = 0; j < 8; ++j) {
    int c = c0 + j;
    float s1 = 0.f, s2 = 0.f;
#pragma unroll
    for (int r = 0; r < 8; ++r) {
      s1 += stats[r * 256 + c];
      s2 += stats[r * 256 + NF + c];
    }
    float mu = s1 / fn;
    float var = s2 / fn - mu * mu;
    float s = gamma[c] * rsqrtf(var + 1e-5f);
    xv[j] = ((float)xh[j] - mu) * s + beta[c];
  }
  float d = dinv[row];
  half8 hs, hu;
#pragma unroll
  for (int j = 0; j < 8; ++j) { hs[j] = (_Float16)(xv[j] * d); hu[j] = (_Float16)xv[j]; }
  *(half8*)(xs16 + (size_t)row * NF + fc * 8) = hs;
  int swz = (fc ^ (row & 15)) * 8;
  *(half8*)(Xsp + (size_t)row * 128 + swz) = hu;
}

// ---------------- launcher ----------------
extern "C" void kernel_launch(void* const* d_in, const int* in_sizes, int n_in,
                              void* d_out, int out_size, void* d_ws, size_t ws_size,
                              hipStream_t stream) {
  const float* feat  = (const float*)d_in[0];
  const int*   src   = (const int*)d_in[1];
  const int*   dst   = (const int*)d_in[2];
  const float* W1    = (const float*)d_in[3];
  const float* b1    = (const float*)d_in[4];
  const float* W3    = (const float*)d_in[5];
  const float* b3    = (const float*)d_in[6];
  const float* gamma = (const float*)d_in[7];
  const float* beta  = (const float*)d_in[8];
  const float* Wm1   = (const float*)d_in[9];
  const float* bm1   = (const float*)d_in[10];
  const float* Wm2   = (const float*)d_in[11];
  const float* bm2   = (const float*)d_in[12];
  int n = in_sizes[0] / NF;
  int e = in_sizes[1];

  char* p = (char*)d_ws;
  auto alloc = [&](size_t bytes) {
    char* r = p;
    p += (bytes + 255) & ~size_t(255);
    return r;
  };
  int nblk  = ceil_div(e, 4096);   // multisplit tiles
  int nbuck = ceil_div(n, 256);    // node buckets

  float* dinv     = (float*)alloc((size_t)n * 4);
  float* dsq      = (float*)alloc((size_t)n * 4);
  int*   offsets  = (int*)alloc((size_t)(n + 1) * 4);
  int*   counts   = (int*)alloc((size_t)nblk * nbuck * 4);
  int*   btot     = (int*)alloc((size_t)nbuck * 4);
  int*   bbase    = (int*)alloc((size_t)(nbuck + 1) * 4);
  int*   csr      = (int*)alloc((size_t)e * 4);
  float* stats    = (float*)alloc(8 * 256 * 4);
  ushort8* Wp1  = (ushort8*)alloc(12 * 8 * 2 * 64 * 16);   // K=384, NT=8
  ushort8* Wp3  = (ushort8*)alloc(12 * 8 * 2 * 64 * 16);
  ushort8* WpM1 = (ushort8*)alloc(4 * 8 * 2 * 64 * 16);    // K=128, NT=8
  ushort8* WpM2 = (ushort8*)alloc(4 * 4 * 2 * 64 * 16);    // K=128, NT=4
  size_t spb = (size_t)(n + 64) * 256;        // swz f16 rows, 64 pad rows for gload_lds
  _Float16* Fsp  = (_Float16*)alloc(spb);
  _Float16* T1sp = (_Float16*)alloc(spb);
  _Float16* T2sp = (_Float16*)alloc(spb);
  _Float16* Xsp  = (_Float16*)alloc(spb);
  _Float16* Xh   = (_Float16*)alloc((size_t)n * NF * 2);  // conv1 output (pre-BN, f16)
  _Float16* xsA  = (_Float16*)alloc((size_t)n * NF * 2);  // fp16 scaled gather sources
  _Float16* xsB  = (_Float16*)alloc((size_t)n * NF * 2);
  int2* binned = (int2*)Fsp;   // alias: 6.4 MB scratch, dead before prep_feat writes Fsp

  hipMemsetAsync(stats, 0, 8 * 256 * 4, stream);

  int fb = ceil_div(n * 16, 256);            // frag-grid over matrices
  int sb = ceil_div(n, 4);                   // spmv: 4 nodes/block
  int gb = ceil_div(n, 64);                  // gemm: 64 rows/block, 512 threads

  // CSR build (sorted by dst) via two-level multisplit; also emits offsets/dinv/dsq
  bucket_hist_kernel<<<nblk, 256, 0, stream>>>(dst, counts, e, nblk, nbuck);
  bucket_scan_rows_kernel<<<nbuck, 256, 0, stream>>>(counts, btot, nblk);
  bucket_base_kernel<<<1, 256, 0, stream>>>(btot, bbase, nbuck, e);
  bucket_bin_kernel<<<nblk, 256, 0, stream>>>(src, dst, counts, bbase, binned, e, nblk, nbuck);
  bucket_finalize_kernel<<<nbuck, 256, 0, stream>>>(binned, bbase, offsets, csr, dinv, dsq, n, e, nbuck);

  // W split+pack (f16 hi/lo)
  pack_all_kernel<<<120, 256, 0, stream>>>(W1, Wp1, W3, Wp3, Wm1, WpM1, Wm2, WpM2);

  // conv1: T1 = -A^ F ; T2 = -2 A^ T1 - F ; Xh = f16(relu([F,T1,T2] @ W1^T + b1))  (+BN stats)
  prep_feat_kernel<<<fb, 256, 0, stream>>>(feat, dinv, Fsp, xsA, n);
  spmv_kernel<<<sb, 256, 0, stream>>>(xsA, dinv, offsets, csr, nullptr, nullptr, -1.f, 0.f, T1sp, xsB, n);
  spmv_kernel<<<sb, 256, 0, stream>>>(xsB, dinv, offsets, csr, xsA, dsq, -2.f, -1.f, T2sp, nullptr, n);
  conv1_gemm_kernel<<<gb, 512, 0, stream>>>(Fsp, T1sp, T2sp, Wp1, b1, Xh, stats, n);

  // BatchNorm apply (inline from replicated stats); emits Xsp + xsA = fp16(X*dinv)
  bn_apply_kernel<<<fb, 256, 0, stream>>>(Xh, stats, gamma, beta, dinv, Xsp, xsA, (float)n, n);

  // conv2 spmvs (z-term from xsA * dsq)
  spmv_kernel<<<sb, 256, 0, stream>>>(xsA, dinv, offsets, csr, nullptr, nullptr, -1.f, 0.f, T1sp, xsB, n);
  spmv_kernel<<<sb, 256, 0, stream>>>(xsB, dinv, offsets, csr, xsA, dsq, -2.f, -1.f, T2sp, nullptr, n);

  // fused conv2-GEMM + residual + MLP1 + MLP2 (Y, H stay on-chip)
  fused_tail_kernel<<<gb, 512, 0, stream>>>(Xsp, T1sp, T2sp, xsA, dsq, Wp3, b3, WpM1, bm1,
                                            WpM2, bm2, (float*)d_out, n);
}

// Round 16
// 254.796 us; speedup vs baseline: 1.3334x; 1.0500x over previous
//
#include <hip/hip_runtime.h>
#include <hip/hip_bf16.h>
#include <math.h>

#define NF 128   // IN_F == HID == 128

typedef unsigned short ushort8 __attribute__((ext_vector_type(8)));
typedef float f32x4 __attribute__((ext_vector_type(4)));
typedef _Float16 half8 __attribute__((ext_vector_type(8)));

static inline int ceil_div(int a, int b) { return (a + b - 1) / b; }

// ================= CSR build: two-level multisplit counting sort =================
__global__ __launch_bounds__(256) void bucket_hist_kernel(const int* __restrict__ dst,
                                                          int* __restrict__ counts,
                                                          int e, int nblk, int nbuck) {
  __shared__ int h[256];
  int t = threadIdx.x, blk = blockIdx.x;
  h[t] = 0;
  __syncthreads();
  int base = blk * 4096;
#pragma unroll
  for (int k = 0; k < 16; ++k) {
    int i = base + k * 256 + t;
    if (i < e) atomicAdd(&h[dst[i] >> 8], 1);
  }
  __syncthreads();
  for (int b = t; b < nbuck; b += 256) counts[b * nblk + blk] = h[b];
}

__global__ __launch_bounds__(256) void bucket_scan_rows_kernel(int* __restrict__ counts,
                                                               int* __restrict__ btot,
                                                               int nblk) {
  __shared__ int sh[256];
  int b = blockIdx.x, t = threadIdx.x;
  int* row = counts + (size_t)b * nblk;
  int carry = 0;
  for (int base = 0; base < nblk; base += 256) {
    int v = (base + t < nblk) ? row[base + t] : 0;
    sh[t] = v;
    __syncthreads();
    for (int off = 1; off < 256; off <<= 1) {
      int add = (t >= off) ? sh[t - off] : 0;
      __syncthreads();
      sh[t] += add;
      __syncthreads();
    }
    if (base + t < nblk) row[base + t] = carry + sh[t] - v;
    carry += sh[255];
    __syncthreads();
  }
  if (t == 0) btot[b] = carry;
}

__global__ __launch_bounds__(256) void bucket_base_kernel(const int* __restrict__ btot,
                                                          int* __restrict__ bbase,
                                                          int nbuck, int e) {
  __shared__ int sh[256];
  __shared__ int carry;
  int t = threadIdx.x;
  if (t == 0) carry = 0;
  __syncthreads();
  for (int base = 0; base < nbuck; base += 256) {
    int v = (base + t < nbuck) ? btot[base + t] : 0;
    sh[t] = v;
    __syncthreads();
    for (int off = 1; off < 256; off <<= 1) {
      int add = (t >= off) ? sh[t - off] : 0;
      __syncthreads();
      sh[t] += add;
      __syncthreads();
    }
    if (base + t < nbuck) bbase[base + t] = carry + sh[t] - v;
    __syncthreads();
    if (t == 0) carry += sh[255];
    __syncthreads();
  }
  if (t == 0) bbase[nbuck] = e;
}

__global__ __launch_bounds__(256) void bucket_bin_kernel(const int* __restrict__ src,
                                                         const int* __restrict__ dst,
                                                         const int* __restrict__ counts,
                                                         const int* __restrict__ bbase,
                                                         int2* __restrict__ binned,
                                                         int e, int nblk, int nbuck) {
  __shared__ int cur[256];
  int t = threadIdx.x, blk = blockIdx.x;
  for (int b = t; b < nbuck; b += 256) cur[b] = counts[b * nblk + blk] + bbase[b];
  __syncthreads();
  int base = blk * 4096;
#pragma unroll
  for (int k = 0; k < 16; ++k) {
    int i = base + k * 256 + t;
    if (i < e) {
      int d = dst[i];
      int pos = atomicAdd(&cur[d >> 8], 1);
      binned[pos] = make_int2(src[i], d);
    }
  }
}

__global__ __launch_bounds__(256) void bucket_finalize_kernel(const int2* __restrict__ binned,
                                                              const int* __restrict__ bbase,
                                                              int* __restrict__ offsets,
                                                              int* __restrict__ csr,
                                                              float* __restrict__ dinv,
                                                              int n, int e, int nbuck) {
  __shared__ int deg[256];
  __shared__ int offs[256];
  __shared__ int cur[256];
  int b = blockIdx.x, t = threadIdx.x;
  int ebeg = bbase[b];
  int eend = bbase[b + 1];
  deg[t] = 0;
  __syncthreads();
  for (int j = ebeg + t; j < eend; j += 256) atomicAdd(&deg[binned[j].y & 255], 1);
  __syncthreads();
  int v = deg[t];
  offs[t] = v;
  __syncthreads();
  for (int off = 1; off < 256; off <<= 1) {
    int add = (t >= off) ? offs[t - off] : 0;
    __syncthreads();
    offs[t] += add;
    __syncthreads();
  }
  int excl = offs[t] - v;
  cur[t] = excl;
  int node = b * 256 + t;
  if (node < n) {
    offsets[node] = ebeg + excl;
    float d = (float)(v > 1 ? v : 1);
    dinv[node] = rsqrtf(d);
  }
  if (b == nbuck - 1 && t == 0) offsets[n] = e;
  __syncthreads();
  for (int j = ebeg + t; j < eend; j += 256) {
    int2 pr = binned[j];
    int pos = atomicAdd(&cur[pr.y & 255], 1);
    csr[ebeg + pos] = pr.x;
  }
}

// ============== swz-f16 row layout (256 B): 16 frags of 8 f16, frag slot fc^(row&15) ========

// ---------------- prep_feat: emits Fsp (swz f16) only ----------------
__global__ void prep_feat_kernel(const float* __restrict__ feat,
                                 _Float16* __restrict__ Fsp, int n) {
  int i = blockIdx.x * 256 + threadIdx.x;   // frag index
  if (i >= n * 16) return;
  int row = i >> 4, fc = i & 15;
  const float4* s = (const float4*)(feat + (size_t)row * NF + fc * 8);
  float4 a = s[0], b = s[1];
  float xv[8] = {a.x, a.y, a.z, a.w, b.x, b.y, b.z, b.w};
  half8 f;
#pragma unroll
  for (int j = 0; j < 8; ++j) f[j] = (_Float16)xv[j];
  int swz = (fc ^ (row & 15)) * 8;
  *(half8*)(Fsp + (size_t)row * 128 + swz) = f;
}

// ---------------- SpMV: gathers swizzled f16 rows with per-edge dinv weight ----------------
// out[v] = a*dinv[v] * sum_e dinv[src_e]*xsp[src_e] + bz*zsp[v]; all rows swz-f16.
__global__ __launch_bounds__(256) void spmv_kernel(
    const _Float16* __restrict__ xsp, const float* __restrict__ dinv,
    const int* __restrict__ offsets, const int* __restrict__ csr,
    const _Float16* __restrict__ zsp, float a, float bz,
    _Float16* __restrict__ outsp, int n) {
  int w = threadIdx.x >> 6, lane = threadIdx.x & 63;
  int node = blockIdx.x * 4 + w;
  if (node >= n) return;
  int beg = __builtin_amdgcn_readfirstlane(offsets[node]);
  int end = __builtin_amdgcn_readfirstlane(offsets[node + 1]);
  int eh = lane >> 4;        // which edge of the quad (0..3)
  int cq = lane & 15;        // frag index within the row

  float acc[8];
#pragma unroll
  for (int j = 0; j < 8; ++j) acc[j] = 0.f;

  int e2 = beg;
  for (; e2 + 8 <= end; e2 += 8) {
    int s0 = csr[e2 + eh];
    int s1 = csr[e2 + 4 + eh];
    float w0 = dinv[s0], w1 = dinv[s1];
    half8 g0 = *(const half8*)(xsp + (size_t)s0 * 128 + ((cq ^ (s0 & 15)) << 3));
    half8 g1 = *(const half8*)(xsp + (size_t)s1 * 128 + ((cq ^ (s1 & 15)) << 3));
#pragma unroll
    for (int j = 0; j < 8; ++j) acc[j] += w0 * (float)g0[j];
#pragma unroll
    for (int j = 0; j < 8; ++j) acc[j] += w1 * (float)g1[j];
  }
  for (; e2 + 4 <= end; e2 += 4) {
    int s0 = csr[e2 + eh];
    float w0 = dinv[s0];
    half8 g0 = *(const half8*)(xsp + (size_t)s0 * 128 + ((cq ^ (s0 & 15)) << 3));
#pragma unroll
    for (int j = 0; j < 8; ++j) acc[j] += w0 * (float)g0[j];
  }
  int rem = end - e2;
  if (eh < rem) {
    int s0 = csr[e2 + eh];
    float w0 = dinv[s0];
    half8 g0 = *(const half8*)(xsp + (size_t)s0 * 128 + ((cq ^ (s0 & 15)) << 3));
#pragma unroll
    for (int j = 0; j < 8; ++j) acc[j] += w0 * (float)g0[j];
  }
#pragma unroll
  for (int j = 0; j < 8; ++j) {
    acc[j] += __shfl_xor(acc[j], 16);
    acc[j] += __shfl_xor(acc[j], 32);
  }
  if (eh == 0) {
    float dv = a * dinv[node];
    float v[8];
#pragma unroll
    for (int j = 0; j < 8; ++j) v[j] = dv * acc[j];
    int swz = (cq ^ (node & 15)) << 3;
    if (zsp) {
      half8 zz = *(const half8*)(zsp + (size_t)node * 128 + swz);
#pragma unroll
      for (int j = 0; j < 8; ++j) v[j] += bz * (float)zz[j];
    }
    half8 ho;
#pragma unroll
    for (int j = 0; j < 8; ++j) ho[j] = (_Float16)v[j];
    *(half8*)(outsp + (size_t)node * 128 + swz) = ho;
  }
}

// ---------------- W pre-split (f16 hi/lo) + frag-pack, with kunit rotation ----------------
__device__ __forceinline__ void pack_one(const float* __restrict__ W, ushort8* __restrict__ Wp,
                                         int f, int NT, int K, int rot) {
  int lane = f & 63;
  int hl = (f >> 6) & 1;
  int rest = f >> 7;
  int nt = rest % NT;
  int kunit = rest / NT;
  int nK = K >> 5;
  int srcKunit = (kunit + rot) % nK;
  int nrow = nt * 16 + (lane & 15);
  int k0 = srcKunit * 32 + (lane >> 4) * 8;
  const float* srcp = W + (size_t)nrow * K + k0;
  ushort8 v;
#pragma unroll
  for (int j = 0; j < 8; ++j) {
    float x = srcp[j];
    _Float16 h = (_Float16)x;
    if (hl) h = (_Float16)(x - (float)h);
    v[j] = __builtin_bit_cast(unsigned short, h);
  }
  Wp[f] = v;
}

__global__ void pack_all_kernel(const float* __restrict__ W1, ushort8* __restrict__ P1,
                                const float* __restrict__ W3, ushort8* __restrict__ P3,
                                const float* __restrict__ Wm1, ushort8* __restrict__ PM1,
                                const float* __restrict__ Wm2, ushort8* __restrict__ PM2) {
  int f = blockIdx.x * 256 + threadIdx.x;
  if (f < 12288) pack_one(W1, P1, f, 8, 384, 0);
  else if (f < 24576) pack_one(W3, P3, f - 12288, 8, 384, 4);   // parts {T1,T2,X}
  else if (f < 28672) pack_one(Wm1, PM1, f - 24576, 8, 128, 0);
  else if (f < 30720) pack_one(Wm2, PM2, f - 28672, 4, 128, 0);
}

// ================= GEMM machinery (f16 A single, f16 W hi+lo) =================

__device__ __forceinline__ void stage_sp(const _Float16* gsrc, float4* lbuf, int tid) {
  const char* g = (const char*)gsrc;
  char* l = (char*)lbuf;
#pragma unroll
  for (int k = 0; k < 2; ++k) {
    int off = k * 8192 + tid * 16;
    __builtin_amdgcn_global_load_lds(
        (const __attribute__((address_space(1))) void*)(g + off),
        (__attribute__((address_space(3))) void*)(l + off), 16, 0, 0);
  }
}

__device__ __forceinline__ int lds_off16(int row, int col) {
  return row * 128 + (((col >> 3) ^ (row & 15)) << 3) + (col & 7);
}

// B chunk: 2 kunits x NT2=2 n-tiles x (hi,lo) = 8 frags = 32 VGPR
struct Bchunk {
  ushort8 h[2][2];
  ushort8 l[2][2];
};

__device__ __forceinline__ void loadB(const ushort8* __restrict__ Wp, int kunit0,
                                      int lane, int wn, Bchunk& c) {
#pragma unroll
  for (int k2 = 0; k2 < 2; ++k2) {
#pragma unroll
    for (int j = 0; j < 2; ++j) {
      const ushort8* bp = Wp + (size_t)((kunit0 + k2) * 8 + wn * 2 + j) * 128 + lane;
      c.h[k2][j] = bp[0];
      c.l[k2][j] = bp[64];
    }
  }
}

// MFMA one B-chunk: 2 kunits x 2 mt x 2 j x 2 terms = 16 MFMAs
__device__ __forceinline__ void mfma_chunk(const float4* A4, const Bchunk& c, int kbase,
                                           int lane, int wm, f32x4 (*acc)[2]) {
#pragma unroll
  for (int k2 = 0; k2 < 2; ++k2) {
    int kunit = kbase + k2;
    half8 a[2];
#pragma unroll
    for (int mt = 0; mt < 2; ++mt) {
      int arow = wm * 32 + mt * 16 + (lane & 15);
      int fc = (kunit & 3) * 4 + (lane >> 4);
      a[mt] = __builtin_bit_cast(half8, A4[arow * 16 + (fc ^ (arow & 15))]);
    }
#pragma unroll
    for (int j = 0; j < 2; ++j) {
      half8 bh = __builtin_bit_cast(half8, c.h[k2][j]);
      half8 bl = __builtin_bit_cast(half8, c.l[k2][j]);
#pragma unroll
      for (int mt = 0; mt < 2; ++mt) {
        acc[mt][j] = __builtin_amdgcn_mfma_f32_16x16x32_f16(a[mt], bh, acc[mt][j], 0, 0, 0);
        acc[mt][j] = __builtin_amdgcn_mfma_f32_16x16x32_f16(a[mt], bl, acc[mt][j], 0, 0, 0);
      }
    }
  }
}

// generic gemm_step for the MLP phases (A = f16 LDS tile, B compiler-managed)
template<int NT, int NT2>
__device__ __forceinline__ void gemm_step16(const float4* A4, const ushort8* __restrict__ Wp,
                                            int kunit, int lane, int wm, int wn,
                                            f32x4 (*acc)[NT2]) {
  half8 a[2];
#pragma unroll
  for (int mt = 0; mt < 2; ++mt) {
    int arow = wm * 32 + mt * 16 + (lane & 15);
    int fc = (kunit & 3) * 4 + (lane >> 4);
    a[mt] = __builtin_bit_cast(half8, A4[arow * 16 + (fc ^ (arow & 15))]);
  }
#pragma unroll
  for (int j = 0; j < NT2; ++j) {
    int nt = wn * NT2 + j;
    const ushort8* bp = Wp + (size_t)(kunit * NT + nt) * 2 * 64 + lane;
    half8 bh = __builtin_bit_cast(half8, bp[0]);
    half8 bl = __builtin_bit_cast(half8, bp[64]);
#pragma unroll
    for (int mt = 0; mt < 2; ++mt) {
      acc[mt][j] = __builtin_amdgcn_mfma_f32_16x16x32_f16(a[mt], bh, acc[mt][j], 0, 0, 0);
      acc[mt][j] = __builtin_amdgcn_mfma_f32_16x16x32_f16(a[mt], bl, acc[mt][j], 0, 0, 0);
    }
  }
}

// 3-part pipelined K-loop: order per phase = {bc0, bc1, stage A[p+1]} -> vmcnt(10) retires
// previous A; consuming bc1 needs only vmcnt(2) so A[p+1] stays in flight across the phase.
// After the loop buf[0] holds part A2's tile.
__device__ __forceinline__ void gemm3_pipeline(const _Float16* A0, const _Float16* A1,
                                               const _Float16* A2, const ushort8* Wp,
                                               float4 (*buf)[1024], size_t r0,
                                               int tid, int lane, int wm, int wn,
                                               f32x4 (*acc)[2]) {
  const _Float16* Aarr[3] = {A0, A1, A2};
  stage_sp(A0 + r0 * 128, buf[0], tid);
  Bchunk bc0, bc1;
#pragma unroll
  for (int p = 0; p < 3; ++p) {
    loadB(Wp, p * 4, lane, wn, bc0);
    loadB(Wp, p * 4 + 2, lane, wn, bc1);
    if (p + 1 < 3) stage_sp(Aarr[p + 1] + r0 * 128, buf[(p + 1) & 1], tid);
    asm volatile("s_waitcnt vmcnt(10)" ::: "memory");
    __builtin_amdgcn_s_barrier();
    __builtin_amdgcn_sched_barrier(0);
    mfma_chunk(buf[p & 1], bc0, p * 4, lane, wm, acc);
    mfma_chunk(buf[p & 1], bc1, p * 4 + 2, lane, wm, acc);   // compiler waits vmcnt(2)
    __builtin_amdgcn_sched_barrier(0);
    __builtin_amdgcn_s_barrier();
  }
}

// ---------------- conv1 GEMM + fused BN partial stats (8-way replicated) ----------------
__global__ __launch_bounds__(512, 4) void conv1_gemm_kernel(
    const _Float16* __restrict__ A0, const _Float16* __restrict__ A1,
    const _Float16* __restrict__ A2,
    const ushort8* __restrict__ Wp, const float* __restrict__ bias,
    _Float16* __restrict__ Xh, float* __restrict__ stats, int n) {
  __shared__ float4 buf[2][1024];   // 32 KB
  __shared__ float sstat[256];

  int tid = threadIdx.x;
  int lane = tid & 63, wid = tid >> 6;
  int wm = wid >> 2, wn = wid & 3;
  size_t r0 = (size_t)blockIdx.x * 64;

  f32x4 acc[2][2];
#pragma unroll
  for (int mt = 0; mt < 2; ++mt)
#pragma unroll
    for (int j = 0; j < 2; ++j) acc[mt][j] = (f32x4)0.f;

  gemm3_pipeline(A0, A1, A2, Wp, buf, r0, tid, lane, wm, wn, acc);

  // epilogue: relu + f16 store + BN partial stats (LDS combine -> replicated global atomics)
  if (tid < 256) sstat[tid] = 0.f;
  __syncthreads();
#pragma unroll
  for (int mt = 0; mt < 2; ++mt) {
    int rbase = (int)r0 + wm * 32 + mt * 16 + (lane >> 4) * 4;
#pragma unroll
    for (int j = 0; j < 2; ++j) {
      int col = wn * 32 + j * 16 + (lane & 15);
      float b = bias[col];
      float sj = 0.f, qj = 0.f;
#pragma unroll
      for (int i = 0; i < 4; ++i) {
        int row = rbase + i;
        if (row < n) {
          float v = fmaxf(acc[mt][j][i] + b, 0.f);
          Xh[(size_t)row * NF + col] = (_Float16)v;
          sj += v; qj += v * v;
        }
      }
      sj += __shfl_xor(sj, 16); sj += __shfl_xor(sj, 32);
      qj += __shfl_xor(qj, 16); qj += __shfl_xor(qj, 32);
      if ((lane >> 4) == 0) {
        atomicAdd(&sstat[col], sj);
        atomicAdd(&sstat[128 + col], qj);
      }
    }
  }
  __syncthreads();
  if (tid < 256) atomicAdd(&stats[(blockIdx.x & 7) * 256 + tid], sstat[tid]);
}

// ---------------- fused tail: conv2 GEMM (parts {T1,T2,X}) + residual-from-LDS ----------------
__global__ __launch_bounds__(512, 4) void fused_tail_kernel(
    const _Float16* __restrict__ T1sp, const _Float16* __restrict__ T2sp,
    const _Float16* __restrict__ Xsp,
    const ushort8* __restrict__ Wp3, const float* __restrict__ b3,
    const ushort8* __restrict__ WpM1, const float* __restrict__ bm1,
    const ushort8* __restrict__ WpM2, const float* __restrict__ bm2,
    float* __restrict__ out, int n) {
  __shared__ float4 buf[2][1024];
  _Float16* L = (_Float16*)buf[0];

  int tid = threadIdx.x;
  int lane = tid & 63, wid = tid >> 6;
  int wm = wid >> 2, wn = wid & 3;
  size_t r0 = (size_t)blockIdx.x * 64;

  f32x4 acc[2][2];
#pragma unroll
  for (int mt = 0; mt < 2; ++mt)
#pragma unroll
    for (int j = 0; j < 2; ++j) acc[mt][j] = (f32x4)0.f;

  // ---- phase 1: conv2 GEMM over {T1sp, T2sp, Xsp}; buf[0] ends holding the X tile
  gemm3_pipeline(T1sp, T2sp, Xsp, Wp3, buf, r0, tid, lane, wm, wn, acc);

  // ---- epilogue 1: Y = relu(acc+b3) + X(LDS) -> overwrite same LDS slot with Y
#pragma unroll
  for (int mt = 0; mt < 2; ++mt) {
    int rb = wm * 32 + mt * 16 + (lane >> 4) * 4;
#pragma unroll
    for (int j = 0; j < 2; ++j) {
      int col = wn * 32 + j * 16 + (lane & 15);
      float b = b3[col];
#pragma unroll
      for (int i = 0; i < 4; ++i) {
        int lrow = rb + i;
        int off = lds_off16(lrow, col);
        float xres = (float)L[off];
        float v = fmaxf(acc[mt][j][i] + b, 0.f) + xres;
        L[off] = (_Float16)v;
      }
    }
  }
  __syncthreads();
  // ---- phase 2: H = relu(Y @ Wm1^T + bm1)
  f32x4 acc2[2][2];
#pragma unroll
  for (int mt = 0; mt < 2; ++mt)
#pragma unroll
    for (int j = 0; j < 2; ++j) acc2[mt][j] = (f32x4)0.f;
#pragma unroll
  for (int ks = 0; ks < 4; ++ks)
    gemm_step16<8, 2>(buf[0], WpM1, ks, lane, wm, wn, acc2);
  __syncthreads();   // all reads of Y done before overwrite
  // ---- epilogue 2: scatter H (f16) into LDS
#pragma unroll
  for (int mt = 0; mt < 2; ++mt) {
    int rb = wm * 32 + mt * 16 + (lane >> 4) * 4;
#pragma unroll
    for (int j = 0; j < 2; ++j) {
      int col = wn * 32 + j * 16 + (lane & 15);
      float b = bm1[col];
#pragma unroll
      for (int i = 0; i < 4; ++i) {
        float v = fmaxf(acc2[mt][j][i] + b, 0.f);
        L[lds_off16(rb + i, col)] = (_Float16)v;
      }
    }
  }
  __syncthreads();
  // ---- phase 3: out = H @ Wm2^T + bm2   (NC=64: NT=4, NT2=1)
  f32x4 acc3[2][1];
#pragma unroll
  for (int mt = 0; mt < 2; ++mt) acc3[mt][0] = (f32x4)0.f;
#pragma unroll
  for (int ks = 0; ks < 4; ++ks)
    gemm_step16<4, 1>(buf[0], WpM2, ks, lane, wm, wn, acc3);
#pragma unroll
  for (int mt = 0; mt < 2; ++mt) {
    int rb = wm * 32 + mt * 16 + (lane >> 4) * 4;
    int col = wn * 16 + (lane & 15);
    float b = bm2[col];
#pragma unroll
    for (int i = 0; i < 4; ++i) {
      int row = (int)r0 + rb + i;
      if (row < n) out[(size_t)row * 64 + col] = acc3[mt][0][i] + b;
    }
  }
}

// ---------------- BatchNorm apply: reads Xh f16, sums 8 stat replicas; emits Xsp only -------
__global__ void bn_apply_kernel(const _Float16* __restrict__ Xh, const float* __restrict__ stats,
                                const float* __restrict__ gamma, const float* __restrict__ beta,
                                _Float16* __restrict__ Xsp, float fn, int n) {
  int i = blockIdx.x * 256 + threadIdx.x;   // frag index
  if (i >= n * 16) return;
  int row = i >> 4, fc = i & 15;
  half8 xh = *(const half8*)(Xh + (size_t)row * NF + fc * 8);
  half8 hu;
  int c0 = fc * 8;
#pragma unroll
  for (int j = 0; j < 8; ++j) {
    int c = c0 + j;
    float s1 = 0.f, s2 = 0.f;
#pragma unroll
    for (int r = 0; r < 8; ++r) {
      s1 += stats[r * 256 + c];
      s2 += stats[r * 256 + NF + c];
    }
    float mu = s1 / fn;
    float var = s2 / fn - mu * mu;
    float s = gamma[c] * rsqrtf(var + 1e-5f);
    hu[j] = (_Float16)(((float)xh[j] - mu) * s + beta[c]);
  }
  int swz = (fc ^ (row & 15)) * 8;
  *(half8*)(Xsp + (size_t)row * 128 + swz) = hu;
}

// ---------------- launcher ----------------
extern "C" void kernel_launch(void* const* d_in, const int* in_sizes, int n_in,
                              void* d_out, int out_size, void* d_ws, size_t ws_size,
                              hipStream_t stream) {
  const float* feat  = (const float*)d_in[0];
  const int*   src   = (const int*)d_in[1];
  const int*   dst   = (const int*)d_in[2];
  const float* W1    = (const float*)d_in[3];
  const float* b1    = (const float*)d_in[4];
  const float* W3    = (const float*)d_in[5];
  const float* b3    = (const float*)d_in[6];
  const float* gamma = (const float*)d_in[7];
  const float* beta  = (const float*)d_in[8];
  const float* Wm1   = (const float*)d_in[9];
  const float* bm1   = (const float*)d_in[10];
  const float* Wm2   = (const float*)d_in[11];
  const float* bm2   = (const float*)d_in[12];
  int n = in_sizes[0] / NF;
  int e = in_sizes[1];

  char* p = (char*)d_ws;
  auto alloc = [&](size_t bytes) {
    char* r = p;
    p += (bytes + 255) & ~size_t(255);
    return r;
  };
  int nblk  = ceil_div(e, 4096);   // multisplit tiles
  int nbuck = ceil_div(n, 256);    // node buckets

  float* dinv     = (float*)alloc((size_t)n * 4);
  int*   offsets  = (int*)alloc((size_t)(n + 1) * 4);
  int*   counts   = (int*)alloc((size_t)nblk * nbuck * 4);
  int*   btot     = (int*)alloc((size_t)nbuck * 4);
  int*   bbase    = (int*)alloc((size_t)(nbuck + 1) * 4);
  int*   csr      = (int*)alloc((size_t)e * 4);
  float* stats    = (float*)alloc(8 * 256 * 4);
  ushort8* Wp1  = (ushort8*)alloc(12 * 8 * 2 * 64 * 16);   // K=384, NT=8
  ushort8* Wp3  = (ushort8*)alloc(12 * 8 * 2 * 64 * 16);
  ushort8* WpM1 = (ushort8*)alloc(4 * 8 * 2 * 64 * 16);    // K=128, NT=8
  ushort8* WpM2 = (ushort8*)alloc(4 * 4 * 2 * 64 * 16);    // K=128, NT=4
  size_t spb = (size_t)(n + 64) * 256;        // swz f16 rows, 64 pad rows for gload_lds
  _Float16* Fsp  = (_Float16*)alloc(spb);
  _Float16* T1sp = (_Float16*)alloc(spb);
  _Float16* T2sp = (_Float16*)alloc(spb);
  _Float16* Xsp  = (_Float16*)alloc(spb);
  _Float16* Xh   = (_Float16*)alloc((size_t)n * NF * 2);  // conv1 output (pre-BN, f16)
  int2* binned = (int2*)Fsp;   // alias: 6.4 MB scratch, dead before prep_feat writes Fsp

  hipMemsetAsync(stats, 0, 8 * 256 * 4, stream);

  int fb = ceil_div(n * 16, 256);            // frag-grid over matrices
  int sb = ceil_div(n, 4);                   // spmv: 4 nodes/block
  int gb = ceil_div(n, 64);                  // gemm: 64 rows/block, 512 threads

  // CSR build (sorted by dst) via two-level multisplit; also emits offsets/dinv
  bucket_hist_kernel<<<nblk, 256, 0, stream>>>(dst, counts, e, nblk, nbuck);
  bucket_scan_rows_kernel<<<nbuck, 256, 0, stream>>>(counts, btot, nblk);
  bucket_base_kernel<<<1, 256, 0, stream>>>(btot, bbase, nbuck, e);
  bucket_bin_kernel<<<nblk, 256, 0, stream>>>(src, dst, counts, bbase, binned, e, nblk, nbuck);
  bucket_finalize_kernel<<<nbuck, 256, 0, stream>>>(binned, bbase, offsets, csr, dinv, n, e, nbuck);

  // W split+pack (f16 hi/lo; W3 rotated for part order {T1,T2,X})
  pack_all_kernel<<<120, 256, 0, stream>>>(W1, Wp1, W3, Wp3, Wm1, WpM1, Wm2, WpM2);

  // conv1: T1 = -A^ F ; T2 = -2 A^ T1 - F ; Xh = f16(relu([F,T1,T2] @ W1^T + b1))  (+BN stats)
  prep_feat_kernel<<<fb, 256, 0, stream>>>(feat, Fsp, n);
  spmv_kernel<<<sb, 256, 0, stream>>>(Fsp, dinv, offsets, csr, nullptr, -1.f, 0.f, T1sp, n);
  spmv_kernel<<<sb, 256, 0, stream>>>(T1sp, dinv, offsets, csr, Fsp, -2.f, -1.f, T2sp, n);
  conv1_gemm_kernel<<<gb, 512, 0, stream>>>(Fsp, T1sp, T2sp, Wp1, b1, Xh, stats, n);

  // BatchNorm apply (inline from replicated stats); emits Xsp
  bn_apply_kernel<<<fb, 256, 0, stream>>>(Xh, stats, gamma, beta, Xsp, (float)n, n);

  // conv2 spmvs (gather/z from swizzled buffers directly)
  spmv_kernel<<<sb, 256, 0, stream>>>(Xsp, dinv, offsets, csr, nullptr, -1.f, 0.f, T1sp, n);
  spmv_kernel<<<sb, 256, 0, stream>>>(T1sp, dinv, offsets, csr, Xsp, -2.f, -1.f, T2sp, n);

  // fused conv2-GEMM (parts {T1,T2,X}) + residual-from-LDS + MLP1 + MLP2
  fused_tail_kernel<<<gb, 512, 0, stream>>>(T1sp, T2sp, Xsp, Wp3, b3, WpM1, bm1,
                                            WpM2, bm2, (float*)d_out, n);
}

// Round 17
// 254.120 us; speedup vs baseline: 1.3369x; 1.0027x over previous
//
#include <hip/hip_runtime.h>
#include <hip/hip_bf16.h>
#include <math.h>

#define NF 128   // IN_F == HID == 128

typedef unsigned short ushort8 __attribute__((ext_vector_type(8)));
typedef float f32x4 __attribute__((ext_vector_type(4)));
typedef _Float16 half8 __attribute__((ext_vector_type(8)));

static inline int ceil_div(int a, int b) { return (a + b - 1) / b; }

// ================= CSR build: two-level multisplit counting sort =================
__global__ __launch_bounds__(256) void bucket_hist_kernel(const int* __restrict__ dst,
                                                          int* __restrict__ counts,
                                                          int e, int nblk, int nbuck) {
  __shared__ int h[256];
  int t = threadIdx.x, blk = blockIdx.x;
  h[t] = 0;
  __syncthreads();
  int base = blk * 4096;
#pragma unroll
  for (int k = 0; k < 16; ++k) {
    int i = base + k * 256 + t;
    if (i < e) atomicAdd(&h[dst[i] >> 8], 1);
  }
  __syncthreads();
  for (int b = t; b < nbuck; b += 256) counts[b * nblk + blk] = h[b];
}

__global__ __launch_bounds__(256) void bucket_scan_rows_kernel(int* __restrict__ counts,
                                                               int* __restrict__ btot,
                                                               int nblk) {
  __shared__ int sh[256];
  int b = blockIdx.x, t = threadIdx.x;
  int* row = counts + (size_t)b * nblk;
  int carry = 0;
  for (int base = 0; base < nblk; base += 256) {
    int v = (base + t < nblk) ? row[base + t] : 0;
    sh[t] = v;
    __syncthreads();
    for (int off = 1; off < 256; off <<= 1) {
      int add = (t >= off) ? sh[t - off] : 0;
      __syncthreads();
      sh[t] += add;
      __syncthreads();
    }
    if (base + t < nblk) row[base + t] = carry + sh[t] - v;
    carry += sh[255];
    __syncthreads();
  }
  if (t == 0) btot[b] = carry;
}

__global__ __launch_bounds__(256) void bucket_base_kernel(const int* __restrict__ btot,
                                                          int* __restrict__ bbase,
                                                          int nbuck, int e) {
  __shared__ int sh[256];
  __shared__ int carry;
  int t = threadIdx.x;
  if (t == 0) carry = 0;
  __syncthreads();
  for (int base = 0; base < nbuck; base += 256) {
    int v = (base + t < nbuck) ? btot[base + t] : 0;
    sh[t] = v;
    __syncthreads();
    for (int off = 1; off < 256; off <<= 1) {
      int add = (t >= off) ? sh[t - off] : 0;
      __syncthreads();
      sh[t] += add;
      __syncthreads();
    }
    if (base + t < nbuck) bbase[base + t] = carry + sh[t] - v;
    __syncthreads();
    if (t == 0) carry += sh[255];
    __syncthreads();
  }
  if (t == 0) bbase[nbuck] = e;
}

// binned word: (dst&255)<<16 | src   (valid because N < 65536)
__global__ __launch_bounds__(256) void bucket_bin_kernel(const int* __restrict__ src,
                                                         const int* __restrict__ dst,
                                                         const int* __restrict__ counts,
                                                         const int* __restrict__ bbase,
                                                         unsigned int* __restrict__ binned,
                                                         int e, int nblk, int nbuck) {
  __shared__ int cur[256];
  int t = threadIdx.x, blk = blockIdx.x;
  for (int b = t; b < nbuck; b += 256) cur[b] = counts[b * nblk + blk] + bbase[b];
  __syncthreads();
  int base = blk * 4096;
#pragma unroll
  for (int k = 0; k < 16; ++k) {
    int i = base + k * 256 + t;
    if (i < e) {
      int d = dst[i];
      int pos = atomicAdd(&cur[d >> 8], 1);
      binned[pos] = ((unsigned)(d & 255) << 16) | (unsigned)src[i];
    }
  }
}

__global__ __launch_bounds__(256) void bucket_finalize_kernel(const unsigned int* __restrict__ binned,
                                                              const int* __restrict__ bbase,
                                                              int* __restrict__ offsets,
                                                              int* __restrict__ csr,
                                                              float* __restrict__ dinv,
                                                              int n, int e, int nbuck) {
  __shared__ int deg[256];
  __shared__ int offs[256];
  __shared__ int cur[256];
  int b = blockIdx.x, t = threadIdx.x;
  int ebeg = bbase[b];
  int eend = bbase[b + 1];
  deg[t] = 0;
  __syncthreads();
  for (int j = ebeg + t; j < eend; j += 256) atomicAdd(&deg[binned[j] >> 16], 1);
  __syncthreads();
  int v = deg[t];
  offs[t] = v;
  __syncthreads();
  for (int off = 1; off < 256; off <<= 1) {
    int add = (t >= off) ? offs[t - off] : 0;
    __syncthreads();
    offs[t] += add;
    __syncthreads();
  }
  int excl = offs[t] - v;
  cur[t] = excl;
  int node = b * 256 + t;
  if (node < n) {
    offsets[node] = ebeg + excl;
    float d = (float)(v > 1 ? v : 1);
    dinv[node] = rsqrtf(d);
  }
  if (b == nbuck - 1 && t == 0) offsets[n] = e;
  __syncthreads();
  for (int j = ebeg + t; j < eend; j += 256) {
    unsigned int pr = binned[j];
    int pos = atomicAdd(&cur[pr >> 16], 1);
    csr[ebeg + pos] = (int)(pr & 0xFFFFu);
  }
}

// ============== swz-f16 row layout (256 B): 16 frags of 8 f16, frag slot fc^(row&15) ========

// ---------------- prep_feat: emits Fsp (swz f16) only ----------------
__global__ void prep_feat_kernel(const float* __restrict__ feat,
                                 _Float16* __restrict__ Fsp, int n) {
  int i = blockIdx.x * 256 + threadIdx.x;   // frag index
  if (i >= n * 16) return;
  int row = i >> 4, fc = i & 15;
  const float4* s = (const float4*)(feat + (size_t)row * NF + fc * 8);
  float4 a = s[0], b = s[1];
  float xv[8] = {a.x, a.y, a.z, a.w, b.x, b.y, b.z, b.w};
  half8 f;
#pragma unroll
  for (int j = 0; j < 8; ++j) f[j] = (_Float16)xv[j];
  int swz = (fc ^ (row & 15)) * 8;
  *(half8*)(Fsp + (size_t)row * 128 + swz) = f;
}

// ---------------- SpMV: gathers swizzled f16 rows with per-edge dinv weight ----------------
__global__ __launch_bounds__(256) void spmv_kernel(
    const _Float16* __restrict__ xsp, const float* __restrict__ dinv,
    const int* __restrict__ offsets, const int* __restrict__ csr,
    const _Float16* __restrict__ zsp, float a, float bz,
    _Float16* __restrict__ outsp, int n) {
  int w = threadIdx.x >> 6, lane = threadIdx.x & 63;
  int node = blockIdx.x * 4 + w;
  if (node >= n) return;
  int beg = __builtin_amdgcn_readfirstlane(offsets[node]);
  int end = __builtin_amdgcn_readfirstlane(offsets[node + 1]);
  int eh = lane >> 4;        // which edge of the quad (0..3)
  int cq = lane & 15;        // frag index within the row

  float acc[8];
#pragma unroll
  for (int j = 0; j < 8; ++j) acc[j] = 0.f;

  int e2 = beg;
  for (; e2 + 8 <= end; e2 += 8) {
    int s0 = csr[e2 + eh];
    int s1 = csr[e2 + 4 + eh];
    float w0 = dinv[s0], w1 = dinv[s1];
    half8 g0 = *(const half8*)(xsp + (size_t)s0 * 128 + ((cq ^ (s0 & 15)) << 3));
    half8 g1 = *(const half8*)(xsp + (size_t)s1 * 128 + ((cq ^ (s1 & 15)) << 3));
#pragma unroll
    for (int j = 0; j < 8; ++j) acc[j] += w0 * (float)g0[j];
#pragma unroll
    for (int j = 0; j < 8; ++j) acc[j] += w1 * (float)g1[j];
  }
  for (; e2 + 4 <= end; e2 += 4) {
    int s0 = csr[e2 + eh];
    float w0 = dinv[s0];
    half8 g0 = *(const half8*)(xsp + (size_t)s0 * 128 + ((cq ^ (s0 & 15)) << 3));
#pragma unroll
    for (int j = 0; j < 8; ++j) acc[j] += w0 * (float)g0[j];
  }
  int rem = end - e2;
  if (eh < rem) {
    int s0 = csr[e2 + eh];
    float w0 = dinv[s0];
    half8 g0 = *(const half8*)(xsp + (size_t)s0 * 128 + ((cq ^ (s0 & 15)) << 3));
#pragma unroll
    for (int j = 0; j < 8; ++j) acc[j] += w0 * (float)g0[j];
  }
#pragma unroll
  for (int j = 0; j < 8; ++j) {
    acc[j] += __shfl_xor(acc[j], 16);
    acc[j] += __shfl_xor(acc[j], 32);
  }
  if (eh == 0) {
    float dv = a * dinv[node];
    float v[8];
#pragma unroll
    for (int j = 0; j < 8; ++j) v[j] = dv * acc[j];
    int swz = (cq ^ (node & 15)) << 3;
    if (zsp) {
      half8 zz = *(const half8*)(zsp + (size_t)node * 128 + swz);
#pragma unroll
      for (int j = 0; j < 8; ++j) v[j] += bz * (float)zz[j];
    }
    half8 ho;
#pragma unroll
    for (int j = 0; j < 8; ++j) ho[j] = (_Float16)v[j];
    *(half8*)(outsp + (size_t)node * 128 + swz) = ho;
  }
}

// ---------------- W pre-split (f16 hi/lo) + frag-pack, with kunit rotation ----------------
__device__ __forceinline__ void pack_one(const float* __restrict__ W, ushort8* __restrict__ Wp,
                                         int f, int NT, int K, int rot) {
  int lane = f & 63;
  int hl = (f >> 6) & 1;
  int rest = f >> 7;
  int nt = rest % NT;
  int kunit = rest / NT;
  int nK = K >> 5;
  int srcKunit = (kunit + rot) % nK;
  int nrow = nt * 16 + (lane & 15);
  int k0 = srcKunit * 32 + (lane >> 4) * 8;
  const float* srcp = W + (size_t)nrow * K + k0;
  ushort8 v;
#pragma unroll
  for (int j = 0; j < 8; ++j) {
    float x = srcp[j];
    _Float16 h = (_Float16)x;
    if (hl) h = (_Float16)(x - (float)h);
    v[j] = __builtin_bit_cast(unsigned short, h);
  }
  Wp[f] = v;
}

__global__ void pack_all_kernel(const float* __restrict__ W1, ushort8* __restrict__ P1,
                                const float* __restrict__ W3, ushort8* __restrict__ P3,
                                const float* __restrict__ Wm1, ushort8* __restrict__ PM1,
                                const float* __restrict__ Wm2, ushort8* __restrict__ PM2) {
  int f = blockIdx.x * 256 + threadIdx.x;
  if (f < 12288) pack_one(W1, P1, f, 8, 384, 0);
  else if (f < 24576) pack_one(W3, P3, f - 12288, 8, 384, 4);   // parts {T1,T2,X}
  else if (f < 28672) pack_one(Wm1, PM1, f - 24576, 8, 128, 0);
  else if (f < 30720) pack_one(Wm2, PM2, f - 28672, 4, 128, 0);
}

// ================= GEMM machinery (f16 A single, f16 W hi+lo) =================

__device__ __forceinline__ void stage_sp(const _Float16* gsrc, float4* lbuf, int tid) {
  const char* g = (const char*)gsrc;
  char* l = (char*)lbuf;
#pragma unroll
  for (int k = 0; k < 2; ++k) {
    int off = k * 8192 + tid * 16;
    __builtin_amdgcn_global_load_lds(
        (const __attribute__((address_space(1))) void*)(g + off),
        (__attribute__((address_space(3))) void*)(l + off), 16, 0, 0);
  }
}

__device__ __forceinline__ int lds_off16(int row, int col) {
  return row * 128 + (((col >> 3) ^ (row & 15)) << 3) + (col & 7);
}

// B chunk: 2 kunits x NT2=2 n-tiles x (hi,lo) = 8 frags = 32 VGPR
struct Bchunk {
  ushort8 h[2][2];
  ushort8 l[2][2];
};

__device__ __forceinline__ void loadB(const ushort8* __restrict__ Wp, int kunit0,
                                      int lane, int wn, Bchunk& c) {
#pragma unroll
  for (int k2 = 0; k2 < 2; ++k2) {
#pragma unroll
    for (int j = 0; j < 2; ++j) {
      const ushort8* bp = Wp + (size_t)((kunit0 + k2) * 8 + wn * 2 + j) * 128 + lane;
      c.h[k2][j] = bp[0];
      c.l[k2][j] = bp[64];
    }
  }
}

// MFMA one B-chunk: 2 kunits x 2 mt x 2 j x 2 terms = 16 MFMAs
__device__ __forceinline__ void mfma_chunk(const float4* A4, const Bchunk& c, int kbase,
                                           int lane, int wm, f32x4 (*acc)[2]) {
#pragma unroll
  for (int k2 = 0; k2 < 2; ++k2) {
    int kunit = kbase + k2;
    half8 a[2];
#pragma unroll
    for (int mt = 0; mt < 2; ++mt) {
      int arow = wm * 32 + mt * 16 + (lane & 15);
      int fc = (kunit & 3) * 4 + (lane >> 4);
      a[mt] = __builtin_bit_cast(half8, A4[arow * 16 + (fc ^ (arow & 15))]);
    }
#pragma unroll
    for (int j = 0; j < 2; ++j) {
      half8 bh = __builtin_bit_cast(half8, c.h[k2][j]);
      half8 bl = __builtin_bit_cast(half8, c.l[k2][j]);
#pragma unroll
      for (int mt = 0; mt < 2; ++mt) {
        acc[mt][j] = __builtin_amdgcn_mfma_f32_16x16x32_f16(a[mt], bh, acc[mt][j], 0, 0, 0);
        acc[mt][j] = __builtin_amdgcn_mfma_f32_16x16x32_f16(a[mt], bl, acc[mt][j], 0, 0, 0);
      }
    }
  }
}

// generic gemm_step for the MLP phases (A = f16 LDS tile, B compiler-managed)
template<int NT, int NT2>
__device__ __forceinline__ void gemm_step16(const float4* A4, const ushort8* __restrict__ Wp,
                                            int kunit, int lane, int wm, int wn,
                                            f32x4 (*acc)[NT2]) {
  half8 a[2];
#pragma unroll
  for (int mt = 0; mt < 2; ++mt) {
    int arow = wm * 32 + mt * 16 + (lane & 15);
    int fc = (kunit & 3) * 4 + (lane >> 4);
    a[mt] = __builtin_bit_cast(half8, A4[arow * 16 + (fc ^ (arow & 15))]);
  }
#pragma unroll
  for (int j = 0; j < NT2; ++j) {
    int nt = wn * NT2 + j;
    const ushort8* bp = Wp + (size_t)(kunit * NT + nt) * 2 * 64 + lane;
    half8 bh = __builtin_bit_cast(half8, bp[0]);
    half8 bl = __builtin_bit_cast(half8, bp[64]);
#pragma unroll
    for (int mt = 0; mt < 2; ++mt) {
      acc[mt][j] = __builtin_amdgcn_mfma_f32_16x16x32_f16(a[mt], bh, acc[mt][j], 0, 0, 0);
      acc[mt][j] = __builtin_amdgcn_mfma_f32_16x16x32_f16(a[mt], bl, acc[mt][j], 0, 0, 0);
    }
  }
}

// 3-part pipelined K-loop
__device__ __forceinline__ void gemm3_pipeline(const _Float16* A0, const _Float16* A1,
                                               const _Float16* A2, const ushort8* Wp,
                                               float4 (*buf)[1024], size_t r0,
                                               int tid, int lane, int wm, int wn,
                                               f32x4 (*acc)[2]) {
  const _Float16* Aarr[3] = {A0, A1, A2};
  stage_sp(A0 + r0 * 128, buf[0], tid);
  Bchunk bc0, bc1;
#pragma unroll
  for (int p = 0; p < 3; ++p) {
    loadB(Wp, p * 4, lane, wn, bc0);
    loadB(Wp, p * 4 + 2, lane, wn, bc1);
    if (p + 1 < 3) stage_sp(Aarr[p + 1] + r0 * 128, buf[(p + 1) & 1], tid);
    asm volatile("s_waitcnt vmcnt(10)" ::: "memory");
    __builtin_amdgcn_s_barrier();
    __builtin_amdgcn_sched_barrier(0);
    mfma_chunk(buf[p & 1], bc0, p * 4, lane, wm, acc);
    mfma_chunk(buf[p & 1], bc1, p * 4 + 2, lane, wm, acc);   // compiler waits vmcnt(2)
    __builtin_amdgcn_sched_barrier(0);
    __builtin_amdgcn_s_barrier();
  }
}

// ---------------- conv1 GEMM + fused BN partial stats; writes PRE-BN Xsp (swizzled) --------
__global__ __launch_bounds__(512, 4) void conv1_gemm_kernel(
    const _Float16* __restrict__ A0, const _Float16* __restrict__ A1,
    const _Float16* __restrict__ A2,
    const ushort8* __restrict__ Wp, const float* __restrict__ bias,
    _Float16* __restrict__ Xsp, float* __restrict__ stats, int n) {
  __shared__ float4 buf[2][1024];   // 32 KB
  __shared__ float sstat[256];

  int tid = threadIdx.x;
  int lane = tid & 63, wid = tid >> 6;
  int wm = wid >> 2, wn = wid & 3;
  size_t r0 = (size_t)blockIdx.x * 64;

  f32x4 acc[2][2];
#pragma unroll
  for (int mt = 0; mt < 2; ++mt)
#pragma unroll
    for (int j = 0; j < 2; ++j) acc[mt][j] = (f32x4)0.f;

  gemm3_pipeline(A0, A1, A2, Wp, buf, r0, tid, lane, wm, wn, acc);

  // epilogue: relu + swizzled f16 store + BN partial stats
  if (tid < 256) sstat[tid] = 0.f;
  __syncthreads();
#pragma unroll
  for (int mt = 0; mt < 2; ++mt) {
    int rbase = (int)r0 + wm * 32 + mt * 16 + (lane >> 4) * 4;
#pragma unroll
    for (int j = 0; j < 2; ++j) {
      int col = wn * 32 + j * 16 + (lane & 15);
      float b = bias[col];
      float sj = 0.f, qj = 0.f;
#pragma unroll
      for (int i = 0; i < 4; ++i) {
        int row = rbase + i;
        if (row < n) {
          float v = fmaxf(acc[mt][j][i] + b, 0.f);
          Xsp[(size_t)row * 128 + (((col >> 3) ^ (row & 15)) << 3) + (col & 7)] = (_Float16)v;
          sj += v; qj += v * v;
        }
      }
      sj += __shfl_xor(sj, 16); sj += __shfl_xor(sj, 32);
      qj += __shfl_xor(qj, 16); qj += __shfl_xor(qj, 32);
      if ((lane >> 4) == 0) {
        atomicAdd(&sstat[col], sj);
        atomicAdd(&sstat[128 + col], qj);
      }
    }
  }
  __syncthreads();
  if (tid < 256) atomicAdd(&stats[(blockIdx.x & 7) * 256 + tid], sstat[tid]);
}

// ---------------- fused tail: conv2 GEMM (parts {T1,T2,X}) + residual-from-LDS ----------------
__global__ __launch_bounds__(512, 4) void fused_tail_kernel(
    const _Float16* __restrict__ T1sp, const _Float16* __restrict__ T2sp,
    const _Float16* __restrict__ Xsp,
    const ushort8* __restrict__ Wp3, const float* __restrict__ b3,
    const ushort8* __restrict__ WpM1, const float* __restrict__ bm1,
    const ushort8* __restrict__ WpM2, const float* __restrict__ bm2,
    float* __restrict__ out, int n) {
  __shared__ float4 buf[2][1024];
  _Float16* L = (_Float16*)buf[0];

  int tid = threadIdx.x;
  int lane = tid & 63, wid = tid >> 6;
  int wm = wid >> 2, wn = wid & 3;
  size_t r0 = (size_t)blockIdx.x * 64;

  f32x4 acc[2][2];
#pragma unroll
  for (int mt = 0; mt < 2; ++mt)
#pragma unroll
    for (int j = 0; j < 2; ++j) acc[mt][j] = (f32x4)0.f;

  // ---- phase 1: conv2 GEMM over {T1sp, T2sp, Xsp}; buf[0] ends holding the X tile
  gemm3_pipeline(T1sp, T2sp, Xsp, Wp3, buf, r0, tid, lane, wm, wn, acc);

  // ---- epilogue 1: Y = relu(acc+b3) + X(LDS) -> overwrite same LDS slot with Y
#pragma unroll
  for (int mt = 0; mt < 2; ++mt) {
    int rb = wm * 32 + mt * 16 + (lane >> 4) * 4;
#pragma unroll
    for (int j = 0; j < 2; ++j) {
      int col = wn * 32 + j * 16 + (lane & 15);
      float b = b3[col];
#pragma unroll
      for (int i = 0; i < 4; ++i) {
        int lrow = rb + i;
        int off = lds_off16(lrow, col);
        float xres = (float)L[off];
        float v = fmaxf(acc[mt][j][i] + b, 0.f) + xres;
        L[off] = (_Float16)v;
      }
    }
  }
  __syncthreads();
  // ---- phase 2: H = relu(Y @ Wm1^T + bm1)
  f32x4 acc2[2][2];
#pragma unroll
  for (int mt = 0; mt < 2; ++mt)
#pragma unroll
    for (int j = 0; j < 2; ++j) acc2[mt][j] = (f32x4)0.f;
#pragma unroll
  for (int ks = 0; ks < 4; ++ks)
    gemm_step16<8, 2>(buf[0], WpM1, ks, lane, wm, wn, acc2);
  __syncthreads();   // all reads of Y done before overwrite
  // ---- epilogue 2: scatter H (f16) into LDS
#pragma unroll
  for (int mt = 0; mt < 2; ++mt) {
    int rb = wm * 32 + mt * 16 + (lane >> 4) * 4;
#pragma unroll
    for (int j = 0; j < 2; ++j) {
      int col = wn * 32 + j * 16 + (lane & 15);
      float b = bm1[col];
#pragma unroll
      for (int i = 0; i < 4; ++i) {
        float v = fmaxf(acc2[mt][j][i] + b, 0.f);
        L[lds_off16(rb + i, col)] = (_Float16)v;
      }
    }
  }
  __syncthreads();
  // ---- phase 3: out = H @ Wm2^T + bm2   (NC=64: NT=4, NT2=1)
  f32x4 acc3[2][1];
#pragma unroll
  for (int mt = 0; mt < 2; ++mt) acc3[mt][0] = (f32x4)0.f;
#pragma unroll
  for (int ks = 0; ks < 4; ++ks)
    gemm_step16<4, 1>(buf[0], WpM2, ks, lane, wm, wn, acc3);
#pragma unroll
  for (int mt = 0; mt < 2; ++mt) {
    int rb = wm * 32 + mt * 16 + (lane >> 4) * 4;
    int col = wn * 16 + (lane & 15);
    float b = bm2[col];
#pragma unroll
    for (int i = 0; i < 4; ++i) {
      int row = (int)r0 + rb + i;
      if (row < n) out[(size_t)row * 64 + col] = acc3[mt][0][i] + b;
    }
  }
}

// ---------------- BatchNorm apply IN PLACE on swizzled Xsp ----------------
__global__ void bn_apply_kernel(_Float16* __restrict__ Xsp, const float* __restrict__ stats,
                                const float* __restrict__ gamma, const float* __restrict__ beta,
                                float fn, int n) {
  int i = blockIdx.x * 256 + threadIdx.x;   // frag index
  if (i >= n * 16) return;
  int row = i >> 4, fc = i & 15;
  int swz = (fc ^ (row & 15)) * 8;
  half8* xp = (half8*)(Xsp + (size_t)row * 128 + swz);
  half8 xh = *xp;
  half8 hu;
  int c0 = fc * 8;
#pragma unroll
  for (int j = 0; j < 8; ++j) {
    int c = c0 + j;
    float s1 = 0.f, s2 = 0.f;
#pragma unroll
    for (int r = 0; r < 8; ++r) {
      s1 += stats[r * 256 + c];
      s2 += stats[r * 256 + NF + c];
    }
    float mu = s1 / fn;
    float var = s2 / fn - mu * mu;
    float s = gamma[c] * rsqrtf(var + 1e-5f);
    hu[j] = (_Float16)(((float)xh[j] - mu) * s + beta[c]);
  }
  *xp = hu;
}

// ---------------- launcher ----------------
extern "C" void kernel_launch(void* const* d_in, const int* in_sizes, int n_in,
                              void* d_out, int out_size, void* d_ws, size_t ws_size,
                              hipStream_t stream) {
  const float* feat  = (const float*)d_in[0];
  const int*   src   = (const int*)d_in[1];
  const int*   dst   = (const int*)d_in[2];
  const float* W1    = (const float*)d_in[3];
  const float* b1    = (const float*)d_in[4];
  const float* W3    = (const float*)d_in[5];
  const float* b3    = (const float*)d_in[6];
  const float* gamma = (const float*)d_in[7];
  const float* beta  = (const float*)d_in[8];
  const float* Wm1   = (const float*)d_in[9];
  const float* bm1   = (const float*)d_in[10];
  const float* Wm2   = (const float*)d_in[11];
  const float* bm2   = (const float*)d_in[12];
  int n = in_sizes[0] / NF;
  int e = in_sizes[1];

  char* p = (char*)d_ws;
  auto alloc = [&](size_t bytes) {
    char* r = p;
    p += (bytes + 255) & ~size_t(255);
    return r;
  };
  int nblk  = ceil_div(e, 4096);   // multisplit tiles
  int nbuck = ceil_div(n, 256);    // node buckets

  float* dinv     = (float*)alloc((size_t)n * 4);
  int*   offsets  = (int*)alloc((size_t)(n + 1) * 4);
  int*   counts   = (int*)alloc((size_t)nblk * nbuck * 4);
  int*   btot     = (int*)alloc((size_t)nbuck * 4);
  int*   bbase    = (int*)alloc((size_t)(nbuck + 1) * 4);
  int*   csr      = (int*)alloc((size_t)e * 4);
  float* stats    = (float*)alloc(8 * 256 * 4);
  ushort8* Wp1  = (ushort8*)alloc(12 * 8 * 2 * 64 * 16);   // K=384, NT=8
  ushort8* Wp3  = (ushort8*)alloc(12 * 8 * 2 * 64 * 16);
  ushort8* WpM1 = (ushort8*)alloc(4 * 8 * 2 * 64 * 16);    // K=128, NT=8
  ushort8* WpM2 = (ushort8*)alloc(4 * 4 * 2 * 64 * 16);    // K=128, NT=4
  size_t spb = (size_t)(n + 64) * 256;        // swz f16 rows, 64 pad rows for gload_lds
  _Float16* Fsp  = (_Float16*)alloc(spb);
  _Float16* T1sp = (_Float16*)alloc(spb);
  _Float16* T2sp = (_Float16*)alloc(spb);
  _Float16* Xsp  = (_Float16*)alloc(spb);
  unsigned int* binned = (unsigned int*)Fsp;   // alias: 3.2 MB scratch, dead before prep_feat

  hipMemsetAsync(stats, 0, 8 * 256 * 4, stream);

  int fb = ceil_div(n * 16, 256);            // frag-grid over matrices
  int sb = ceil_div(n, 4);                   // spmv: 4 nodes/block
  int gb = ceil_div(n, 64);                  // gemm: 64 rows/block, 512 threads

  // CSR build (sorted by dst) via two-level multisplit; also emits offsets/dinv
  bucket_hist_kernel<<<nblk, 256, 0, stream>>>(dst, counts, e, nblk, nbuck);
  bucket_scan_rows_kernel<<<nbuck, 256, 0, stream>>>(counts, btot, nblk);
  bucket_base_kernel<<<1, 256, 0, stream>>>(btot, bbase, nbuck, e);
  bucket_bin_kernel<<<nblk, 256, 0, stream>>>(src, dst, counts, bbase, binned, e, nblk, nbuck);
  bucket_finalize_kernel<<<nbuck, 256, 0, stream>>>(binned, bbase, offsets, csr, dinv, n, e, nbuck);

  // W split+pack (f16 hi/lo; W3 rotated for part order {T1,T2,X})
  pack_all_kernel<<<120, 256, 0, stream>>>(W1, Wp1, W3, Wp3, Wm1, WpM1, Wm2, WpM2);

  // conv1: T1 = -A^ F ; T2 = -2 A^ T1 - F ; Xsp = swz f16(relu([F,T1,T2] @ W1^T + b1))
  prep_feat_kernel<<<fb, 256, 0, stream>>>(feat, Fsp, n);
  spmv_kernel<<<sb, 256, 0, stream>>>(Fsp, dinv, offsets, csr, nullptr, -1.f, 0.f, T1sp, n);
  spmv_kernel<<<sb, 256, 0, stream>>>(T1sp, dinv, offsets, csr, Fsp, -2.f, -1.f, T2sp, n);
  conv1_gemm_kernel<<<gb, 512, 0, stream>>>(Fsp, T1sp, T2sp, Wp1, b1, Xsp, stats, n);

  // BatchNorm apply in place on Xsp (inline from replicated stats)
  bn_apply_kernel<<<fb, 256, 0, stream>>>(Xsp, stats, gamma, beta, (float)n, n);

  // conv2 spmvs (gather/z from swizzled buffers directly)
  spmv_kernel<<<sb, 256, 0, stream>>>(Xsp, dinv, offsets, csr, nullptr, -1.f, 0.f, T1sp, n);
  spmv_kernel<<<sb, 256, 0, stream>>>(T1sp, dinv, offsets, csr, Xsp, -2.f, -1.f, T2sp, n);

  // fused conv2-GEMM (parts {T1,T2,X}) + residual-from-LDS + MLP1 + MLP2
  fused_tail_kernel<<<gb, 512, 0, stream>>>(T1sp, T2sp, Xsp, Wp3, b3, WpM1, bm1,
                                            WpM2, bm2, (float*)d_out, n);
}

// Round 18
// 251.706 us; speedup vs baseline: 1.3498x; 1.0096x over previous
//
#include <hip/hip_runtime.h>
#include <hip/hip_bf16.h>
#include <math.h>

#define NF 128   // IN_F == HID == 128

typedef unsigned short ushort8 __attribute__((ext_vector_type(8)));
typedef float f32x4 __attribute__((ext_vector_type(4)));
typedef _Float16 half8 __attribute__((ext_vector_type(8)));

static inline int ceil_div(int a, int b) { return (a + b - 1) / b; }

// ================= CSR build: two-level multisplit counting sort =================
// NOTE: assumes nbuck <= 256 (N <= 65536), true here (N=50000 -> nbuck=196).
__global__ __launch_bounds__(256) void bucket_hist_kernel(const int* __restrict__ dst,
                                                          int* __restrict__ counts,
                                                          int e, int nblk, int nbuck) {
  __shared__ int h[256];
  int t = threadIdx.x, blk = blockIdx.x;
  h[t] = 0;
  __syncthreads();
  int base = blk * 4096;
#pragma unroll
  for (int k = 0; k < 16; ++k) {
    int i = base + k * 256 + t;
    if (i < e) atomicAdd(&h[dst[i] >> 8], 1);
  }
  __syncthreads();
  for (int b = t; b < nbuck; b += 256) counts[b * nblk + blk] = h[b];
}

__global__ __launch_bounds__(256) void bucket_scan_rows_kernel(int* __restrict__ counts,
                                                               int* __restrict__ btot,
                                                               int nblk) {
  __shared__ int sh[256];
  int b = blockIdx.x, t = threadIdx.x;
  int* row = counts + (size_t)b * nblk;
  int carry = 0;
  for (int base = 0; base < nblk; base += 256) {
    int v = (base + t < nblk) ? row[base + t] : 0;
    sh[t] = v;
    __syncthreads();
    for (int off = 1; off < 256; off <<= 1) {
      int add = (t >= off) ? sh[t - off] : 0;
      __syncthreads();
      sh[t] += add;
      __syncthreads();
    }
    if (base + t < nblk) row[base + t] = carry + sh[t] - v;
    carry += sh[255];
    __syncthreads();
  }
  if (t == 0) btot[b] = carry;
}

// binned word: (dst&255)<<16 | src   (valid because N < 65536)
// bbase computed locally from btot (inclusive LDS scan).
__global__ __launch_bounds__(256) void bucket_bin_kernel(const int* __restrict__ src,
                                                         const int* __restrict__ dst,
                                                         const int* __restrict__ counts,
                                                         const int* __restrict__ btot,
                                                         unsigned int* __restrict__ binned,
                                                         int e, int nblk, int nbuck) {
  __shared__ int sh[256];
  __shared__ int cur[256];
  int t = threadIdx.x, blk = blockIdx.x;
  int v = (t < nbuck) ? btot[t] : 0;
  sh[t] = v;
  __syncthreads();
  for (int off = 1; off < 256; off <<= 1) {
    int add = (t >= off) ? sh[t - off] : 0;
    __syncthreads();
    sh[t] += add;
    __syncthreads();
  }
  if (t < nbuck) cur[t] = counts[(size_t)t * nblk + blk] + (sh[t] - v);   // + exclusive base
  __syncthreads();
  int base = blk * 4096;
#pragma unroll
  for (int k = 0; k < 16; ++k) {
    int i = base + k * 256 + t;
    if (i < e) {
      int d = dst[i];
      int pos = atomicAdd(&cur[d >> 8], 1);
      binned[pos] = ((unsigned)(d & 255) << 16) | (unsigned)src[i];
    }
  }
}

__global__ __launch_bounds__(256) void bucket_finalize_kernel(const unsigned int* __restrict__ binned,
                                                              const int* __restrict__ btot,
                                                              int* __restrict__ offsets,
                                                              int* __restrict__ csr,
                                                              float* __restrict__ dinv,
                                                              int n, int e, int nbuck) {
  __shared__ int sh[256];
  __shared__ int deg[256];
  __shared__ int offs[256];
  __shared__ int cur[256];
  __shared__ int sbeg, send;
  int b = blockIdx.x, t = threadIdx.x;
  // local inclusive scan of btot -> ebeg/eend for this bucket
  int v0 = (t < nbuck) ? btot[t] : 0;
  sh[t] = v0;
  __syncthreads();
  for (int off = 1; off < 256; off <<= 1) {
    int add = (t >= off) ? sh[t - off] : 0;
    __syncthreads();
    sh[t] += add;
    __syncthreads();
  }
  if (t == 0) { sbeg = (b > 0) ? sh[b - 1] : 0; send = sh[b]; }
  deg[t] = 0;
  __syncthreads();
  int ebeg = sbeg, eend = send;
  for (int j = ebeg + t; j < eend; j += 256) atomicAdd(&deg[binned[j] >> 16], 1);
  __syncthreads();
  int v = deg[t];
  offs[t] = v;
  __syncthreads();
  for (int off = 1; off < 256; off <<= 1) {
    int add = (t >= off) ? offs[t - off] : 0;
    __syncthreads();
    offs[t] += add;
    __syncthreads();
  }
  int excl = offs[t] - v;
  cur[t] = excl;
  int node = b * 256 + t;
  if (node < n) {
    offsets[node] = ebeg + excl;
    float d = (float)(v > 1 ? v : 1);
    dinv[node] = rsqrtf(d);
  }
  if (b == nbuck - 1 && t == 0) offsets[n] = e;
  __syncthreads();
  for (int j = ebeg + t; j < eend; j += 256) {
    unsigned int pr = binned[j];
    int pos = atomicAdd(&cur[pr >> 16], 1);
    csr[ebeg + pos] = (int)(pr & 0xFFFFu);
  }
}

// ============== swz-f16 row layout (256 B): 16 frags of 8 f16, frag slot fc^(row&15) ========

// ---------------- W frag-pack helper (f16 hi/lo, kunit rotation) ----------------
__device__ __forceinline__ void pack_one(const float* __restrict__ W, ushort8* __restrict__ Wp,
                                         int f, int NT, int K, int rot) {
  int lane = f & 63;
  int hl = (f >> 6) & 1;
  int rest = f >> 7;
  int nt = rest % NT;
  int kunit = rest / NT;
  int nK = K >> 5;
  int srcKunit = (kunit + rot) % nK;
  int nrow = nt * 16 + (lane & 15);
  int k0 = srcKunit * 32 + (lane >> 4) * 8;
  const float* srcp = W + (size_t)nrow * K + k0;
  ushort8 v;
#pragma unroll
  for (int j = 0; j < 8; ++j) {
    float x = srcp[j];
    _Float16 h = (_Float16)x;
    if (hl) h = (_Float16)(x - (float)h);
    v[j] = __builtin_bit_cast(unsigned short, h);
  }
  Wp[f] = v;
}

// ---------------- merged prep_feat + pack_all ----------------
__global__ void prep_pack_kernel(const float* __restrict__ feat, _Float16* __restrict__ Fsp,
                                 int n, int fb,
                                 const float* __restrict__ W1, ushort8* __restrict__ P1,
                                 const float* __restrict__ W3, ushort8* __restrict__ P3,
                                 const float* __restrict__ Wm1, ushort8* __restrict__ PM1,
                                 const float* __restrict__ Wm2, ushort8* __restrict__ PM2) {
  int blk = blockIdx.x;
  if (blk < fb) {
    int i = blk * 256 + threadIdx.x;   // frag index
    if (i >= n * 16) return;
    int row = i >> 4, fc = i & 15;
    const float4* s = (const float4*)(feat + (size_t)row * NF + fc * 8);
    float4 a = s[0], b = s[1];
    float xv[8] = {a.x, a.y, a.z, a.w, b.x, b.y, b.z, b.w};
    half8 f;
#pragma unroll
    for (int j = 0; j < 8; ++j) f[j] = (_Float16)xv[j];
    int swz = (fc ^ (row & 15)) * 8;
    *(half8*)(Fsp + (size_t)row * 128 + swz) = f;
  } else {
    int f = (blk - fb) * 256 + threadIdx.x;
    if (f < 12288) pack_one(W1, P1, f, 8, 384, 0);
    else if (f < 24576) pack_one(W3, P3, f - 12288, 8, 384, 4);   // parts {T1,T2,X}
    else if (f < 28672) pack_one(Wm1, PM1, f - 24576, 8, 128, 0);
    else if (f < 30720) pack_one(Wm2, PM2, f - 28672, 4, 128, 0);
  }
}

// ---------------- SpMV: gathers swizzled f16 rows with per-edge dinv weight ----------------
__global__ __launch_bounds__(256) void spmv_kernel(
    const _Float16* __restrict__ xsp, const float* __restrict__ dinv,
    const int* __restrict__ offsets, const int* __restrict__ csr,
    const _Float16* __restrict__ zsp, float a, float bz,
    _Float16* __restrict__ outsp, int n) {
  int w = threadIdx.x >> 6, lane = threadIdx.x & 63;
  int node = blockIdx.x * 4 + w;
  if (node >= n) return;
  int beg = __builtin_amdgcn_readfirstlane(offsets[node]);
  int end = __builtin_amdgcn_readfirstlane(offsets[node + 1]);
  int eh = lane >> 4;        // which edge of the quad (0..3)
  int cq = lane & 15;        // frag index within the row

  float acc[8];
#pragma unroll
  for (int j = 0; j < 8; ++j) acc[j] = 0.f;

  int e2 = beg;
  for (; e2 + 8 <= end; e2 += 8) {
    int s0 = csr[e2 + eh];
    int s1 = csr[e2 + 4 + eh];
    float w0 = dinv[s0], w1 = dinv[s1];
    half8 g0 = *(const half8*)(xsp + (size_t)s0 * 128 + ((cq ^ (s0 & 15)) << 3));
    half8 g1 = *(const half8*)(xsp + (size_t)s1 * 128 + ((cq ^ (s1 & 15)) << 3));
#pragma unroll
    for (int j = 0; j < 8; ++j) acc[j] += w0 * (float)g0[j];
#pragma unroll
    for (int j = 0; j < 8; ++j) acc[j] += w1 * (float)g1[j];
  }
  for (; e2 + 4 <= end; e2 += 4) {
    int s0 = csr[e2 + eh];
    float w0 = dinv[s0];
    half8 g0 = *(const half8*)(xsp + (size_t)s0 * 128 + ((cq ^ (s0 & 15)) << 3));
#pragma unroll
    for (int j = 0; j < 8; ++j) acc[j] += w0 * (float)g0[j];
  }
  int rem = end - e2;
  if (eh < rem) {
    int s0 = csr[e2 + eh];
    float w0 = dinv[s0];
    half8 g0 = *(const half8*)(xsp + (size_t)s0 * 128 + ((cq ^ (s0 & 15)) << 3));
#pragma unroll
    for (int j = 0; j < 8; ++j) acc[j] += w0 * (float)g0[j];
  }
#pragma unroll
  for (int j = 0; j < 8; ++j) {
    acc[j] += __shfl_xor(acc[j], 16);
    acc[j] += __shfl_xor(acc[j], 32);
  }
  if (eh == 0) {
    float dv = a * dinv[node];
    float v[8];
#pragma unroll
    for (int j = 0; j < 8; ++j) v[j] = dv * acc[j];
    int swz = (cq ^ (node & 15)) << 3;
    if (zsp) {
      half8 zz = *(const half8*)(zsp + (size_t)node * 128 + swz);
#pragma unroll
      for (int j = 0; j < 8; ++j) v[j] += bz * (float)zz[j];
    }
    half8 ho;
#pragma unroll
    for (int j = 0; j < 8; ++j) ho[j] = (_Float16)v[j];
    *(half8*)(outsp + (size_t)node * 128 + swz) = ho;
  }
}

// ================= GEMM machinery (f16 A single, f16 W hi+lo; single-stage LDS) =================

__device__ __forceinline__ void stage_sp(const _Float16* gsrc, float4* lbuf, int tid) {
  const char* g = (const char*)gsrc;
  char* l = (char*)lbuf;
#pragma unroll
  for (int k = 0; k < 2; ++k) {
    int off = k * 8192 + tid * 16;
    __builtin_amdgcn_global_load_lds(
        (const __attribute__((address_space(1))) void*)(g + off),
        (__attribute__((address_space(3))) void*)(l + off), 16, 0, 0);
  }
}

__device__ __forceinline__ int lds_off16(int row, int col) {
  return row * 128 + (((col >> 3) ^ (row & 15)) << 3) + (col & 7);
}

// B chunk: 2 kunits x NT2=2 n-tiles x (hi,lo) = 8 frags = 32 VGPR
struct Bchunk {
  ushort8 h[2][2];
  ushort8 l[2][2];
};

__device__ __forceinline__ void loadB(const ushort8* __restrict__ Wp, int kunit0,
                                      int lane, int wn, Bchunk& c) {
#pragma unroll
  for (int k2 = 0; k2 < 2; ++k2) {
#pragma unroll
    for (int j = 0; j < 2; ++j) {
      const ushort8* bp = Wp + (size_t)((kunit0 + k2) * 8 + wn * 2 + j) * 128 + lane;
      c.h[k2][j] = bp[0];
      c.l[k2][j] = bp[64];
    }
  }
}

// MFMA one B-chunk: 2 kunits x 2 mt x 2 j x 2 terms = 16 MFMAs
__device__ __forceinline__ void mfma_chunk(const float4* A4, const Bchunk& c, int kbase,
                                           int lane, int wm, f32x4 (*acc)[2]) {
#pragma unroll
  for (int k2 = 0; k2 < 2; ++k2) {
    int kunit = kbase + k2;
    half8 a[2];
#pragma unroll
    for (int mt = 0; mt < 2; ++mt) {
      int arow = wm * 32 + mt * 16 + (lane & 15);
      int fc = (kunit & 3) * 4 + (lane >> 4);
      a[mt] = __builtin_bit_cast(half8, A4[arow * 16 + (fc ^ (arow & 15))]);
    }
#pragma unroll
    for (int j = 0; j < 2; ++j) {
      half8 bh = __builtin_bit_cast(half8, c.h[k2][j]);
      half8 bl = __builtin_bit_cast(half8, c.l[k2][j]);
#pragma unroll
      for (int mt = 0; mt < 2; ++mt) {
        acc[mt][j] = __builtin_amdgcn_mfma_f32_16x16x32_f16(a[mt], bh, acc[mt][j], 0, 0, 0);
        acc[mt][j] = __builtin_amdgcn_mfma_f32_16x16x32_f16(a[mt], bl, acc[mt][j], 0, 0, 0);
      }
    }
  }
}

// generic gemm_step for the MLP phases (A = f16 LDS tile, B compiler-managed)
template<int NT, int NT2>
__device__ __forceinline__ void gemm_step16(const float4* A4, const ushort8* __restrict__ Wp,
                                            int kunit, int lane, int wm, int wn,
                                            f32x4 (*acc)[NT2]) {
  half8 a[2];
#pragma unroll
  for (int mt = 0; mt < 2; ++mt) {
    int arow = wm * 32 + mt * 16 + (lane & 15);
    int fc = (kunit & 3) * 4 + (lane >> 4);
    a[mt] = __builtin_bit_cast(half8, A4[arow * 16 + (fc ^ (arow & 15))]);
  }
#pragma unroll
  for (int j = 0; j < NT2; ++j) {
    int nt = wn * NT2 + j;
    const ushort8* bp = Wp + (size_t)(kunit * NT + nt) * 2 * 64 + lane;
    half8 bh = __builtin_bit_cast(half8, bp[0]);
    half8 bl = __builtin_bit_cast(half8, bp[64]);
#pragma unroll
    for (int mt = 0; mt < 2; ++mt) {
      acc[mt][j] = __builtin_amdgcn_mfma_f32_16x16x32_f16(a[mt], bh, acc[mt][j], 0, 0, 0);
      acc[mt][j] = __builtin_amdgcn_mfma_f32_16x16x32_f16(a[mt], bl, acc[mt][j], 0, 0, 0);
    }
  }
}

// single-stage K-loop: stage all 3 parts (48 KB) at once, one vmcnt+barrier, 96 MFMAs
// with B register-rolled. Part p's tile lives at lds + p*1024 (float4 units).
__device__ __forceinline__ void gemm3_single(const _Float16* A0, const _Float16* A1,
                                             const _Float16* A2, const ushort8* Wp,
                                             float4* lds, size_t r0,
                                             int tid, int lane, int wm, int wn,
                                             f32x4 (*acc)[2]) {
  stage_sp(A0 + r0 * 128, lds, tid);
  stage_sp(A1 + r0 * 128, lds + 1024, tid);
  stage_sp(A2 + r0 * 128, lds + 2048, tid);
  Bchunk bc0, bc1;
  loadB(Wp, 0, lane, wn, bc0);
  asm volatile("s_waitcnt vmcnt(8)" ::: "memory");   // retire the 6 stage loads
  __builtin_amdgcn_s_barrier();
  __builtin_amdgcn_sched_barrier(0);
  loadB(Wp, 2, lane, wn, bc1);
  mfma_chunk(lds, bc0, 0, lane, wm, acc);
  loadB(Wp, 4, lane, wn, bc0);
  mfma_chunk(lds, bc1, 2, lane, wm, acc);
  loadB(Wp, 6, lane, wn, bc1);
  mfma_chunk(lds + 1024, bc0, 4, lane, wm, acc);
  loadB(Wp, 8, lane, wn, bc0);
  mfma_chunk(lds + 1024, bc1, 6, lane, wm, acc);
  loadB(Wp, 10, lane, wn, bc1);
  mfma_chunk(lds + 2048, bc0, 8, lane, wm, acc);
  mfma_chunk(lds + 2048, bc1, 10, lane, wm, acc);
}

// ---------------- conv1 GEMM + fused BN partial stats; writes PRE-BN Xsp (swizzled) --------
__global__ __launch_bounds__(512, 4) void conv1_gemm_kernel(
    const _Float16* __restrict__ A0, const _Float16* __restrict__ A1,
    const _Float16* __restrict__ A2,
    const ushort8* __restrict__ Wp, const float* __restrict__ bias,
    _Float16* __restrict__ Xsp, float* __restrict__ stats, int n) {
  __shared__ float4 lds[3072];   // 48 KB: 3 parts x 16 KB
  __shared__ float sstat[256];

  int tid = threadIdx.x;
  int lane = tid & 63, wid = tid >> 6;
  int wm = wid >> 2, wn = wid & 3;
  size_t r0 = (size_t)blockIdx.x * 64;

  f32x4 acc[2][2];
#pragma unroll
  for (int mt = 0; mt < 2; ++mt)
#pragma unroll
    for (int j = 0; j < 2; ++j) acc[mt][j] = (f32x4)0.f;

  gemm3_single(A0, A1, A2, Wp, lds, r0, tid, lane, wm, wn, acc);

  // epilogue: relu + swizzled f16 store + BN partial stats
  if (tid < 256) sstat[tid] = 0.f;
  __syncthreads();
#pragma unroll
  for (int mt = 0; mt < 2; ++mt) {
    int rbase = (int)r0 + wm * 32 + mt * 16 + (lane >> 4) * 4;
#pragma unroll
    for (int j = 0; j < 2; ++j) {
      int col = wn * 32 + j * 16 + (lane & 15);
      float b = bias[col];
      float sj = 0.f, qj = 0.f;
#pragma unroll
      for (int i = 0; i < 4; ++i) {
        int row = rbase + i;
        if (row < n) {
          float v = fmaxf(acc[mt][j][i] + b, 0.f);
          Xsp[(size_t)row * 128 + (((col >> 3) ^ (row & 15)) << 3) + (col & 7)] = (_Float16)v;
          sj += v; qj += v * v;
        }
      }
      sj += __shfl_xor(sj, 16); sj += __shfl_xor(sj, 32);
      qj += __shfl_xor(qj, 16); qj += __shfl_xor(qj, 32);
      if ((lane >> 4) == 0) {
        atomicAdd(&sstat[col], sj);
        atomicAdd(&sstat[128 + col], qj);
      }
    }
  }
  __syncthreads();
  if (tid < 256) atomicAdd(&stats[(blockIdx.x & 7) * 256 + tid], sstat[tid]);
}

// ---------------- fused tail: conv2 GEMM (parts {T1,T2,X}) + residual-from-LDS ----------------
__global__ __launch_bounds__(512, 4) void fused_tail_kernel(
    const _Float16* __restrict__ T1sp, const _Float16* __restrict__ T2sp,
    const _Float16* __restrict__ Xsp,
    const ushort8* __restrict__ Wp3, const float* __restrict__ b3,
    const ushort8* __restrict__ WpM1, const float* __restrict__ bm1,
    const ushort8* __restrict__ WpM2, const float* __restrict__ bm2,
    float* __restrict__ out, int n) {
  __shared__ float4 lds[3072];   // 48 KB
  _Float16* L0 = (_Float16*)lds;           // region 0: T1 tile -> then Y -> then H
  _Float16* LX = (_Float16*)(lds + 2048);  // region 2: X tile (resident after pipeline)

  int tid = threadIdx.x;
  int lane = tid & 63, wid = tid >> 6;
  int wm = wid >> 2, wn = wid & 3;
  size_t r0 = (size_t)blockIdx.x * 64;

  f32x4 acc[2][2];
#pragma unroll
  for (int mt = 0; mt < 2; ++mt)
#pragma unroll
    for (int j = 0; j < 2; ++j) acc[mt][j] = (f32x4)0.f;

  // ---- phase 1: conv2 GEMM over {T1sp, T2sp, Xsp}
  gemm3_single(T1sp, T2sp, Xsp, Wp3, lds, r0, tid, lane, wm, wn, acc);
  __syncthreads();   // all waves done reading region 0 (T1) before we overwrite with Y

  // ---- epilogue 1: Y = relu(acc+b3) + X(region 2) -> write into region 0
#pragma unroll
  for (int mt = 0; mt < 2; ++mt) {
    int rb = wm * 32 + mt * 16 + (lane >> 4) * 4;
#pragma unroll
    for (int j = 0; j < 2; ++j) {
      int col = wn * 32 + j * 16 + (lane & 15);
      float b = b3[col];
#pragma unroll
      for (int i = 0; i < 4; ++i) {
        int lrow = rb + i;
        int off = lds_off16(lrow, col);
        float xres = (float)LX[off];
        float v = fmaxf(acc[mt][j][i] + b, 0.f) + xres;
        L0[off] = (_Float16)v;
      }
    }
  }
  __syncthreads();
  // ---- phase 2: H = relu(Y @ Wm1^T + bm1)
  f32x4 acc2[2][2];
#pragma unroll
  for (int mt = 0; mt < 2; ++mt)
#pragma unroll
    for (int j = 0; j < 2; ++j) acc2[mt][j] = (f32x4)0.f;
#pragma unroll
  for (int ks = 0; ks < 4; ++ks)
    gemm_step16<8, 2>(lds, WpM1, ks, lane, wm, wn, acc2);
  __syncthreads();   // all reads of Y done before overwrite
  // ---- epilogue 2: scatter H (f16) into region 0
#pragma unroll
  for (int mt = 0; mt < 2; ++mt) {
    int rb = wm * 32 + mt * 16 + (lane >> 4) * 4;
#pragma unroll
    for (int j = 0; j < 2; ++j) {
      int col = wn * 32 + j * 16 + (lane & 15);
      float b = bm1[col];
#pragma unroll
      for (int i = 0; i < 4; ++i) {
        float v = fmaxf(acc2[mt][j][i] + b, 0.f);
        L0[lds_off16(rb + i, col)] = (_Float16)v;
      }
    }
  }
  __syncthreads();
  // ---- phase 3: out = H @ Wm2^T + bm2   (NC=64: NT=4, NT2=1)
  f32x4 acc3[2][1];
#pragma unroll
  for (int mt = 0; mt < 2; ++mt) acc3[mt][0] = (f32x4)0.f;
#pragma unroll
  for (int ks = 0; ks < 4; ++ks)
    gemm_step16<4, 1>(lds, WpM2, ks, lane, wm, wn, acc3);
#pragma unroll
  for (int mt = 0; mt < 2; ++mt) {
    int rb = wm * 32 + mt * 16 + (lane >> 4) * 4;
    int col = wn * 16 + (lane & 15);
    float b = bm2[col];
#pragma unroll
    for (int i = 0; i < 4; ++i) {
      int row = (int)r0 + rb + i;
      if (row < n) out[(size_t)row * 64 + col] = acc3[mt][0][i] + b;
    }
  }
}

// ---------------- BatchNorm apply IN PLACE on swizzled Xsp ----------------
__global__ void bn_apply_kernel(_Float16* __restrict__ Xsp, const float* __restrict__ stats,
                                const float* __restrict__ gamma, const float* __restrict__ beta,
                                float fn, int n) {
  int i = blockIdx.x * 256 + threadIdx.x;   // frag index
  if (i >= n * 16) return;
  int row = i >> 4, fc = i & 15;
  int swz = (fc ^ (row & 15)) * 8;
  half8* xp = (half8*)(Xsp + (size_t)row * 128 + swz);
  half8 xh = *xp;
  half8 hu;
  int c0 = fc * 8;
#pragma unroll
  for (int j = 0; j < 8; ++j) {
    int c = c0 + j;
    float s1 = 0.f, s2 = 0.f;
#pragma unroll
    for (int r = 0; r < 8; ++r) {
      s1 += stats[r * 256 + c];
      s2 += stats[r * 256 + NF + c];
    }
    float mu = s1 / fn;
    float var = s2 / fn - mu * mu;
    float s = gamma[c] * rsqrtf(var + 1e-5f);
    hu[j] = (_Float16)(((float)xh[j] - mu) * s + beta[c]);
  }
  *xp = hu;
}

// ---------------- launcher ----------------
extern "C" void kernel_launch(void* const* d_in, const int* in_sizes, int n_in,
                              void* d_out, int out_size, void* d_ws, size_t ws_size,
                              hipStream_t stream) {
  const float* feat  = (const float*)d_in[0];
  const int*   src   = (const int*)d_in[1];
  const int*   dst   = (const int*)d_in[2];
  const float* W1    = (const float*)d_in[3];
  const float* b1    = (const float*)d_in[4];
  const float* W3    = (const float*)d_in[5];
  const float* b3    = (const float*)d_in[6];
  const float* gamma = (const float*)d_in[7];
  const float* beta  = (const float*)d_in[8];
  const float* Wm1   = (const float*)d_in[9];
  const float* bm1   = (const float*)d_in[10];
  const float* Wm2   = (const float*)d_in[11];
  const float* bm2   = (const float*)d_in[12];
  int n = in_sizes[0] / NF;
  int e = in_sizes[1];

  char* p = (char*)d_ws;
  auto alloc = [&](size_t bytes) {
    char* r = p;
    p += (bytes + 255) & ~size_t(255);
    return r;
  };
  int nblk  = ceil_div(e, 4096);   // multisplit tiles
  int nbuck = ceil_div(n, 256);    // node buckets (<= 256 assumed)

  float* dinv     = (float*)alloc((size_t)n * 4);
  int*   offsets  = (int*)alloc((size_t)(n + 1) * 4);
  int*   counts   = (int*)alloc((size_t)nblk * nbuck * 4);
  int*   btot     = (int*)alloc((size_t)nbuck * 4);
  int*   csr      = (int*)alloc((size_t)e * 4);
  float* stats    = (float*)alloc(8 * 256 * 4);
  ushort8* Wp1  = (ushort8*)alloc(12 * 8 * 2 * 64 * 16);   // K=384, NT=8
  ushort8* Wp3  = (ushort8*)alloc(12 * 8 * 2 * 64 * 16);
  ushort8* WpM1 = (ushort8*)alloc(4 * 8 * 2 * 64 * 16);    // K=128, NT=8
  ushort8* WpM2 = (ushort8*)alloc(4 * 4 * 2 * 64 * 16);    // K=128, NT=4
  size_t spb = (size_t)(n + 64) * 256;        // swz f16 rows, 64 pad rows for gload_lds
  _Float16* Fsp  = (_Float16*)alloc(spb);
  _Float16* T1sp = (_Float16*)alloc(spb);
  _Float16* T2sp = (_Float16*)alloc(spb);
  _Float16* Xsp  = (_Float16*)alloc(spb);
  unsigned int* binned = (unsigned int*)Fsp;   // alias: 3.2 MB scratch, dead before prep

  hipMemsetAsync(stats, 0, 8 * 256 * 4, stream);

  int fb = ceil_div(n * 16, 256);            // frag-grid over matrices
  int sb = ceil_div(n, 4);                   // spmv: 4 nodes/block
  int gb = ceil_div(n, 64);                  // gemm: 64 rows/block, 512 threads

  // CSR build (sorted by dst) via two-level multisplit; emits offsets/dinv
  bucket_hist_kernel<<<nblk, 256, 0, stream>>>(dst, counts, e, nblk, nbuck);
  bucket_scan_rows_kernel<<<nbuck, 256, 0, stream>>>(counts, btot, nblk);
  bucket_bin_kernel<<<nblk, 256, 0, stream>>>(src, dst, counts, btot, binned, e, nblk, nbuck);
  bucket_finalize_kernel<<<nbuck, 256, 0, stream>>>(binned, btot, offsets, csr, dinv, n, e, nbuck);

  // merged prep_feat + W pack
  prep_pack_kernel<<<fb + 120, 256, 0, stream>>>(feat, Fsp, n, fb,
                                                 W1, Wp1, W3, Wp3, Wm1, WpM1, Wm2, WpM2);

  // conv1: T1 = -A^ F ; T2 = -2 A^ T1 - F ; Xsp = swz f16(relu([F,T1,T2] @ W1^T + b1))
  spmv_kernel<<<sb, 256, 0, stream>>>(Fsp, dinv, offsets, csr, nullptr, -1.f, 0.f, T1sp, n);
  spmv_kernel<<<sb, 256, 0, stream>>>(T1sp, dinv, offsets, csr, Fsp, -2.f, -1.f, T2sp, n);
  conv1_gemm_kernel<<<gb, 512, 0, stream>>>(Fsp, T1sp, T2sp, Wp1, b1, Xsp, stats, n);

  // BatchNorm apply in place on Xsp (inline from replicated stats)
  bn_apply_kernel<<<fb, 256, 0, stream>>>(Xsp, stats, gamma, beta, (float)n, n);

  // conv2 spmvs (gather/z from swizzled buffers directly)
  spmv_kernel<<<sb, 256, 0, stream>>>(Xsp, dinv, offsets, csr, nullptr, -1.f, 0.f, T1sp, n);
  spmv_kernel<<<sb, 256, 0, stream>>>(T1sp, dinv, offsets, csr, Xsp, -2.f, -1.f, T2sp, n);

  // fused conv2-GEMM (parts {T1,T2,X}) + residual-from-LDS + MLP1 + MLP2
  fused_tail_kernel<<<gb, 512, 0, stream>>>(T1sp, T2sp, Xsp, Wp3, b3, WpM1, bm1,
                                            WpM2, bm2, (float*)d_out, n);
}

// Round 19
// 247.169 us; speedup vs baseline: 1.3745x; 1.0184x over previous
//
#include <hip/hip_runtime.h>
#include <hip/hip_bf16.h>
#include <math.h>

#define NF 128   // IN_F == HID == 128

typedef unsigned short ushort8 __attribute__((ext_vector_type(8)));
typedef float f32x4 __attribute__((ext_vector_type(4)));
typedef _Float16 half8 __attribute__((ext_vector_type(8)));

static inline int ceil_div(int a, int b) { return (a + b - 1) / b; }

// ================= CSR build: two-level multisplit counting sort =================
// NOTE: assumes nbuck <= 256 (N <= 65536), true here (N=50000 -> nbuck=196).
__global__ __launch_bounds__(256) void bucket_hist_kernel(const int* __restrict__ dst,
                                                          int* __restrict__ counts,
                                                          int e, int nblk, int nbuck) {
  __shared__ int h[256];
  int t = threadIdx.x, blk = blockIdx.x;
  h[t] = 0;
  __syncthreads();
  int base = blk * 4096;
#pragma unroll
  for (int k = 0; k < 16; ++k) {
    int i = base + k * 256 + t;
    if (i < e) atomicAdd(&h[dst[i] >> 8], 1);
  }
  __syncthreads();
  for (int b = t; b < nbuck; b += 256) counts[b * nblk + blk] = h[b];
}

__global__ __launch_bounds__(256) void bucket_scan_rows_kernel(int* __restrict__ counts,
                                                               int* __restrict__ btot,
                                                               int nblk) {
  __shared__ int sh[256];
  int b = blockIdx.x, t = threadIdx.x;
  int* row = counts + (size_t)b * nblk;
  int carry = 0;
  for (int base = 0; base < nblk; base += 256) {
    int v = (base + t < nblk) ? row[base + t] : 0;
    sh[t] = v;
    __syncthreads();
    for (int off = 1; off < 256; off <<= 1) {
      int add = (t >= off) ? sh[t - off] : 0;
      __syncthreads();
      sh[t] += add;
      __syncthreads();
    }
    if (base + t < nblk) row[base + t] = carry + sh[t] - v;
    carry += sh[255];
    __syncthreads();
  }
  if (t == 0) btot[b] = carry;
}

// binned word: (dst&255)<<16 | src   (valid because N < 65536)
__global__ __launch_bounds__(256) void bucket_bin_kernel(const int* __restrict__ src,
                                                         const int* __restrict__ dst,
                                                         const int* __restrict__ counts,
                                                         const int* __restrict__ btot,
                                                         unsigned int* __restrict__ binned,
                                                         int e, int nblk, int nbuck) {
  __shared__ int sh[256];
  __shared__ int cur[256];
  int t = threadIdx.x, blk = blockIdx.x;
  int v = (t < nbuck) ? btot[t] : 0;
  sh[t] = v;
  __syncthreads();
  for (int off = 1; off < 256; off <<= 1) {
    int add = (t >= off) ? sh[t - off] : 0;
    __syncthreads();
    sh[t] += add;
    __syncthreads();
  }
  if (t < nbuck) cur[t] = counts[(size_t)t * nblk + blk] + (sh[t] - v);   // + exclusive base
  __syncthreads();
  int base = blk * 4096;
#pragma unroll
  for (int k = 0; k < 16; ++k) {
    int i = base + k * 256 + t;
    if (i < e) {
      int d = dst[i];
      int pos = atomicAdd(&cur[d >> 8], 1);
      binned[pos] = ((unsigned)(d & 255) << 16) | (unsigned)src[i];
    }
  }
}

__global__ __launch_bounds__(256) void bucket_finalize_kernel(const unsigned int* __restrict__ binned,
                                                              const int* __restrict__ btot,
                                                              int* __restrict__ offsets,
                                                              int* __restrict__ csr,
                                                              float* __restrict__ dinv,
                                                              int n, int e, int nbuck) {
  __shared__ int sh[256];
  __shared__ int deg[256];
  __shared__ int offs[256];
  __shared__ int cur[256];
  __shared__ int sbeg, send;
  int b = blockIdx.x, t = threadIdx.x;
  int v0 = (t < nbuck) ? btot[t] : 0;
  sh[t] = v0;
  __syncthreads();
  for (int off = 1; off < 256; off <<= 1) {
    int add = (t >= off) ? sh[t - off] : 0;
    __syncthreads();
    sh[t] += add;
    __syncthreads();
  }
  if (t == 0) { sbeg = (b > 0) ? sh[b - 1] : 0; send = sh[b]; }
  deg[t] = 0;
  __syncthreads();
  int ebeg = sbeg, eend = send;
  for (int j = ebeg + t; j < eend; j += 256) atomicAdd(&deg[binned[j] >> 16], 1);
  __syncthreads();
  int v = deg[t];
  offs[t] = v;
  __syncthreads();
  for (int off = 1; off < 256; off <<= 1) {
    int add = (t >= off) ? offs[t - off] : 0;
    __syncthreads();
    offs[t] += add;
    __syncthreads();
  }
  int excl = offs[t] - v;
  cur[t] = excl;
  int node = b * 256 + t;
  if (node < n) {
    offsets[node] = ebeg + excl;
    float d = (float)(v > 1 ? v : 1);
    dinv[node] = rsqrtf(d);
  }
  if (b == nbuck - 1 && t == 0) offsets[n] = e;
  __syncthreads();
  for (int j = ebeg + t; j < eend; j += 256) {
    unsigned int pr = binned[j];
    int pos = atomicAdd(&cur[pr >> 16], 1);
    csr[ebeg + pos] = (int)(pr & 0xFFFFu);
  }
}

// ============== swz-f16 row layout (256 B): 16 frags of 8 f16, frag slot fc^(row&15) ========

// ---------------- W frag-pack (f16 hi/lo, kunit rotation, Cheb affine folded) ----------------
// For cheb packs (K=384): source block 0 -> W0 - W2; block 1 -> -W1; block 2 -> 2*W2.
// Then parts {F,U1,U2} (or {U1,U2,X} with rot=4) with PURE spmv outputs U = A^ x.
__device__ __forceinline__ void pack_one(const float* __restrict__ W, ushort8* __restrict__ Wp,
                                         int f, int NT, int K, int rot, bool cheb) {
  int lane = f & 63;
  int hl = (f >> 6) & 1;
  int rest = f >> 7;
  int nt = rest % NT;
  int kunit = rest / NT;
  int nK = K >> 5;
  int srcKunit = (kunit + rot) % nK;
  int blkid = srcKunit >> 2;   // k-block of the original [W0|W1|W2] concat
  int nrow = nt * 16 + (lane & 15);
  int k0 = srcKunit * 32 + (lane >> 4) * 8;
  const float* srcp = W + (size_t)nrow * K + k0;
  ushort8 v;
#pragma unroll
  for (int j = 0; j < 8; ++j) {
    float x = srcp[j];
    if (cheb) {
      if (blkid == 0)      x = x - srcp[j + 256];   // W0 - W2
      else if (blkid == 1) x = -x;                  // -W1
      else                 x = 2.f * x;             // 2*W2
    }
    _Float16 h = (_Float16)x;
    if (hl) h = (_Float16)(x - (float)h);
    v[j] = __builtin_bit_cast(unsigned short, h);
  }
  Wp[f] = v;
}

// ---------------- merged prep_feat + pack_all ----------------
__global__ void prep_pack_kernel(const float* __restrict__ feat, _Float16* __restrict__ Fsp,
                                 int n, int fb,
                                 const float* __restrict__ W1, ushort8* __restrict__ P1,
                                 const float* __restrict__ W3, ushort8* __restrict__ P3,
                                 const float* __restrict__ Wm1, ushort8* __restrict__ PM1,
                                 const float* __restrict__ Wm2, ushort8* __restrict__ PM2) {
  int blk = blockIdx.x;
  if (blk < fb) {
    int i = blk * 256 + threadIdx.x;   // frag index
    if (i >= n * 16) return;
    int row = i >> 4, fc = i & 15;
    const float4* s = (const float4*)(feat + (size_t)row * NF + fc * 8);
    float4 a = s[0], b = s[1];
    float xv[8] = {a.x, a.y, a.z, a.w, b.x, b.y, b.z, b.w};
    half8 f;
#pragma unroll
    for (int j = 0; j < 8; ++j) f[j] = (_Float16)xv[j];
    int swz = (fc ^ (row & 15)) * 8;
    *(half8*)(Fsp + (size_t)row * 128 + swz) = f;
  } else {
    int f = (blk - fb) * 256 + threadIdx.x;
    if (f < 12288) pack_one(W1, P1, f, 8, 384, 0, true);          // parts {F,U1,U2}
    else if (f < 24576) pack_one(W3, P3, f - 12288, 8, 384, 4, true);   // parts {U1,U2,X}
    else if (f < 28672) pack_one(Wm1, PM1, f - 24576, 8, 128, 0, false);
    else if (f < 30720) pack_one(Wm2, PM2, f - 28672, 4, 128, 0, false);
  }
}

// ---------------- SpMV (pure): out[v] = dinv[v] * sum_e dinv[src]*x[src]  (swz-f16 rows) ----
__global__ __launch_bounds__(256) void spmv_kernel(
    const _Float16* __restrict__ xsp, const float* __restrict__ dinv,
    const int* __restrict__ offsets, const int* __restrict__ csr,
    _Float16* __restrict__ outsp, int n) {
  int w = threadIdx.x >> 6, lane = threadIdx.x & 63;
  int node = blockIdx.x * 4 + w;
  if (node >= n) return;
  int beg = __builtin_amdgcn_readfirstlane(offsets[node]);
  int end = __builtin_amdgcn_readfirstlane(offsets[node + 1]);
  int eh = lane >> 4;        // which edge of the quad (0..3)
  int cq = lane & 15;        // frag index within the row

  float acc[8];
#pragma unroll
  for (int j = 0; j < 8; ++j) acc[j] = 0.f;

  int e2 = beg;
  for (; e2 + 8 <= end; e2 += 8) {
    int s0 = csr[e2 + eh];
    int s1 = csr[e2 + 4 + eh];
    float w0 = dinv[s0], w1 = dinv[s1];
    half8 g0 = *(const half8*)(xsp + (size_t)s0 * 128 + ((cq ^ (s0 & 15)) << 3));
    half8 g1 = *(const half8*)(xsp + (size_t)s1 * 128 + ((cq ^ (s1 & 15)) << 3));
#pragma unroll
    for (int j = 0; j < 8; ++j) acc[j] += w0 * (float)g0[j];
#pragma unroll
    for (int j = 0; j < 8; ++j) acc[j] += w1 * (float)g1[j];
  }
  for (; e2 + 4 <= end; e2 += 4) {
    int s0 = csr[e2 + eh];
    float w0 = dinv[s0];
    half8 g0 = *(const half8*)(xsp + (size_t)s0 * 128 + ((cq ^ (s0 & 15)) << 3));
#pragma unroll
    for (int j = 0; j < 8; ++j) acc[j] += w0 * (float)g0[j];
  }
  int rem = end - e2;
  if (eh < rem) {
    int s0 = csr[e2 + eh];
    float w0 = dinv[s0];
    half8 g0 = *(const half8*)(xsp + (size_t)s0 * 128 + ((cq ^ (s0 & 15)) << 3));
#pragma unroll
    for (int j = 0; j < 8; ++j) acc[j] += w0 * (float)g0[j];
  }
#pragma unroll
  for (int j = 0; j < 8; ++j) {
    acc[j] += __shfl_xor(acc[j], 16);
    acc[j] += __shfl_xor(acc[j], 32);
  }
  if (eh == 0) {
    float dv = dinv[node];
    half8 ho;
#pragma unroll
    for (int j = 0; j < 8; ++j) ho[j] = (_Float16)(dv * acc[j]);
    int swz = (cq ^ (node & 15)) << 3;
    *(half8*)(outsp + (size_t)node * 128 + swz) = ho;
  }
}

// ================= GEMM machinery (f16 A single, f16 W hi+lo; single-stage LDS) =================

__device__ __forceinline__ void stage_sp(const _Float16* gsrc, float4* lbuf, int tid) {
  const char* g = (const char*)gsrc;
  char* l = (char*)lbuf;
#pragma unroll
  for (int k = 0; k < 2; ++k) {
    int off = k * 8192 + tid * 16;
    __builtin_amdgcn_global_load_lds(
        (const __attribute__((address_space(1))) void*)(g + off),
        (__attribute__((address_space(3))) void*)(l + off), 16, 0, 0);
  }
}

__device__ __forceinline__ int lds_off16(int row, int col) {
  return row * 128 + (((col >> 3) ^ (row & 15)) << 3) + (col & 7);
}

// B chunk: 2 kunits x NT2=2 n-tiles x (hi,lo) = 8 frags = 32 VGPR
struct Bchunk {
  ushort8 h[2][2];
  ushort8 l[2][2];
};

__device__ __forceinline__ void loadB(const ushort8* __restrict__ Wp, int kunit0,
                                      int lane, int wn, Bchunk& c) {
#pragma unroll
  for (int k2 = 0; k2 < 2; ++k2) {
#pragma unroll
    for (int j = 0; j < 2; ++j) {
      const ushort8* bp = Wp + (size_t)((kunit0 + k2) * 8 + wn * 2 + j) * 128 + lane;
      c.h[k2][j] = bp[0];
      c.l[k2][j] = bp[64];
    }
  }
}

// MFMA one B-chunk: 2 kunits x 2 mt x 2 j x 2 terms = 16 MFMAs
__device__ __forceinline__ void mfma_chunk(const float4* A4, const Bchunk& c, int kbase,
                                           int lane, int wm, f32x4 (*acc)[2]) {
#pragma unroll
  for (int k2 = 0; k2 < 2; ++k2) {
    int kunit = kbase + k2;
    half8 a[2];
#pragma unroll
    for (int mt = 0; mt < 2; ++mt) {
      int arow = wm * 32 + mt * 16 + (lane & 15);
      int fc = (kunit & 3) * 4 + (lane >> 4);
      a[mt] = __builtin_bit_cast(half8, A4[arow * 16 + (fc ^ (arow & 15))]);
    }
#pragma unroll
    for (int j = 0; j < 2; ++j) {
      half8 bh = __builtin_bit_cast(half8, c.h[k2][j]);
      half8 bl = __builtin_bit_cast(half8, c.l[k2][j]);
#pragma unroll
      for (int mt = 0; mt < 2; ++mt) {
        acc[mt][j] = __builtin_amdgcn_mfma_f32_16x16x32_f16(a[mt], bh, acc[mt][j], 0, 0, 0);
        acc[mt][j] = __builtin_amdgcn_mfma_f32_16x16x32_f16(a[mt], bl, acc[mt][j], 0, 0, 0);
      }
    }
  }
}

// generic gemm_step for the MLP phases (A = f16 LDS tile, B compiler-managed)
template<int NT, int NT2>
__device__ __forceinline__ void gemm_step16(const float4* A4, const ushort8* __restrict__ Wp,
                                            int kunit, int lane, int wm, int wn,
                                            f32x4 (*acc)[NT2]) {
  half8 a[2];
#pragma unroll
  for (int mt = 0; mt < 2; ++mt) {
    int arow = wm * 32 + mt * 16 + (lane & 15);
    int fc = (kunit & 3) * 4 + (lane >> 4);
    a[mt] = __builtin_bit_cast(half8, A4[arow * 16 + (fc ^ (arow & 15))]);
  }
#pragma unroll
  for (int j = 0; j < NT2; ++j) {
    int nt = wn * NT2 + j;
    const ushort8* bp = Wp + (size_t)(kunit * NT + nt) * 2 * 64 + lane;
    half8 bh = __builtin_bit_cast(half8, bp[0]);
    half8 bl = __builtin_bit_cast(half8, bp[64]);
#pragma unroll
    for (int mt = 0; mt < 2; ++mt) {
      acc[mt][j] = __builtin_amdgcn_mfma_f32_16x16x32_f16(a[mt], bh, acc[mt][j], 0, 0, 0);
      acc[mt][j] = __builtin_amdgcn_mfma_f32_16x16x32_f16(a[mt], bl, acc[mt][j], 0, 0, 0);
    }
  }
}

// single-stage K-loop: stage all 3 parts (48 KB) at once, one vmcnt+barrier, 96 MFMAs
// with B register-rolled. Part p's tile lives at lds + p*1024 (float4 units).
__device__ __forceinline__ void gemm3_single(const _Float16* A0, const _Float16* A1,
                                             const _Float16* A2, const ushort8* Wp,
                                             float4* lds, size_t r0,
                                             int tid, int lane, int wm, int wn,
                                             f32x4 (*acc)[2]) {
  stage_sp(A0 + r0 * 128, lds, tid);
  stage_sp(A1 + r0 * 128, lds + 1024, tid);
  stage_sp(A2 + r0 * 128, lds + 2048, tid);
  Bchunk bc0, bc1;
  loadB(Wp, 0, lane, wn, bc0);
  asm volatile("s_waitcnt vmcnt(8)" ::: "memory");   // retire the 6 stage loads
  __builtin_amdgcn_s_barrier();
  __builtin_amdgcn_sched_barrier(0);
  loadB(Wp, 2, lane, wn, bc1);
  mfma_chunk(lds, bc0, 0, lane, wm, acc);
  loadB(Wp, 4, lane, wn, bc0);
  mfma_chunk(lds, bc1, 2, lane, wm, acc);
  loadB(Wp, 6, lane, wn, bc1);
  mfma_chunk(lds + 1024, bc0, 4, lane, wm, acc);
  loadB(Wp, 8, lane, wn, bc0);
  mfma_chunk(lds + 1024, bc1, 6, lane, wm, acc);
  loadB(Wp, 10, lane, wn, bc1);
  mfma_chunk(lds + 2048, bc0, 8, lane, wm, acc);
  mfma_chunk(lds + 2048, bc1, 10, lane, wm, acc);
}

// ---------------- conv1 GEMM + fused BN partial stats; writes PRE-BN Xsp (swizzled) --------
__global__ __launch_bounds__(512, 4) void conv1_gemm_kernel(
    const _Float16* __restrict__ A0, const _Float16* __restrict__ A1,
    const _Float16* __restrict__ A2,
    const ushort8* __restrict__ Wp, const float* __restrict__ bias,
    _Float16* __restrict__ Xsp, float* __restrict__ stats, int n) {
  __shared__ float4 lds[3072];   // 48 KB: 3 parts x 16 KB
  __shared__ float sstat[256];

  int tid = threadIdx.x;
  int lane = tid & 63, wid = tid >> 6;
  int wm = wid >> 2, wn = wid & 3;
  size_t r0 = (size_t)blockIdx.x * 64;

  f32x4 acc[2][2];
#pragma unroll
  for (int mt = 0; mt < 2; ++mt)
#pragma unroll
    for (int j = 0; j < 2; ++j) acc[mt][j] = (f32x4)0.f;

  gemm3_single(A0, A1, A2, Wp, lds, r0, tid, lane, wm, wn, acc);

  // epilogue: relu + swizzled f16 store + BN partial stats
  if (tid < 256) sstat[tid] = 0.f;
  __syncthreads();
#pragma unroll
  for (int mt = 0; mt < 2; ++mt) {
    int rbase = (int)r0 + wm * 32 + mt * 16 + (lane >> 4) * 4;
#pragma unroll
    for (int j = 0; j < 2; ++j) {
      int col = wn * 32 + j * 16 + (lane & 15);
      float b = bias[col];
      float sj = 0.f, qj = 0.f;
#pragma unroll
      for (int i = 0; i < 4; ++i) {
        int row = rbase + i;
        if (row < n) {
          float v = fmaxf(acc[mt][j][i] + b, 0.f);
          Xsp[(size_t)row * 128 + (((col >> 3) ^ (row & 15)) << 3) + (col & 7)] = (_Float16)v;
          sj += v; qj += v * v;
        }
      }
      sj += __shfl_xor(sj, 16); sj += __shfl_xor(sj, 32);
      qj += __shfl_xor(qj, 16); qj += __shfl_xor(qj, 32);
      if ((lane >> 4) == 0) {
        atomicAdd(&sstat[col], sj);
        atomicAdd(&sstat[128 + col], qj);
      }
    }
  }
  __syncthreads();
  if (tid < 256) atomicAdd(&stats[(blockIdx.x & 7) * 256 + tid], sstat[tid]);
}

// ---------------- fused tail: conv2 GEMM (parts {U1,U2,X}) + residual-from-LDS ----------------
__global__ __launch_bounds__(512, 4) void fused_tail_kernel(
    const _Float16* __restrict__ T1sp, const _Float16* __restrict__ T2sp,
    const _Float16* __restrict__ Xsp,
    const ushort8* __restrict__ Wp3, const float* __restrict__ b3,
    const ushort8* __restrict__ WpM1, const float* __restrict__ bm1,
    const ushort8* __restrict__ WpM2, const float* __restrict__ bm2,
    float* __restrict__ out, int n) {
  __shared__ float4 lds[3072];   // 48 KB
  _Float16* L0 = (_Float16*)lds;           // region 0: U1 tile -> then Y -> then H
  _Float16* LX = (_Float16*)(lds + 2048);  // region 2: X tile (resident after pipeline)

  int tid = threadIdx.x;
  int lane = tid & 63, wid = tid >> 6;
  int wm = wid >> 2, wn = wid & 3;
  size_t r0 = (size_t)blockIdx.x * 64;

  f32x4 acc[2][2];
#pragma unroll
  for (int mt = 0; mt < 2; ++mt)
#pragma unroll
    for (int j = 0; j < 2; ++j) acc[mt][j] = (f32x4)0.f;

  // ---- phase 1: conv2 GEMM over {U1, U2, X}
  gemm3_single(T1sp, T2sp, Xsp, Wp3, lds, r0, tid, lane, wm, wn, acc);
  __syncthreads();   // all waves done reading region 0 before overwrite with Y

  // ---- epilogue 1: Y = relu(acc+b3) + X(region 2) -> write into region 0
#pragma unroll
  for (int mt = 0; mt < 2; ++mt) {
    int rb = wm * 32 + mt * 16 + (lane >> 4) * 4;
#pragma unroll
    for (int j = 0; j < 2; ++j) {
      int col = wn * 32 + j * 16 + (lane & 15);
      float b = b3[col];
#pragma unroll
      for (int i = 0; i < 4; ++i) {
        int lrow = rb + i;
        int off = lds_off16(lrow, col);
        float xres = (float)LX[off];
        float v = fmaxf(acc[mt][j][i] + b, 0.f) + xres;
        L0[off] = (_Float16)v;
      }
    }
  }
  __syncthreads();
  // ---- phase 2: H = relu(Y @ Wm1^T + bm1)
  f32x4 acc2[2][2];
#pragma unroll
  for (int mt = 0; mt < 2; ++mt)
#pragma unroll
    for (int j = 0; j < 2; ++j) acc2[mt][j] = (f32x4)0.f;
#pragma unroll
  for (int ks = 0; ks < 4; ++ks)
    gemm_step16<8, 2>(lds, WpM1, ks, lane, wm, wn, acc2);
  __syncthreads();   // all reads of Y done before overwrite
  // ---- epilogue 2: scatter H (f16) into region 0
#pragma unroll
  for (int mt = 0; mt < 2; ++mt) {
    int rb = wm * 32 + mt * 16 + (lane >> 4) * 4;
#pragma unroll
    for (int j = 0; j < 2; ++j) {
      int col = wn * 32 + j * 16 + (lane & 15);
      float b = bm1[col];
#pragma unroll
      for (int i = 0; i < 4; ++i) {
        float v = fmaxf(acc2[mt][j][i] + b, 0.f);
        L0[lds_off16(rb + i, col)] = (_Float16)v;
      }
    }
  }
  __syncthreads();
  // ---- phase 3: out = H @ Wm2^T + bm2   (NC=64: NT=4, NT2=1)
  f32x4 acc3[2][1];
#pragma unroll
  for (int mt = 0; mt < 2; ++mt) acc3[mt][0] = (f32x4)0.f;
#pragma unroll
  for (int ks = 0; ks < 4; ++ks)
    gemm_step16<4, 1>(lds, WpM2, ks, lane, wm, wn, acc3);
#pragma unroll
  for (int mt = 0; mt < 2; ++mt) {
    int rb = wm * 32 + mt * 16 + (lane >> 4) * 4;
    int col = wn * 16 + (lane & 15);
    float b = bm2[col];
#pragma unroll
    for (int i = 0; i < 4; ++i) {
      int row = (int)r0 + rb + i;
      if (row < n) out[(size_t)row * 64 + col] = acc3[mt][0][i] + b;
    }
  }
}

// ---------------- BatchNorm apply IN PLACE on swizzled Xsp ----------------
__global__ void bn_apply_kernel(_Float16* __restrict__ Xsp, const float* __restrict__ stats,
                                const float* __restrict__ gamma, const float* __restrict__ beta,
                                float fn, int n) {
  int i = blockIdx.x * 256 + threadIdx.x;   // frag index
  if (i >= n * 16) return;
  int row = i >> 4, fc = i & 15;
  int swz = (fc ^ (row & 15)) * 8;
  half8* xp = (half8*)(Xsp + (size_t)row * 128 + swz);
  half8 xh = *xp;
  half8 hu;
  int c0 = fc * 8;
#pragma unroll
  for (int j = 0; j < 8; ++j) {
    int c = c0 + j;
    float s1 = 0.f, s2 = 0.f;
#pragma unroll
    for (int r = 0; r < 8; ++r) {
      s1 += stats[r * 256 + c];
      s2 += stats[r * 256 + NF + c];
    }
    float mu = s1 / fn;
    float var = s2 / fn - mu * mu;
    float s = gamma[c] * rsqrtf(var + 1e-5f);
    hu[j] = (_Float16)(((float)xh[j] - mu) * s + beta[c]);
  }
  *xp = hu;
}

// ---------------- launcher ----------------
extern "C" void kernel_launch(void* const* d_in, const int* in_sizes, int n_in,
                              void* d_out, int out_size, void* d_ws, size_t ws_size,
                              hipStream_t stream) {
  const float* feat  = (const float*)d_in[0];
  const int*   src   = (const int*)d_in[1];
  const int*   dst   = (const int*)d_in[2];
  const float* W1    = (const float*)d_in[3];
  const float* b1    = (const float*)d_in[4];
  const float* W3    = (const float*)d_in[5];
  const float* b3    = (const float*)d_in[6];
  const float* gamma = (const float*)d_in[7];
  const float* beta  = (const float*)d_in[8];
  const float* Wm1   = (const float*)d_in[9];
  const float* bm1   = (const float*)d_in[10];
  const float* Wm2   = (const float*)d_in[11];
  const float* bm2   = (const float*)d_in[12];
  int n = in_sizes[0] / NF;
  int e = in_sizes[1];

  char* p = (char*)d_ws;
  auto alloc = [&](size_t bytes) {
    char* r = p;
    p += (bytes + 255) & ~size_t(255);
    return r;
  };
  int nblk  = ceil_div(e, 4096);   // multisplit tiles
  int nbuck = ceil_div(n, 256);    // node buckets (<= 256 assumed)

  float* dinv     = (float*)alloc((size_t)n * 4);
  int*   offsets  = (int*)alloc((size_t)(n + 1) * 4);
  int*   counts   = (int*)alloc((size_t)nblk * nbuck * 4);
  int*   btot     = (int*)alloc((size_t)nbuck * 4);
  int*   csr      = (int*)alloc((size_t)e * 4);
  float* stats    = (float*)alloc(8 * 256 * 4);
  ushort8* Wp1  = (ushort8*)alloc(12 * 8 * 2 * 64 * 16);   // K=384, NT=8
  ushort8* Wp3  = (ushort8*)alloc(12 * 8 * 2 * 64 * 16);
  ushort8* WpM1 = (ushort8*)alloc(4 * 8 * 2 * 64 * 16);    // K=128, NT=8
  ushort8* WpM2 = (ushort8*)alloc(4 * 4 * 2 * 64 * 16);    // K=128, NT=4
  size_t spb = (size_t)(n + 64) * 256;        // swz f16 rows, 64 pad rows for gload_lds
  _Float16* Fsp  = (_Float16*)alloc(spb);
  _Float16* T1sp = (_Float16*)alloc(spb);
  _Float16* T2sp = (_Float16*)alloc(spb);
  _Float16* Xsp  = (_Float16*)alloc(spb);
  unsigned int* binned = (unsigned int*)Fsp;   // alias: 3.2 MB scratch, dead before prep

  hipMemsetAsync(stats, 0, 8 * 256 * 4, stream);

  int fb = ceil_div(n * 16, 256);            // frag-grid over matrices
  int sb = ceil_div(n, 4);                   // spmv: 4 nodes/block
  int gb = ceil_div(n, 64);                  // gemm: 64 rows/block, 512 threads

  // CSR build (sorted by dst) via two-level multisplit; emits offsets/dinv
  bucket_hist_kernel<<<nblk, 256, 0, stream>>>(dst, counts, e, nblk, nbuck);
  bucket_scan_rows_kernel<<<nbuck, 256, 0, stream>>>(counts, btot, nblk);
  bucket_bin_kernel<<<nblk, 256, 0, stream>>>(src, dst, counts, btot, binned, e, nblk, nbuck);
  bucket_finalize_kernel<<<nbuck, 256, 0, stream>>>(binned, btot, offsets, csr, dinv, n, e, nbuck);

  // merged prep_feat + W pack (Cheb affine folded into Wp1/Wp3)
  prep_pack_kernel<<<fb + 120, 256, 0, stream>>>(feat, Fsp, n, fb,
                                                 W1, Wp1, W3, Wp3, Wm1, WpM1, Wm2, WpM2);

  // conv1: U1 = A^ F ; U2 = A^ U1 ; Xsp = swz f16(relu([F,U1,U2] @ W1'^T + b1))
  spmv_kernel<<<sb, 256, 0, stream>>>(Fsp, dinv, offsets, csr, T1sp, n);
  spmv_kernel<<<sb, 256, 0, stream>>>(T1sp, dinv, offsets, csr, T2sp, n);
  conv1_gemm_kernel<<<gb, 512, 0, stream>>>(Fsp, T1sp, T2sp, Wp1, b1, Xsp, stats, n);

  // BatchNorm apply in place on Xsp (inline from replicated stats)
  bn_apply_kernel<<<fb, 256, 0, stream>>>(Xsp, stats, gamma, beta, (float)n, n);

  // conv2 spmvs (pure)
  spmv_kernel<<<sb, 256, 0, stream>>>(Xsp, dinv, offsets, csr, T1sp, n);
  spmv_kernel<<<sb, 256, 0, stream>>>(T1sp, dinv, offsets, csr, T2sp, n);

  // fused conv2-GEMM (parts {U1,U2,X}) + residual-from-LDS + MLP1 + MLP2
  fused_tail_kernel<<<gb, 512, 0, stream>>>(T1sp, T2sp, Xsp, Wp3, b3, WpM1, bm1,
                                            WpM2, bm2, (float*)d_out, n);
}